// Round 1
// baseline (2144.592 us; speedup 1.0000x reference)
//
#include <hip/hip_runtime.h>
#include <hip/hip_bf16.h>

#define HW_ 4096

// ---------------- GEMM: Y[b][o][p] = sum_c W[o][c] * X[b][c][p] ----------------
// grid (64 p-tiles, 4 o-tiles, B), block 256; thread tile 4o x 4p
__global__ __launch_bounds__(256) void gemm256_kernel(
    const float* __restrict__ X, const float* __restrict__ W, float* __restrict__ Y) {
  __shared__ float Xs[16][64];
  __shared__ float Ws[16][64];
  const int t = threadIdx.x;
  const int p0 = blockIdx.x * 64;
  const int o0 = blockIdx.y * 64;
  const int b = blockIdx.z;
  const float* Xb = X + (size_t)b * 256 * HW_;
  const int tp0 = (t & 15) * 4;
  const int to0 = (t >> 4) * 4;
  float acc[4][4] = {};
  for (int c0 = 0; c0 < 256; c0 += 16) {
    {
      const int cc = t >> 4;
      const int pp = (t & 15) * 4;
      *(float4*)&Xs[cc][pp] = *(const float4*)&Xb[(size_t)(c0 + cc) * HW_ + p0 + pp];
      const int oo = t >> 2;
      const int c4 = (t & 3) * 4;
      float4 wv = *(const float4*)&W[(size_t)(o0 + oo) * 256 + c0 + c4];
      Ws[c4 + 0][oo] = wv.x;
      Ws[c4 + 1][oo] = wv.y;
      Ws[c4 + 2][oo] = wv.z;
      Ws[c4 + 3][oo] = wv.w;
    }
    __syncthreads();
#pragma unroll
    for (int cc = 0; cc < 16; ++cc) {
      float4 xv = *(const float4*)&Xs[cc][tp0];
      float4 wv = *(const float4*)&Ws[cc][to0];
      const float xa[4] = {xv.x, xv.y, xv.z, xv.w};
      const float wa[4] = {wv.x, wv.y, wv.z, wv.w};
#pragma unroll
      for (int i = 0; i < 4; ++i)
#pragma unroll
        for (int j = 0; j < 4; ++j) acc[i][j] += wa[i] * xa[j];
    }
    __syncthreads();
  }
#pragma unroll
  for (int i = 0; i < 4; ++i) {
    float4 ov = {acc[i][0], acc[i][1], acc[i][2], acc[i][3]};
    *(float4*)&Y[((size_t)b * 256 + o0 + to0 + i) * HW_ + p0 + tp0] = ov;
  }
}

// ---------------- Flash attention, fp32, QB=64, KB=64 ----------------
// grid (64 q-tiles, 16 bn), block 256; thread tile 4q x 4j (and 4q x 4d for O)
// q/k/v layout: [b][c=n*64+dd][p]; ao aliases q (block writes exactly the
// region it read, after all reads).
__global__ __launch_bounds__(256) void attn_kernel(
    const float* q, const float* __restrict__ k, const float* __restrict__ v, float* ao) {
  __shared__ float q_l[64][64];
  __shared__ float k_l[64][64];
  __shared__ float v_l[64][64];  // row=dd(=d), col=j, XOR-swizzled
  __shared__ float s_l[64][68];
  const int t = threadIdx.x;
  const int p0 = blockIdx.x * 64;
  const size_t base = (size_t)blockIdx.y * 64 * HW_;  // (b*256+n*64)*HW
  const float* qb = q + base;
  const float* kb = k + base;
  const float* vb = v + base;
  const int tq0 = (t >> 4) * 4;
  const int tj0 = (t & 15) * 4;

#pragma unroll
  for (int it = 0; it < 4; ++it) {
    const int dd = it * 16 + (t >> 4);
    const int pp = (t & 15) * 4;
    *(float4*)&q_l[dd][pp] = *(const float4*)&qb[(size_t)dd * HW_ + p0 + pp];
  }

  float m_r[4], l_r[4];
  float acc_o[4][4] = {};
#pragma unroll
  for (int i = 0; i < 4; ++i) { m_r[i] = -1e30f; l_r[i] = 0.f; }

  for (int kbi = 0; kbi < 64; ++kbi) {
    const int j0 = kbi * 64;
    __syncthreads();  // protect k_l/v_l/s_l (and first-iter q_l)
#pragma unroll
    for (int it = 0; it < 4; ++it) {
      const int dd = it * 16 + (t >> 4);
      const int pp = (t & 15) * 4;
      *(float4*)&k_l[dd][pp] = *(const float4*)&kb[(size_t)dd * HW_ + j0 + pp];
      const int sw = ((dd >> 2) & 7) << 2;
      *(float4*)&v_l[dd][pp ^ sw] = *(const float4*)&vb[(size_t)dd * HW_ + j0 + pp];
    }
    __syncthreads();

    float s[4][4] = {};
#pragma unroll 8
    for (int dd = 0; dd < 64; ++dd) {
      float4 qv = *(const float4*)&q_l[dd][tq0];
      float4 kv = *(const float4*)&k_l[dd][tj0];
      const float qa[4] = {qv.x, qv.y, qv.z, qv.w};
      const float ka[4] = {kv.x, kv.y, kv.z, kv.w};
#pragma unroll
      for (int i = 0; i < 4; ++i)
#pragma unroll
        for (int j = 0; j < 4; ++j) s[i][j] += qa[i] * ka[j];
    }

#pragma unroll
    for (int i = 0; i < 4; ++i) {
      const float sv0 = s[i][0] * 0.125f, sv1 = s[i][1] * 0.125f;
      const float sv2 = s[i][2] * 0.125f, sv3 = s[i][3] * 0.125f;
      float mx = fmaxf(fmaxf(sv0, sv1), fmaxf(sv2, sv3));
      mx = fmaxf(mx, __shfl_xor(mx, 1));
      mx = fmaxf(mx, __shfl_xor(mx, 2));
      mx = fmaxf(mx, __shfl_xor(mx, 4));
      mx = fmaxf(mx, __shfl_xor(mx, 8));
      const float m_new = fmaxf(m_r[i], mx);
      const float corr = __expf(m_r[i] - m_new);
      const float e0 = __expf(sv0 - m_new);
      const float e1 = __expf(sv1 - m_new);
      const float e2 = __expf(sv2 - m_new);
      const float e3 = __expf(sv3 - m_new);
      float rs = e0 + e1 + e2 + e3;
      rs += __shfl_xor(rs, 1);
      rs += __shfl_xor(rs, 2);
      rs += __shfl_xor(rs, 4);
      rs += __shfl_xor(rs, 8);
      l_r[i] = l_r[i] * corr + rs;
      m_r[i] = m_new;
      acc_o[i][0] *= corr; acc_o[i][1] *= corr; acc_o[i][2] *= corr; acc_o[i][3] *= corr;
      float4 pw = {e0, e1, e2, e3};
      *(float4*)&s_l[tq0 + i][tj0] = pw;
    }
    __syncthreads();

#pragma unroll 2
    for (int jj = 0; jj < 64; jj += 4) {
      float4 pv[4], vv[4];
#pragma unroll
      for (int i = 0; i < 4; ++i) pv[i] = *(const float4*)&s_l[tq0 + i][jj];
#pragma unroll
      for (int kk = 0; kk < 4; ++kk) {
        const int row = tj0 + kk;
        vv[kk] = *(const float4*)&v_l[row][jj ^ (((row >> 2) & 7) << 2)];
      }
#pragma unroll
      for (int i = 0; i < 4; ++i)
#pragma unroll
        for (int kk = 0; kk < 4; ++kk)
          acc_o[i][kk] += pv[i].x * vv[kk].x + pv[i].y * vv[kk].y +
                          pv[i].z * vv[kk].z + pv[i].w * vv[kk].w;
    }
  }

#pragma unroll
  for (int kk = 0; kk < 4; ++kk) {
    float4 ov = {acc_o[0][kk] / l_r[0], acc_o[1][kk] / l_r[1],
                 acc_o[2][kk] / l_r[2], acc_o[3][kk] / l_r[3]};
    *(float4*)&ao[base + (size_t)(tj0 + kk) * HW_ + p0 + tq0] = ov;
  }
}

// ---------------- SE pooling: avg & max over spatial per (b, ch of 512) ----------------
__global__ __launch_bounds__(256) void pool_kernel(
    const float* __restrict__ proj, const float* __restrict__ gray,
    float* __restrict__ pavg, float* __restrict__ pmax) {
  const int ch = blockIdx.x;
  const int b = blockIdx.y;
  const int t = threadIdx.x;
  const float* src = (ch < 256) ? (proj + ((size_t)b * 256 + ch) * HW_)
                                : (gray + ((size_t)b * 256 + (ch - 256)) * HW_);
  float s = 0.f, mx = -1e30f;
  for (int p = t; p < HW_; p += 256) {
    const float v_ = src[p];
    s += v_;
    mx = fmaxf(mx, v_);
  }
#pragma unroll
  for (int o = 1; o < 64; o <<= 1) {
    s += __shfl_xor(s, o);
    mx = fmaxf(mx, __shfl_xor(mx, o));
  }
  __shared__ float ss[4], sm[4];
  if ((t & 63) == 0) { ss[t >> 6] = s; sm[t >> 6] = mx; }
  __syncthreads();
  if (t == 0) {
    const float S = ss[0] + ss[1] + ss[2] + ss[3];
    const float M = fmaxf(fmaxf(sm[0], sm[1]), fmaxf(sm[2], sm[3]));
    pavg[b * 512 + ch] = S * (1.f / 4096.f);
    pmax[b * 512 + ch] = M;
  }
}

// ---------------- SE MLP: wch = sigmoid(mlp(avg)+mlp(max)) ----------------
__global__ __launch_bounds__(256) void se_kernel(
    const float* __restrict__ pavg, const float* __restrict__ pmax,
    const float* __restrict__ w1, const float* __restrict__ w2,
    float* __restrict__ wch) {
  const int b = blockIdx.x;
  const int t = threadIdx.x;
  __shared__ float za[512], zm[512], hs[64];
  za[t] = pavg[b * 512 + t];
  za[256 + t] = pavg[b * 512 + 256 + t];
  zm[t] = pmax[b * 512 + t];
  zm[256 + t] = pmax[b * 512 + 256 + t];
  __syncthreads();
  if (t < 64) {
    float ha = 0.f, hm = 0.f;
    for (int c = 0; c < 512; ++c) {
      const float w = w1[t * 512 + c];
      ha += w * za[c];
      hm += w * zm[c];
    }
    hs[t] = fmaxf(ha, 0.f) + fmaxf(hm, 0.f);
  }
  __syncthreads();
  for (int o = t; o < 512; o += 256) {
    float acc = 0.f;
#pragma unroll
    for (int hh = 0; hh < 64; ++hh) acc += hs[hh] * w2[o * 64 + hh];
    wch[b * 512 + o] = 1.f / (1.f + __expf(-acc));
  }
}

// ---------------- spatial-attention input: per-pixel mean/max over gated channels ----------------
__global__ __launch_bounds__(256) void sa_reduce_kernel(
    const float* __restrict__ proj, const float* __restrict__ gray,
    const float* __restrict__ wch, float* __restrict__ sa_in) {
  const int b = blockIdx.y;
  const int p = blockIdx.x * 256 + threadIdx.x;
  __shared__ float wl[512];
  wl[threadIdx.x] = wch[b * 512 + threadIdx.x];
  wl[256 + threadIdx.x] = wch[b * 512 + 256 + threadIdx.x];
  __syncthreads();
  const float* pb = proj + (size_t)b * 256 * HW_;
  const float* gb = gray + (size_t)b * 256 * HW_;
  float s = 0.f, mx = -1e30f;
  for (int ch = 0; ch < 256; ++ch) {
    const float v_ = pb[(size_t)ch * HW_ + p] * wl[ch];
    s += v_;
    mx = fmaxf(mx, v_);
  }
  for (int ch = 0; ch < 256; ++ch) {
    const float v_ = gb[(size_t)ch * HW_ + p] * wl[256 + ch];
    s += v_;
    mx = fmaxf(mx, v_);
  }
  sa_in[((size_t)b * 2 + 0) * HW_ + p] = s * (1.f / 512.f);
  sa_in[((size_t)b * 2 + 1) * HW_ + p] = mx;
}

// ---------------- 7x7 spatial conv + sigmoid -> wsp ----------------
__global__ __launch_bounds__(256) void sa_conv_kernel(
    const float* __restrict__ sa_in, const float* __restrict__ sa_w,
    float* __restrict__ wsp) {
  const int b = blockIdx.y;
  const int t = threadIdx.x;
  __shared__ float pl[2][64][64];
  __shared__ float wl[98];
  for (int e = t; e < 8192; e += 256) ((float*)pl)[e] = sa_in[(size_t)b * 8192 + e];
  if (t < 98) wl[t] = sa_w[t];
  __syncthreads();
  const int pix = blockIdx.x * 256 + t;
  const int y = pix >> 6, x = pix & 63;
  float acc = 0.f;
#pragma unroll
  for (int ic = 0; ic < 2; ++ic)
#pragma unroll
    for (int ky = 0; ky < 7; ++ky) {
      const int yy = y + ky - 3;
      if (yy < 0 || yy > 63) continue;
#pragma unroll
      for (int kx = 0; kx < 7; ++kx) {
        const int xx = x + kx - 3;
        if (xx < 0 || xx > 63) continue;
        acc += pl[ic][yy][xx] * wl[ic * 49 + ky * 7 + kx];
      }
    }
  wsp[(size_t)b * HW_ + pix] = 1.f / (1.f + __expf(-acc));
}

// ---------------- fuse: 3x3 conv over gated cat (gating on load) + BN + LeakyReLU ----------------
// grid (64 y, 4 oc-tiles, B), block 128 = 16 oc-groups x 8 x-groups; thread 4oc x 8x
__global__ __launch_bounds__(128) void fuse_kernel(
    const float* __restrict__ proj, const float* __restrict__ gray,
    const float* __restrict__ wch, const float* __restrict__ wsp,
    const float* __restrict__ fw, const float* __restrict__ bn_g,
    const float* __restrict__ bn_b, const float* __restrict__ bn_m,
    const float* __restrict__ bn_v, float* __restrict__ out) {
  __shared__ float cg[8][3][68];     // [ic][row y-1..y+1][1+xx], xx in -1..64
  __shared__ float wl[8][3][3][64];  // [ic][ky][kx][oc]
  __shared__ float wchl[512];
  __shared__ float wspl[3][66];
  const int t = threadIdx.x;
  const int y = blockIdx.x;
  const int o0 = blockIdx.y * 64;
  const int b = blockIdx.z;
  const int oc0 = (t >> 3) * 4;
  const int x0 = (t & 7) * 8;

  for (int e = t; e < 512; e += 128) wchl[e] = wch[b * 512 + e];
  for (int e = t; e < 198; e += 128) {
    const int r = e / 66;
    const int xi = e % 66;
    const int xx = xi - 1;
    const int yy = y + r - 1;
    float vw = 0.f;
    if (yy >= 0 && yy < 64 && xx >= 0 && xx < 64) vw = wsp[(size_t)b * HW_ + yy * 64 + xx];
    wspl[r][xi] = vw;
  }

  const float* pb = proj + (size_t)b * 256 * HW_;
  const float* gb = gray + (size_t)b * 256 * HW_;
  float acc[4][8] = {};

  for (int ic0 = 0; ic0 < 512; ic0 += 8) {
    __syncthreads();
    for (int e = t; e < 1584; e += 128) {
      const int ic = e / 198;
      const int rr = e % 198;
      const int r = rr / 66;
      const int xi = rr % 66;
      const int xx = xi - 1;
      const int yy = y + r - 1;
      const int ch = ic0 + ic;
      float val = 0.f;
      if (yy >= 0 && yy < 64 && xx >= 0 && xx < 64) {
        const float sv = (ch < 256) ? pb[(size_t)ch * HW_ + yy * 64 + xx]
                                    : gb[(size_t)(ch - 256) * HW_ + yy * 64 + xx];
        val = sv * wchl[ch] * wspl[r][xi];
      }
      cg[ic][r][xi] = val;
    }
    for (int e4 = t * 4; e4 < 4608; e4 += 512) {
      const int oc = e4 / 72;
      const int r = e4 % 72;
      float4 wv = *(const float4*)&fw[(size_t)(o0 + oc) * 4608 + (size_t)ic0 * 9 + r];
      const float wa[4] = {wv.x, wv.y, wv.z, wv.w};
#pragma unroll
      for (int u = 0; u < 4; ++u) {
        const int rr = r + u;
        wl[rr / 9][(rr % 9) / 3][rr % 3][oc] = wa[u];
      }
    }
    __syncthreads();
    for (int ic = 0; ic < 8; ++ic) {
#pragma unroll
      for (int ky = 0; ky < 3; ++ky) {
        float xv[10];
        float4 a0 = *(const float4*)&cg[ic][ky][x0];
        float4 a1 = *(const float4*)&cg[ic][ky][x0 + 4];
        float2 a2 = *(const float2*)&cg[ic][ky][x0 + 8];
        xv[0] = a0.x; xv[1] = a0.y; xv[2] = a0.z; xv[3] = a0.w;
        xv[4] = a1.x; xv[5] = a1.y; xv[6] = a1.z; xv[7] = a1.w;
        xv[8] = a2.x; xv[9] = a2.y;
#pragma unroll
        for (int kx = 0; kx < 3; ++kx) {
          float4 wv = *(const float4*)&wl[ic][ky][kx][oc0];
          const float wa[4] = {wv.x, wv.y, wv.z, wv.w};
#pragma unroll
          for (int oi = 0; oi < 4; ++oi)
#pragma unroll
            for (int xj = 0; xj < 8; ++xj) acc[oi][xj] += wa[oi] * xv[xj + kx];
        }
      }
    }
  }

#pragma unroll
  for (int oi = 0; oi < 4; ++oi) {
    const int oc = o0 + oc0 + oi;
    const float inv = bn_g[oc] * rsqrtf(bn_v[oc] + 1e-5f);
    const float mu = bn_m[oc];
    const float bb = bn_b[oc];
    float vals[8];
#pragma unroll
    for (int xj = 0; xj < 8; ++xj) {
      const float yv = (acc[oi][xj] - mu) * inv + bb;
      vals[xj] = yv > 0.f ? yv : 0.2f * yv;
    }
    float4 r0 = {vals[0], vals[1], vals[2], vals[3]};
    float4 r1 = {vals[4], vals[5], vals[6], vals[7]};
    float* op = out + ((size_t)(b * 256 + oc)) * HW_ + y * 64 + x0;
    *(float4*)&op[0] = r0;
    *(float4*)&op[4] = r1;
  }
}

extern "C" void kernel_launch(void* const* d_in, const int* in_sizes, int n_in,
                              void* d_out, int out_size, void* d_ws, size_t ws_size,
                              hipStream_t stream) {
  const float* color  = (const float*)d_in[0];
  const float* gray   = (const float*)d_in[1];
  const float* Wq     = (const float*)d_in[2];
  const float* Wk     = (const float*)d_in[3];
  const float* Wv     = (const float*)d_in[4];
  const float* Wproj  = (const float*)d_in[5];
  const float* ca_w1  = (const float*)d_in[6];
  const float* ca_w2  = (const float*)d_in[7];
  const float* sa_w   = (const float*)d_in[8];
  const float* fuse_w = (const float*)d_in[9];
  const float* bn_g   = (const float*)d_in[10];
  const float* bn_b   = (const float*)d_in[11];
  const float* bn_m   = (const float*)d_in[12];
  const float* bn_v   = (const float*)d_in[13];
  float* out = (float*)d_out;

  float* ws    = (float*)d_ws;
  float* q     = ws;               // 4M floats; attention output (ao) aliases q
  float* kbuf  = q + 4194304;      // k; later reused for proj
  float* vbuf  = kbuf + 4194304;   // v
  float* pavg  = vbuf + 4194304;   // 2048
  float* pmax  = pavg + 2048;      // 2048
  float* wch   = pmax + 2048;      // 2048
  float* sa_in = wch + 2048;       // 32768
  float* wsp   = sa_in + 32768;    // 16384
  (void)in_sizes; (void)n_in; (void)out_size; (void)ws_size;

  dim3 g_gemm(64, 4, 4);
  gemm256_kernel<<<g_gemm, 256, 0, stream>>>(color, Wq, q);
  gemm256_kernel<<<g_gemm, 256, 0, stream>>>(gray, Wk, kbuf);
  gemm256_kernel<<<g_gemm, 256, 0, stream>>>(gray, Wv, vbuf);
  attn_kernel<<<dim3(64, 16), 256, 0, stream>>>(q, kbuf, vbuf, q);
  gemm256_kernel<<<g_gemm, 256, 0, stream>>>(q, Wproj, kbuf);  // proj -> kbuf
  pool_kernel<<<dim3(512, 4), 256, 0, stream>>>(kbuf, gray, pavg, pmax);
  se_kernel<<<dim3(4), 256, 0, stream>>>(pavg, pmax, ca_w1, ca_w2, wch);
  sa_reduce_kernel<<<dim3(16, 4), 256, 0, stream>>>(kbuf, gray, wch, sa_in);
  sa_conv_kernel<<<dim3(16, 4), 256, 0, stream>>>(sa_in, sa_w, wsp);
  fuse_kernel<<<dim3(64, 4, 4), 128, 0, stream>>>(kbuf, gray, wch, wsp, fuse_w,
                                                  bn_g, bn_b, bn_m, bn_v, out);
}

// Round 2
// 1172.323 us; speedup vs baseline: 1.8294x; 1.8294x over previous
//
#include <hip/hip_runtime.h>
#include <hip/hip_bf16.h>
#include <stdint.h>

#define HW_ 4096

typedef short bf16x8 __attribute__((ext_vector_type(8)));
typedef short short4v __attribute__((ext_vector_type(4)));
typedef float f32x4 __attribute__((ext_vector_type(4)));

__device__ inline unsigned short f2bf(float x) {
  uint32_t u = __builtin_bit_cast(uint32_t, x);
  uint32_t r = ((u >> 16) & 1u) + 0x7fffu;
  return (unsigned short)((u + r) >> 16);
}
__device__ inline uint32_t pack2bf(float lo, float hi) {
  return (uint32_t)f2bf(lo) | ((uint32_t)f2bf(hi) << 16);
}
__device__ inline void gld_lds16(const unsigned short* g, unsigned short* l) {
  __builtin_amdgcn_global_load_lds((const __attribute__((address_space(1))) void*)g,
                                   (__attribute__((address_space(3))) void*)l, 16, 0, 0);
}

// ---------------- GEMM: Y[b][o][p] = sum_c W[o][c] * X[b][c][p] ----------------
// mode 0: fp32 [b][c][p]. mode 1: bf16 [b*4+n][p][dd] (*oscale). mode 2: bf16 [b][c][p].
__global__ __launch_bounds__(256) void gemm256_kernel(
    const float* __restrict__ X, const float* __restrict__ W, void* __restrict__ Yv,
    int mode, float oscale) {
  __shared__ float Xs[16][64];
  __shared__ float Ws[16][64];
  const int t = threadIdx.x;
  const int p0 = blockIdx.x * 64;
  const int o0 = blockIdx.y * 64;
  const int b = blockIdx.z;
  const float* Xb = X + (size_t)b * 256 * HW_;
  const int tp0 = (t & 15) * 4;
  const int to0 = (t >> 4) * 4;
  float acc[4][4] = {};
  for (int c0 = 0; c0 < 256; c0 += 16) {
    {
      const int cc = t >> 4;
      const int pp = (t & 15) * 4;
      *(float4*)&Xs[cc][pp] = *(const float4*)&Xb[(size_t)(c0 + cc) * HW_ + p0 + pp];
      const int oo = t >> 2;
      const int c4 = (t & 3) * 4;
      float4 wv = *(const float4*)&W[(size_t)(o0 + oo) * 256 + c0 + c4];
      Ws[c4 + 0][oo] = wv.x;
      Ws[c4 + 1][oo] = wv.y;
      Ws[c4 + 2][oo] = wv.z;
      Ws[c4 + 3][oo] = wv.w;
    }
    __syncthreads();
#pragma unroll
    for (int cc = 0; cc < 16; ++cc) {
      float4 xv = *(const float4*)&Xs[cc][tp0];
      float4 wv = *(const float4*)&Ws[cc][to0];
      const float xa[4] = {xv.x, xv.y, xv.z, xv.w};
      const float wa[4] = {wv.x, wv.y, wv.z, wv.w};
#pragma unroll
      for (int i = 0; i < 4; ++i)
#pragma unroll
        for (int j = 0; j < 4; ++j) acc[i][j] += wa[i] * xa[j];
    }
    __syncthreads();
  }
  if (mode == 0) {
    float* Y = (float*)Yv;
#pragma unroll
    for (int i = 0; i < 4; ++i) {
      float4 ov = {acc[i][0], acc[i][1], acc[i][2], acc[i][3]};
      *(float4*)&Y[((size_t)b * 256 + o0 + to0 + i) * HW_ + p0 + tp0] = ov;
    }
  } else if (mode == 1) {
    // bf16 [b*4+n][p][dd]; o0 is 64-aligned so n = o0>>6, dd = to0+i
    unsigned short* Y = (unsigned short*)Yv;
    const size_t bn = (size_t)b * 4 + (o0 >> 6);
#pragma unroll
    for (int j = 0; j < 4; ++j) {
      ushort4 ov;
      ov.x = f2bf(acc[0][j] * oscale);
      ov.y = f2bf(acc[1][j] * oscale);
      ov.z = f2bf(acc[2][j] * oscale);
      ov.w = f2bf(acc[3][j] * oscale);
      *(ushort4*)&Y[(bn * HW_ + p0 + tp0 + j) * 64 + to0] = ov;
    }
  } else {
    // bf16 [b][c][p]
    unsigned short* Y = (unsigned short*)Yv;
#pragma unroll
    for (int i = 0; i < 4; ++i) {
      ushort4 ov;
      ov.x = f2bf(acc[i][0]);
      ov.y = f2bf(acc[i][1]);
      ov.z = f2bf(acc[i][2]);
      ov.w = f2bf(acc[i][3]);
      *(ushort4*)&Y[((size_t)b * 256 + o0 + to0 + i) * HW_ + p0 + tp0] = ov;
    }
  }
}

// ---------------- MFMA flash attention ----------------
// Qb,Kb: bf16 [bn][p][d] (Q pre-scaled by 0.125*log2e). Vb: bf16 [bn*64+dd][p].
// AO: fp32 [bn*64+dd][p]. Block: 4 waves, each 32 q-rows (2 n-tiles). KB=64.
// Swapped QK^T (S^T in acc) keeps softmax rows lane-local; k-permuted PV keeps
// P fragments entirely in registers.
__global__ __launch_bounds__(256) void attn_mfma_kernel(
    const unsigned short* __restrict__ Qb, const unsigned short* __restrict__ Kb,
    const unsigned short* __restrict__ Vb, float* __restrict__ AO) {
  __shared__ unsigned short k_l[2][64][64];  // [buf][j][d], 16B-chunk XOR-swizzled by (j&7)
  __shared__ unsigned short v_l[2][64][64];  // [buf][dd][j], swizzled by (dd&7)
  const int t = threadIdx.x;
  const int w = t >> 6;
  const int l = t & 63;
  const int g = l >> 4;
  const int c = l & 15;
  const int bn = blockIdx.y;
  const int q0 = blockIdx.x * 128 + w * 32;

  // Q fragments (held in registers for the whole kernel)
  bf16x8 qf[2][2];
#pragma unroll
  for (int qt = 0; qt < 2; ++qt)
#pragma unroll
    for (int dh = 0; dh < 2; ++dh)
      qf[qt][dh] = *(const bf16x8*)&Qb[((size_t)bn * HW_ + q0 + qt * 16 + c) * 64 + dh * 32 + g * 8];

  // staging: wave w stages rows 16w..16w+15 (two 8-row halves), linear LDS dest,
  // pre-swizzled global source (chunk XOR by row&7)
  const int srow = 16 * w + (l >> 3);
  const int schunk = (l & 7) ^ ((l >> 3) & 7);
  const unsigned short* gK = Kb + ((size_t)bn * HW_ + srow) * 64 + schunk * 8;
  const unsigned short* gV = Vb + ((size_t)bn * 64 + srow) * HW_ + schunk * 8;

  f32x4 accO[2][4] = {};
  float m_r[2] = {-1e30f, -1e30f};
  float l_r[2] = {0.f, 0.f};

  // prologue: stage tile 0 into buf 0
#pragma unroll
  for (int h = 0; h < 2; ++h) {
    gld_lds16(gK + (size_t)(8 * h) * 64, &k_l[0][16 * w + 8 * h][0]);
    gld_lds16(gV + (size_t)(8 * h) * HW_, &v_l[0][16 * w + 8 * h][0]);
  }

  int buf = 0;
  for (int kt = 0; kt < 64; ++kt) {
    asm volatile("s_waitcnt vmcnt(0)" ::: "memory");
    __syncthreads();
    if (kt < 63) {
      const int j0 = (kt + 1) * 64;
#pragma unroll
      for (int h = 0; h < 2; ++h) {
        gld_lds16(gK + ((size_t)j0 + 8 * h) * 64, &k_l[buf ^ 1][16 * w + 8 * h][0]);
        gld_lds16(gV + (size_t)(8 * h) * HW_ + j0, &v_l[buf ^ 1][16 * w + 8 * h][0]);
      }
    }

    // ---- QK^T (swapped: acc holds S^T tile; lane owns q-row q0+qt*16+c) ----
    f32x4 accS[2][4] = {};
#pragma unroll
    for (int jt = 0; jt < 4; ++jt) {
      const int jrow = jt * 16 + c;
      bf16x8 kf0 = *(const bf16x8*)&k_l[buf][jrow][((0 * 4 + g) ^ (c & 7)) * 8];
      bf16x8 kf1 = *(const bf16x8*)&k_l[buf][jrow][((1 * 4 + g) ^ (c & 7)) * 8];
#pragma unroll
      for (int qt = 0; qt < 2; ++qt) {
        accS[qt][jt] = __builtin_amdgcn_mfma_f32_16x16x32_bf16(kf0, qf[qt][0], accS[qt][jt], 0, 0, 0);
        accS[qt][jt] = __builtin_amdgcn_mfma_f32_16x16x32_bf16(kf1, qf[qt][1], accS[qt][jt], 0, 0, 0);
      }
    }

    // ---- online softmax, fully in-register (exp2 domain) ----
    uint32_t pw[2][4][2];
#pragma unroll
    for (int qt = 0; qt < 2; ++qt) {
      float mx = accS[qt][0][0];
#pragma unroll
      for (int jt = 0; jt < 4; ++jt)
#pragma unroll
        for (int r = 0; r < 4; ++r) mx = fmaxf(mx, accS[qt][jt][r]);
      mx = fmaxf(mx, __shfl_xor(mx, 16));
      mx = fmaxf(mx, __shfl_xor(mx, 32));
      const float m_new = fmaxf(m_r[qt], mx);
      const float corr = __builtin_amdgcn_exp2f(m_r[qt] - m_new);
      m_r[qt] = m_new;
      float rs = 0.f;
#pragma unroll
      for (int jt = 0; jt < 4; ++jt) {
        float e0 = __builtin_amdgcn_exp2f(accS[qt][jt][0] - m_new);
        float e1 = __builtin_amdgcn_exp2f(accS[qt][jt][1] - m_new);
        float e2 = __builtin_amdgcn_exp2f(accS[qt][jt][2] - m_new);
        float e3 = __builtin_amdgcn_exp2f(accS[qt][jt][3] - m_new);
        rs += (e0 + e1) + (e2 + e3);
        pw[qt][jt][0] = pack2bf(e0, e1);
        pw[qt][jt][1] = pack2bf(e2, e3);
      }
      rs += __shfl_xor(rs, 16);
      rs += __shfl_xor(rs, 32);
      l_r[qt] = l_r[qt] * corr + rs;
#pragma unroll
      for (int dt = 0; dt < 4; ++dt)
#pragma unroll
        for (int r = 0; r < 4; ++r) accO[qt][dt][r] *= corr;
    }

    // ---- PV (A = V^T from LDS with permuted-k; B = P packed words in-reg) ----
#pragma unroll
    for (int dt = 0; dt < 4; ++dt) {
      const int row = dt * 16 + c;
      const int sw = c & 7;
#pragma unroll
      for (int kb = 0; kb < 2; ++kb) {
        short4v va = *(const short4v*)&v_l[buf][row][(((kb * 4 + 0) + (g >> 1)) ^ sw) * 8 + (g & 1) * 4];
        short4v vb = *(const short4v*)&v_l[buf][row][(((kb * 4 + 2) + (g >> 1)) ^ sw) * 8 + (g & 1) * 4];
        bf16x8 vf;
        vf[0] = va[0]; vf[1] = va[1]; vf[2] = va[2]; vf[3] = va[3];
        vf[4] = vb[0]; vf[5] = vb[1]; vf[6] = vb[2]; vf[7] = vb[3];
#pragma unroll
        for (int qt = 0; qt < 2; ++qt) {
          union { uint32_t u[4]; bf16x8 v; } pu;
          pu.u[0] = pw[qt][2 * kb][0];
          pu.u[1] = pw[qt][2 * kb][1];
          pu.u[2] = pw[qt][2 * kb + 1][0];
          pu.u[3] = pw[qt][2 * kb + 1][1];
          accO[qt][dt] = __builtin_amdgcn_mfma_f32_16x16x32_bf16(vf, pu.v, accO[qt][dt], 0, 0, 0);
        }
      }
    }
    buf ^= 1;
  }

  // ---- epilogue: O^T[dd][q] -> AO [bn*64+dd][q] fp32 ----
#pragma unroll
  for (int qt = 0; qt < 2; ++qt) {
    const float inv = 1.0f / l_r[qt];
    const int qq = q0 + qt * 16 + c;
#pragma unroll
    for (int dt = 0; dt < 4; ++dt)
#pragma unroll
      for (int r = 0; r < 4; ++r) {
        const int dd = dt * 16 + g * 4 + r;
        AO[((size_t)bn * 64 + dd) * HW_ + qq] = accO[qt][dt][r] * inv;
      }
  }
}

// ---------------- SE pooling: avg & max over spatial per (b, ch of 512) ----------------
__global__ __launch_bounds__(256) void pool_kernel(
    const float* __restrict__ proj, const float* __restrict__ gray,
    float* __restrict__ pavg, float* __restrict__ pmax) {
  const int ch = blockIdx.x;
  const int b = blockIdx.y;
  const int t = threadIdx.x;
  const float* src = (ch < 256) ? (proj + ((size_t)b * 256 + ch) * HW_)
                                : (gray + ((size_t)b * 256 + (ch - 256)) * HW_);
  float s = 0.f, mx = -1e30f;
  for (int p = t; p < HW_; p += 256) {
    const float v_ = src[p];
    s += v_;
    mx = fmaxf(mx, v_);
  }
#pragma unroll
  for (int o = 1; o < 64; o <<= 1) {
    s += __shfl_xor(s, o);
    mx = fmaxf(mx, __shfl_xor(mx, o));
  }
  __shared__ float ss[4], sm[4];
  if ((t & 63) == 0) { ss[t >> 6] = s; sm[t >> 6] = mx; }
  __syncthreads();
  if (t == 0) {
    const float S = ss[0] + ss[1] + ss[2] + ss[3];
    const float M = fmaxf(fmaxf(sm[0], sm[1]), fmaxf(sm[2], sm[3]));
    pavg[b * 512 + ch] = S * (1.f / 4096.f);
    pmax[b * 512 + ch] = M;
  }
}

// ---------------- SE MLP: wch = sigmoid(mlp(avg)+mlp(max)) ----------------
__global__ __launch_bounds__(256) void se_kernel(
    const float* __restrict__ pavg, const float* __restrict__ pmax,
    const float* __restrict__ w1, const float* __restrict__ w2,
    float* __restrict__ wch) {
  const int b = blockIdx.x;
  const int t = threadIdx.x;
  __shared__ float za[512], zm[512], hs[64];
  za[t] = pavg[b * 512 + t];
  za[256 + t] = pavg[b * 512 + 256 + t];
  zm[t] = pmax[b * 512 + t];
  zm[256 + t] = pmax[b * 512 + 256 + t];
  __syncthreads();
  if (t < 64) {
    float ha = 0.f, hm = 0.f;
    for (int c = 0; c < 512; ++c) {
      const float w = w1[t * 512 + c];
      ha += w * za[c];
      hm += w * zm[c];
    }
    hs[t] = fmaxf(ha, 0.f) + fmaxf(hm, 0.f);
  }
  __syncthreads();
  for (int o = t; o < 512; o += 256) {
    float acc = 0.f;
#pragma unroll
    for (int hh = 0; hh < 64; ++hh) acc += hs[hh] * w2[o * 64 + hh];
    wch[b * 512 + o] = 1.f / (1.f + __expf(-acc));
  }
}

// ---------------- spatial-attention input ----------------
__global__ __launch_bounds__(256) void sa_reduce_kernel(
    const float* __restrict__ proj, const float* __restrict__ gray,
    const float* __restrict__ wch, float* __restrict__ sa_in) {
  const int b = blockIdx.y;
  const int p = blockIdx.x * 256 + threadIdx.x;
  __shared__ float wl[512];
  wl[threadIdx.x] = wch[b * 512 + threadIdx.x];
  wl[256 + threadIdx.x] = wch[b * 512 + 256 + threadIdx.x];
  __syncthreads();
  const float* pb = proj + (size_t)b * 256 * HW_;
  const float* gb = gray + (size_t)b * 256 * HW_;
  float s = 0.f, mx = -1e30f;
  for (int ch = 0; ch < 256; ++ch) {
    const float v_ = pb[(size_t)ch * HW_ + p] * wl[ch];
    s += v_;
    mx = fmaxf(mx, v_);
  }
  for (int ch = 0; ch < 256; ++ch) {
    const float v_ = gb[(size_t)ch * HW_ + p] * wl[256 + ch];
    s += v_;
    mx = fmaxf(mx, v_);
  }
  sa_in[((size_t)b * 2 + 0) * HW_ + p] = s * (1.f / 512.f);
  sa_in[((size_t)b * 2 + 1) * HW_ + p] = mx;
}

// ---------------- 7x7 spatial conv + sigmoid -> wsp ----------------
__global__ __launch_bounds__(256) void sa_conv_kernel(
    const float* __restrict__ sa_in, const float* __restrict__ sa_w,
    float* __restrict__ wsp) {
  const int b = blockIdx.y;
  const int t = threadIdx.x;
  __shared__ float pl[2][64][64];
  __shared__ float wl[98];
  for (int e = t; e < 8192; e += 256) ((float*)pl)[e] = sa_in[(size_t)b * 8192 + e];
  if (t < 98) wl[t] = sa_w[t];
  __syncthreads();
  const int pix = blockIdx.x * 256 + t;
  const int y = pix >> 6, x = pix & 63;
  float acc = 0.f;
#pragma unroll
  for (int ic = 0; ic < 2; ++ic)
#pragma unroll
    for (int ky = 0; ky < 7; ++ky) {
      const int yy = y + ky - 3;
      if (yy < 0 || yy > 63) continue;
#pragma unroll
      for (int kx = 0; kx < 7; ++kx) {
        const int xx = x + kx - 3;
        if (xx < 0 || xx > 63) continue;
        acc += pl[ic][yy][xx] * wl[ic * 49 + ky * 7 + kx];
      }
    }
  wsp[(size_t)b * HW_ + pix] = 1.f / (1.f + __expf(-acc));
}

// ---------------- fuse: 3x3 conv + BN + LeakyReLU ----------------
__global__ __launch_bounds__(128) void fuse_kernel(
    const float* __restrict__ proj, const float* __restrict__ gray,
    const float* __restrict__ wch, const float* __restrict__ wsp,
    const float* __restrict__ fw, const float* __restrict__ bn_g,
    const float* __restrict__ bn_b, const float* __restrict__ bn_m,
    const float* __restrict__ bn_v, float* __restrict__ out) {
  __shared__ float cg[8][3][68];
  __shared__ float wl[8][3][3][64];
  __shared__ float wchl[512];
  __shared__ float wspl[3][66];
  const int t = threadIdx.x;
  const int y = blockIdx.x;
  const int o0 = blockIdx.y * 64;
  const int b = blockIdx.z;
  const int oc0 = (t >> 3) * 4;
  const int x0 = (t & 7) * 8;

  for (int e = t; e < 512; e += 128) wchl[e] = wch[b * 512 + e];
  for (int e = t; e < 198; e += 128) {
    const int r = e / 66;
    const int xi = e % 66;
    const int xx = xi - 1;
    const int yy = y + r - 1;
    float vw = 0.f;
    if (yy >= 0 && yy < 64 && xx >= 0 && xx < 64) vw = wsp[(size_t)b * HW_ + yy * 64 + xx];
    wspl[r][xi] = vw;
  }

  const float* pb = proj + (size_t)b * 256 * HW_;
  const float* gb = gray + (size_t)b * 256 * HW_;
  float acc[4][8] = {};

  for (int ic0 = 0; ic0 < 512; ic0 += 8) {
    __syncthreads();
    for (int e = t; e < 1584; e += 128) {
      const int ic = e / 198;
      const int rr = e % 198;
      const int r = rr / 66;
      const int xi = rr % 66;
      const int xx = xi - 1;
      const int yy = y + r - 1;
      const int ch = ic0 + ic;
      float val = 0.f;
      if (yy >= 0 && yy < 64 && xx >= 0 && xx < 64) {
        const float sv = (ch < 256) ? pb[(size_t)ch * HW_ + yy * 64 + xx]
                                    : gb[(size_t)(ch - 256) * HW_ + yy * 64 + xx];
        val = sv * wchl[ch] * wspl[r][xi];
      }
      cg[ic][r][xi] = val;
    }
    for (int e4 = t * 4; e4 < 4608; e4 += 512) {
      const int oc = e4 / 72;
      const int r = e4 % 72;
      float4 wv = *(const float4*)&fw[(size_t)(o0 + oc) * 4608 + (size_t)ic0 * 9 + r];
      const float wa[4] = {wv.x, wv.y, wv.z, wv.w};
#pragma unroll
      for (int u = 0; u < 4; ++u) {
        const int rr = r + u;
        wl[rr / 9][(rr % 9) / 3][rr % 3][oc] = wa[u];
      }
    }
    __syncthreads();
    for (int ic = 0; ic < 8; ++ic) {
#pragma unroll
      for (int ky = 0; ky < 3; ++ky) {
        float xv[10];
        float4 a0 = *(const float4*)&cg[ic][ky][x0];
        float4 a1 = *(const float4*)&cg[ic][ky][x0 + 4];
        float2 a2 = *(const float2*)&cg[ic][ky][x0 + 8];
        xv[0] = a0.x; xv[1] = a0.y; xv[2] = a0.z; xv[3] = a0.w;
        xv[4] = a1.x; xv[5] = a1.y; xv[6] = a1.z; xv[7] = a1.w;
        xv[8] = a2.x; xv[9] = a2.y;
#pragma unroll
        for (int kx = 0; kx < 3; ++kx) {
          float4 wv = *(const float4*)&wl[ic][ky][kx][oc0];
          const float wa[4] = {wv.x, wv.y, wv.z, wv.w};
#pragma unroll
          for (int oi = 0; oi < 4; ++oi)
#pragma unroll
            for (int xj = 0; xj < 8; ++xj) acc[oi][xj] += wa[oi] * xv[xj + kx];
        }
      }
    }
  }

#pragma unroll
  for (int oi = 0; oi < 4; ++oi) {
    const int oc = o0 + oc0 + oi;
    const float inv = bn_g[oc] * rsqrtf(bn_v[oc] + 1e-5f);
    const float mu = bn_m[oc];
    const float bb = bn_b[oc];
    float vals[8];
#pragma unroll
    for (int xj = 0; xj < 8; ++xj) {
      const float yv = (acc[oi][xj] - mu) * inv + bb;
      vals[xj] = yv > 0.f ? yv : 0.2f * yv;
    }
    float4 r0 = {vals[0], vals[1], vals[2], vals[3]};
    float4 r1 = {vals[4], vals[5], vals[6], vals[7]};
    float* op = out + ((size_t)(b * 256 + oc)) * HW_ + y * 64 + x0;
    *(float4*)&op[0] = r0;
    *(float4*)&op[4] = r1;
  }
}

extern "C" void kernel_launch(void* const* d_in, const int* in_sizes, int n_in,
                              void* d_out, int out_size, void* d_ws, size_t ws_size,
                              hipStream_t stream) {
  const float* color  = (const float*)d_in[0];
  const float* gray   = (const float*)d_in[1];
  const float* Wq     = (const float*)d_in[2];
  const float* Wk     = (const float*)d_in[3];
  const float* Wv     = (const float*)d_in[4];
  const float* Wproj  = (const float*)d_in[5];
  const float* ca_w1  = (const float*)d_in[6];
  const float* ca_w2  = (const float*)d_in[7];
  const float* sa_w   = (const float*)d_in[8];
  const float* fuse_w = (const float*)d_in[9];
  const float* bn_g   = (const float*)d_in[10];
  const float* bn_b   = (const float*)d_in[11];
  const float* bn_m   = (const float*)d_in[12];
  const float* bn_v   = (const float*)d_in[13];
  float* out = (float*)d_out;

  char* ws = (char*)d_ws;
  // [0,16MB): Qbf(8MB) + Kbf(8MB); proj fp32 (16MB) overlays after attention.
  unsigned short* Qbf = (unsigned short*)(ws);
  unsigned short* Kbf = (unsigned short*)(ws + (8u << 20));
  float* proj         = (float*)(ws);
  float* ao           = (float*)(ws + (16u << 20));   // 16MB fp32
  unsigned short* Vbf = (unsigned short*)(ws + (32u << 20));  // 8MB
  float* pavg  = (float*)(ws + (40u << 20));
  float* pmax  = pavg + 2048;
  float* wch   = pmax + 2048;
  float* sa_in = wch + 2048;     // 32768
  float* wsp   = sa_in + 32768;  // 16384
  (void)in_sizes; (void)n_in; (void)out_size; (void)ws_size;

  const float qscale = 0.125f * 1.44269504f;  // fold softmax scale + log2(e) into Q

  dim3 g_gemm(64, 4, 4);
  gemm256_kernel<<<g_gemm, 256, 0, stream>>>(color, Wq, Qbf, 1, qscale);
  gemm256_kernel<<<g_gemm, 256, 0, stream>>>(gray, Wk, Kbf, 1, 1.0f);
  gemm256_kernel<<<g_gemm, 256, 0, stream>>>(gray, Wv, Vbf, 2, 1.0f);
  attn_mfma_kernel<<<dim3(32, 16), 256, 0, stream>>>(Qbf, Kbf, Vbf, ao);
  gemm256_kernel<<<g_gemm, 256, 0, stream>>>(ao, Wproj, proj, 0, 1.0f);
  pool_kernel<<<dim3(512, 4), 256, 0, stream>>>(proj, gray, pavg, pmax);
  se_kernel<<<dim3(4), 256, 0, stream>>>(pavg, pmax, ca_w1, ca_w2, wch);
  sa_reduce_kernel<<<dim3(16, 4), 256, 0, stream>>>(proj, gray, wch, sa_in);
  sa_conv_kernel<<<dim3(16, 4), 256, 0, stream>>>(sa_in, sa_w, wsp);
  fuse_kernel<<<dim3(64, 4, 4), 128, 0, stream>>>(proj, gray, wch, wsp, fuse_w,
                                                  bn_g, bn_b, bn_m, bn_v, out);
}

// Round 3
// 444.056 us; speedup vs baseline: 4.8296x; 2.6400x over previous
//
#include <hip/hip_runtime.h>
#include <hip/hip_bf16.h>
#include <stdint.h>

#define HW_ 4096

typedef short bf16x8 __attribute__((ext_vector_type(8)));
typedef short short4v __attribute__((ext_vector_type(4)));
typedef short short8v __attribute__((ext_vector_type(8)));
typedef float f32x4 __attribute__((ext_vector_type(4)));
typedef float f32x16 __attribute__((ext_vector_type(16)));

__device__ inline unsigned short f2bf(float x) {
  uint32_t u = __builtin_bit_cast(uint32_t, x);
  uint32_t r = ((u >> 16) & 1u) + 0x7fffu;
  return (unsigned short)((u + r) >> 16);
}
__device__ inline uint32_t pack2bf(float lo, float hi) {
  return (uint32_t)f2bf(lo) | ((uint32_t)f2bf(hi) << 16);
}
__device__ inline void gld_lds16(const unsigned short* g, unsigned short* l) {
  __builtin_amdgcn_global_load_lds((const __attribute__((address_space(1))) void*)g,
                                   (__attribute__((address_space(3))) void*)l, 16, 0, 0);
}

// ---------------- GEMM: Y[b][o][p] = sum_c W[o][c] * X[b][c][p] ----------------
// mode 0: fp32 [b][c][p]. mode 1: bf16 [b*4+n][p][dd] (*oscale). mode 2: bf16 [b][c][p].
__global__ __launch_bounds__(256) void gemm256_kernel(
    const float* __restrict__ X, const float* __restrict__ W, void* __restrict__ Yv,
    int mode, float oscale) {
  __shared__ float Xs[16][64];
  __shared__ float Ws[16][64];
  const int t = threadIdx.x;
  const int p0 = blockIdx.x * 64;
  const int o0 = blockIdx.y * 64;
  const int b = blockIdx.z;
  const float* Xb = X + (size_t)b * 256 * HW_;
  const int tp0 = (t & 15) * 4;
  const int to0 = (t >> 4) * 4;
  float acc[4][4] = {};
  for (int c0 = 0; c0 < 256; c0 += 16) {
    {
      const int cc = t >> 4;
      const int pp = (t & 15) * 4;
      *(float4*)&Xs[cc][pp] = *(const float4*)&Xb[(size_t)(c0 + cc) * HW_ + p0 + pp];
      const int oo = t >> 2;
      const int c4 = (t & 3) * 4;
      float4 wv = *(const float4*)&W[(size_t)(o0 + oo) * 256 + c0 + c4];
      Ws[c4 + 0][oo] = wv.x;
      Ws[c4 + 1][oo] = wv.y;
      Ws[c4 + 2][oo] = wv.z;
      Ws[c4 + 3][oo] = wv.w;
    }
    __syncthreads();
#pragma unroll
    for (int cc = 0; cc < 16; ++cc) {
      float4 xv = *(const float4*)&Xs[cc][tp0];
      float4 wv = *(const float4*)&Ws[cc][to0];
      const float xa[4] = {xv.x, xv.y, xv.z, xv.w};
      const float wa[4] = {wv.x, wv.y, wv.z, wv.w};
#pragma unroll
      for (int i = 0; i < 4; ++i)
#pragma unroll
        for (int j = 0; j < 4; ++j) acc[i][j] += wa[i] * xa[j];
    }
    __syncthreads();
  }
  if (mode == 0) {
    float* Y = (float*)Yv;
#pragma unroll
    for (int i = 0; i < 4; ++i) {
      float4 ov = {acc[i][0], acc[i][1], acc[i][2], acc[i][3]};
      *(float4*)&Y[((size_t)b * 256 + o0 + to0 + i) * HW_ + p0 + tp0] = ov;
    }
  } else if (mode == 1) {
    unsigned short* Y = (unsigned short*)Yv;
    const size_t bn = (size_t)b * 4 + (o0 >> 6);
#pragma unroll
    for (int j = 0; j < 4; ++j) {
      ushort4 ov;
      ov.x = f2bf(acc[0][j] * oscale);
      ov.y = f2bf(acc[1][j] * oscale);
      ov.z = f2bf(acc[2][j] * oscale);
      ov.w = f2bf(acc[3][j] * oscale);
      *(ushort4*)&Y[(bn * HW_ + p0 + tp0 + j) * 64 + to0] = ov;
    }
  } else {
    unsigned short* Y = (unsigned short*)Yv;
#pragma unroll
    for (int i = 0; i < 4; ++i) {
      ushort4 ov;
      ov.x = f2bf(acc[i][0]);
      ov.y = f2bf(acc[i][1]);
      ov.z = f2bf(acc[i][2]);
      ov.w = f2bf(acc[i][3]);
      *(ushort4*)&Y[((size_t)b * 256 + o0 + to0 + i) * HW_ + p0 + tp0] = ov;
    }
  }
}

// ---------------- MFMA flash attention (unchanged from round 2) ----------------
__global__ __launch_bounds__(256) void attn_mfma_kernel(
    const unsigned short* __restrict__ Qb, const unsigned short* __restrict__ Kb,
    const unsigned short* __restrict__ Vb, float* __restrict__ AO) {
  __shared__ unsigned short k_l[2][64][64];
  __shared__ unsigned short v_l[2][64][64];
  const int t = threadIdx.x;
  const int w = t >> 6;
  const int l = t & 63;
  const int g = l >> 4;
  const int c = l & 15;
  const int bn = blockIdx.y;
  const int q0 = blockIdx.x * 128 + w * 32;

  bf16x8 qf[2][2];
#pragma unroll
  for (int qt = 0; qt < 2; ++qt)
#pragma unroll
    for (int dh = 0; dh < 2; ++dh)
      qf[qt][dh] = *(const bf16x8*)&Qb[((size_t)bn * HW_ + q0 + qt * 16 + c) * 64 + dh * 32 + g * 8];

  const int srow = 16 * w + (l >> 3);
  const int schunk = (l & 7) ^ ((l >> 3) & 7);
  const unsigned short* gK = Kb + ((size_t)bn * HW_ + srow) * 64 + schunk * 8;
  const unsigned short* gV = Vb + ((size_t)bn * 64 + srow) * HW_ + schunk * 8;

  f32x4 accO[2][4] = {};
  float m_r[2] = {-1e30f, -1e30f};
  float l_r[2] = {0.f, 0.f};

#pragma unroll
  for (int h = 0; h < 2; ++h) {
    gld_lds16(gK + (size_t)(8 * h) * 64, &k_l[0][16 * w + 8 * h][0]);
    gld_lds16(gV + (size_t)(8 * h) * HW_, &v_l[0][16 * w + 8 * h][0]);
  }

  int buf = 0;
  for (int kt = 0; kt < 64; ++kt) {
    asm volatile("s_waitcnt vmcnt(0)" ::: "memory");
    __syncthreads();
    if (kt < 63) {
      const int j0 = (kt + 1) * 64;
#pragma unroll
      for (int h = 0; h < 2; ++h) {
        gld_lds16(gK + ((size_t)j0 + 8 * h) * 64, &k_l[buf ^ 1][16 * w + 8 * h][0]);
        gld_lds16(gV + (size_t)(8 * h) * HW_ + j0, &v_l[buf ^ 1][16 * w + 8 * h][0]);
      }
    }

    f32x4 accS[2][4] = {};
#pragma unroll
    for (int jt = 0; jt < 4; ++jt) {
      const int jrow = jt * 16 + c;
      bf16x8 kf0 = *(const bf16x8*)&k_l[buf][jrow][((0 * 4 + g) ^ (c & 7)) * 8];
      bf16x8 kf1 = *(const bf16x8*)&k_l[buf][jrow][((1 * 4 + g) ^ (c & 7)) * 8];
#pragma unroll
      for (int qt = 0; qt < 2; ++qt) {
        accS[qt][jt] = __builtin_amdgcn_mfma_f32_16x16x32_bf16(kf0, qf[qt][0], accS[qt][jt], 0, 0, 0);
        accS[qt][jt] = __builtin_amdgcn_mfma_f32_16x16x32_bf16(kf1, qf[qt][1], accS[qt][jt], 0, 0, 0);
      }
    }

    uint32_t pw[2][4][2];
#pragma unroll
    for (int qt = 0; qt < 2; ++qt) {
      float mx = accS[qt][0][0];
#pragma unroll
      for (int jt = 0; jt < 4; ++jt)
#pragma unroll
        for (int r = 0; r < 4; ++r) mx = fmaxf(mx, accS[qt][jt][r]);
      mx = fmaxf(mx, __shfl_xor(mx, 16));
      mx = fmaxf(mx, __shfl_xor(mx, 32));
      const float m_new = fmaxf(m_r[qt], mx);
      const float corr = __builtin_amdgcn_exp2f(m_r[qt] - m_new);
      m_r[qt] = m_new;
      float rs = 0.f;
#pragma unroll
      for (int jt = 0; jt < 4; ++jt) {
        float e0 = __builtin_amdgcn_exp2f(accS[qt][jt][0] - m_new);
        float e1 = __builtin_amdgcn_exp2f(accS[qt][jt][1] - m_new);
        float e2 = __builtin_amdgcn_exp2f(accS[qt][jt][2] - m_new);
        float e3 = __builtin_amdgcn_exp2f(accS[qt][jt][3] - m_new);
        rs += (e0 + e1) + (e2 + e3);
        pw[qt][jt][0] = pack2bf(e0, e1);
        pw[qt][jt][1] = pack2bf(e2, e3);
      }
      rs += __shfl_xor(rs, 16);
      rs += __shfl_xor(rs, 32);
      l_r[qt] = l_r[qt] * corr + rs;
#pragma unroll
      for (int dt = 0; dt < 4; ++dt)
#pragma unroll
        for (int r = 0; r < 4; ++r) accO[qt][dt][r] *= corr;
    }

#pragma unroll
    for (int dt = 0; dt < 4; ++dt) {
      const int row = dt * 16 + c;
      const int sw = c & 7;
#pragma unroll
      for (int kb = 0; kb < 2; ++kb) {
        short4v va = *(const short4v*)&v_l[buf][row][(((kb * 4 + 0) + (g >> 1)) ^ sw) * 8 + (g & 1) * 4];
        short4v vb = *(const short4v*)&v_l[buf][row][(((kb * 4 + 2) + (g >> 1)) ^ sw) * 8 + (g & 1) * 4];
        bf16x8 vf;
        vf[0] = va[0]; vf[1] = va[1]; vf[2] = va[2]; vf[3] = va[3];
        vf[4] = vb[0]; vf[5] = vb[1]; vf[6] = vb[2]; vf[7] = vb[3];
#pragma unroll
        for (int qt = 0; qt < 2; ++qt) {
          union { uint32_t u[4]; bf16x8 v; } pu;
          pu.u[0] = pw[qt][2 * kb][0];
          pu.u[1] = pw[qt][2 * kb][1];
          pu.u[2] = pw[qt][2 * kb + 1][0];
          pu.u[3] = pw[qt][2 * kb + 1][1];
          accO[qt][dt] = __builtin_amdgcn_mfma_f32_16x16x32_bf16(vf, pu.v, accO[qt][dt], 0, 0, 0);
        }
      }
    }
    buf ^= 1;
  }

#pragma unroll
  for (int qt = 0; qt < 2; ++qt) {
    const float inv = 1.0f / l_r[qt];
    const int qq = q0 + qt * 16 + c;
#pragma unroll
    for (int dt = 0; dt < 4; ++dt)
#pragma unroll
      for (int r = 0; r < 4; ++r) {
        const int dd = dt * 16 + g * 4 + r;
        AO[((size_t)bn * 64 + dd) * HW_ + qq] = accO[qt][dt][r] * inv;
      }
  }
}

// ---------------- SE pooling ----------------
__global__ __launch_bounds__(256) void pool_kernel(
    const float* __restrict__ proj, const float* __restrict__ gray,
    float* __restrict__ pavg, float* __restrict__ pmax) {
  const int ch = blockIdx.x;
  const int b = blockIdx.y;
  const int t = threadIdx.x;
  const float* src = (ch < 256) ? (proj + ((size_t)b * 256 + ch) * HW_)
                                : (gray + ((size_t)b * 256 + (ch - 256)) * HW_);
  float s = 0.f, mx = -1e30f;
  for (int p = t; p < HW_; p += 256) {
    const float v_ = src[p];
    s += v_;
    mx = fmaxf(mx, v_);
  }
#pragma unroll
  for (int o = 1; o < 64; o <<= 1) {
    s += __shfl_xor(s, o);
    mx = fmaxf(mx, __shfl_xor(mx, o));
  }
  __shared__ float ss[4], sm[4];
  if ((t & 63) == 0) { ss[t >> 6] = s; sm[t >> 6] = mx; }
  __syncthreads();
  if (t == 0) {
    const float S = ss[0] + ss[1] + ss[2] + ss[3];
    const float M = fmaxf(fmaxf(sm[0], sm[1]), fmaxf(sm[2], sm[3]));
    pavg[b * 512 + ch] = S * (1.f / 4096.f);
    pmax[b * 512 + ch] = M;
  }
}

// ---------------- SE MLP ----------------
__global__ __launch_bounds__(256) void se_kernel(
    const float* __restrict__ pavg, const float* __restrict__ pmax,
    const float* __restrict__ w1, const float* __restrict__ w2,
    float* __restrict__ wch) {
  const int b = blockIdx.x;
  const int t = threadIdx.x;
  __shared__ float za[512], zm[512], hs[64];
  za[t] = pavg[b * 512 + t];
  za[256 + t] = pavg[b * 512 + 256 + t];
  zm[t] = pmax[b * 512 + t];
  zm[256 + t] = pmax[b * 512 + 256 + t];
  __syncthreads();
  if (t < 64) {
    float ha = 0.f, hm = 0.f;
    for (int c = 0; c < 512; ++c) {
      const float w = w1[t * 512 + c];
      ha += w * za[c];
      hm += w * zm[c];
    }
    hs[t] = fmaxf(ha, 0.f) + fmaxf(hm, 0.f);
  }
  __syncthreads();
  for (int o = t; o < 512; o += 256) {
    float acc = 0.f;
#pragma unroll
    for (int hh = 0; hh < 64; ++hh) acc += hs[hh] * w2[o * 64 + hh];
    wch[b * 512 + o] = 1.f / (1.f + __expf(-acc));
  }
}

// ---------------- spatial-attention input ----------------
__global__ __launch_bounds__(256) void sa_reduce_kernel(
    const float* __restrict__ proj, const float* __restrict__ gray,
    const float* __restrict__ wch, float* __restrict__ sa_in) {
  const int b = blockIdx.y;
  const int p = blockIdx.x * 256 + threadIdx.x;
  __shared__ float wl[512];
  wl[threadIdx.x] = wch[b * 512 + threadIdx.x];
  wl[256 + threadIdx.x] = wch[b * 512 + 256 + threadIdx.x];
  __syncthreads();
  const float* pb = proj + (size_t)b * 256 * HW_;
  const float* gb = gray + (size_t)b * 256 * HW_;
  float s = 0.f, mx = -1e30f;
  for (int ch = 0; ch < 256; ++ch) {
    const float v_ = pb[(size_t)ch * HW_ + p] * wl[ch];
    s += v_;
    mx = fmaxf(mx, v_);
  }
  for (int ch = 0; ch < 256; ++ch) {
    const float v_ = gb[(size_t)ch * HW_ + p] * wl[256 + ch];
    s += v_;
    mx = fmaxf(mx, v_);
  }
  sa_in[((size_t)b * 2 + 0) * HW_ + p] = s * (1.f / 512.f);
  sa_in[((size_t)b * 2 + 1) * HW_ + p] = mx;
}

// ---------------- 7x7 spatial conv + sigmoid -> wsp ----------------
__global__ __launch_bounds__(256) void sa_conv_kernel(
    const float* __restrict__ sa_in, const float* __restrict__ sa_w,
    float* __restrict__ wsp) {
  const int b = blockIdx.y;
  const int t = threadIdx.x;
  __shared__ float pl[2][64][64];
  __shared__ float wl[98];
  for (int e = t; e < 8192; e += 256) ((float*)pl)[e] = sa_in[(size_t)b * 8192 + e];
  if (t < 98) wl[t] = sa_w[t];
  __syncthreads();
  const int pix = blockIdx.x * 256 + t;
  const int y = pix >> 6, x = pix & 63;
  float acc = 0.f;
#pragma unroll
  for (int ic = 0; ic < 2; ++ic)
#pragma unroll
    for (int ky = 0; ky < 7; ++ky) {
      const int yy = y + ky - 3;
      if (yy < 0 || yy > 63) continue;
#pragma unroll
      for (int kx = 0; kx < 7; ++kx) {
        const int xx = x + kx - 3;
        if (xx < 0 || xx > 63) continue;
        acc += pl[ic][yy][xx] * wl[ic * 49 + ky * 7 + kx];
      }
    }
  wsp[(size_t)b * HW_ + pix] = 1.f / (1.f + __expf(-acc));
}

// ---------------- gate: catg[b][yp:66][xi:80][ic:512] bf16 = cat*wch*wsp, halo=0 ----------------
__global__ __launch_bounds__(256) void gate_kernel(
    const float* __restrict__ proj, const float* __restrict__ gray,
    const float* __restrict__ wch, const float* __restrict__ wsp,
    unsigned short* __restrict__ catg) {
  const int yp = blockIdx.x;  // 0..65
  const int b = blockIdx.y;
  const int t = threadIdx.x;
  unsigned short* rowp = catg + ((size_t)b * 66 + yp) * 80 * 512;
  if (yp == 0 || yp == 65) {
    short8v z = {};
    for (int m = t; m < 5120; m += 256) *(short8v*)&rowp[m * 8] = z;
    return;
  }
  const int y = yp - 1;
  __shared__ unsigned short tile[64][136];
  __shared__ float wchl[512];
  __shared__ float wspl[64];
  for (int e = t; e < 512; e += 256) wchl[e] = wch[b * 512 + e];
  if (t < 64) wspl[t] = wsp[(size_t)b * HW_ + y * 64 + t];
  {
    short8v z = {};
    for (int m = t; m < 1024; m += 256) {
      const int col = m >> 6;
      const int xi = (col < 8) ? col : (col + 64);
      const int c8 = m & 63;
      *(short8v*)&rowp[xi * 512 + c8 * 8] = z;
    }
  }
  const float* pb = proj + (size_t)b * 256 * HW_;
  const float* gb = gray + (size_t)b * 256 * HW_;
  const int x = t & 63;
  const int cg = t >> 6;
  for (int ct = 0; ct < 4; ++ct) {
    __syncthreads();
    for (int r = 0; r < 32; ++r) {
      const int ch = ct * 128 + cg * 32 + r;
      const float sv = (ch < 256) ? pb[(size_t)ch * HW_ + y * 64 + x]
                                  : gb[(size_t)(ch - 256) * HW_ + y * 64 + x];
      tile[x][cg * 32 + r] = f2bf(sv * wchl[ch] * wspl[x]);
    }
    __syncthreads();
    const int c8t = t & 15;
    const int xg = t >> 4;
#pragma unroll
    for (int p = 0; p < 4; ++p) {
      const int xx = xg * 4 + p;
      short8v v8 = *(const short8v*)&tile[xx][c8t * 8];
      *(short8v*)&rowp[(size_t)(xx + 8) * 512 + ct * 128 + c8t * 8] = v8;
    }
  }
}

// ---------------- weight transform: fuse_w fp32 [oc][ic][3][3] -> bf16 [tap][oc][ic] ----------------
__global__ __launch_bounds__(256) void wtrans_kernel(
    const float* __restrict__ fw, unsigned short* __restrict__ wt) {
  const size_t i = (size_t)blockIdx.x * 256 + threadIdx.x;  // over 256*512
  const int oc = (int)(i >> 9);
  const int ic = (int)(i & 511);
  const float* src = fw + i * 9;
#pragma unroll
  for (int tap = 0; tap < 9; ++tap)
    wt[((size_t)tap * 256 + oc) * 512 + ic] = f2bf(src[tap]);
}

// ---------------- fuse conv via MFMA: out = BN(LeakyReLU) of conv3x3(catg) ----------------
// block: 64 oc x (4 y-rows x 64 x), 4 waves (one y-row each, 2x2 frags of 32x32x16)
__global__ __launch_bounds__(256) void fuse_mfma_kernel(
    const unsigned short* __restrict__ catg, const unsigned short* __restrict__ wt,
    const float* __restrict__ bn_g, const float* __restrict__ bn_b,
    const float* __restrict__ bn_m, const float* __restrict__ bn_v,
    float* __restrict__ out) {
  __shared__ unsigned short X_l[2][6][2][80][8];  // [buf][row][ichalf][xi][ic8]
  __shared__ unsigned short W_l[2][9][2][64][8];  // [buf][tap][ichalf][oc][ic8]
  __shared__ float invl[64], shl[64];
  const int t = threadIdx.x;
  const int w = t >> 6;
  const int l = t & 63;
  const int n = l & 31;
  const int g = l >> 5;
  const int y0 = blockIdx.x * 4;
  const int o0 = blockIdx.y * 64;
  const int b = blockIdx.z;

  if (t < 64) {
    const float iv = bn_g[o0 + t] * rsqrtf(bn_v[o0 + t] + 1e-5f);
    invl[t] = iv;
    shl[t] = bn_b[o0 + t] - bn_m[o0 + t] * iv;
  }

  const unsigned short* catb = catg + ((size_t)b * 66 + y0) * 80 * 512;

  auto stageX = [&](int bi, int ic0) {
    for (int wc = w; wc < 15; wc += 4) {
      const int m = wc * 64 + l;
      const int lr = m / 160;
      const int rem = m - lr * 160;
      const int half = rem / 80;
      const int xi = rem - half * 80;
      gld_lds16(catb + ((size_t)lr * 80 + xi) * 512 + ic0 + half * 8,
                &X_l[bi][0][0][0][0] + (size_t)wc * 512);
    }
  };
  auto stageW = [&](int bi, int ic0) {
    for (int wc = w; wc < 18; wc += 4) {
      const int m = wc * 64 + l;
      const int tap = m >> 7;
      const int rem = m & 127;
      const int half = rem >> 6;
      const int oc = rem & 63;
      gld_lds16(wt + ((size_t)tap * 256 + o0 + oc) * 512 + ic0 + half * 8,
                &W_l[bi][0][0][0][0] + (size_t)wc * 512);
    }
  };

  f32x16 acc[2][2] = {};

  stageX(0, 0);
  stageW(0, 0);
  int buf = 0;
  for (int ks = 0; ks < 32; ++ks) {
    asm volatile("s_waitcnt vmcnt(0)" ::: "memory");
    __syncthreads();
    if (ks < 31) {
      stageX(buf ^ 1, (ks + 1) * 16);
      stageW(buf ^ 1, (ks + 1) * 16);
    }
#pragma unroll
    for (int ky = 0; ky < 3; ++ky) {
      const int lr = w + ky;
#pragma unroll
      for (int kx = 0; kx < 3; ++kx) {
        const int tap = ky * 3 + kx;
        bf16x8 a0 = *(const bf16x8*)&W_l[buf][tap][g][n][0];
        bf16x8 a1 = *(const bf16x8*)&W_l[buf][tap][g][32 + n][0];
        bf16x8 b0 = *(const bf16x8*)&X_l[buf][lr][g][n + kx + 7][0];
        bf16x8 b1 = *(const bf16x8*)&X_l[buf][lr][g][32 + n + kx + 7][0];
        acc[0][0] = __builtin_amdgcn_mfma_f32_32x32x16_bf16(a0, b0, acc[0][0], 0, 0, 0);
        acc[0][1] = __builtin_amdgcn_mfma_f32_32x32x16_bf16(a0, b1, acc[0][1], 0, 0, 0);
        acc[1][0] = __builtin_amdgcn_mfma_f32_32x32x16_bf16(a1, b0, acc[1][0], 0, 0, 0);
        acc[1][1] = __builtin_amdgcn_mfma_f32_32x32x16_bf16(a1, b1, acc[1][1], 0, 0, 0);
      }
    }
    buf ^= 1;
  }

#pragma unroll
  for (int of = 0; of < 2; ++of)
#pragma unroll
    for (int pf = 0; pf < 2; ++pf)
#pragma unroll
      for (int r = 0; r < 16; ++r) {
        const int row = (r & 3) + 8 * (r >> 2) + 4 * g;
        const int oc = of * 32 + row;
        const float yv = acc[of][pf][r] * invl[oc] + shl[oc];
        const float ov = yv > 0.f ? yv : 0.2f * yv;
        out[((size_t)b * 256 + o0 + oc) * HW_ + (size_t)(y0 + w) * 64 + pf * 32 + n] = ov;
      }
}

extern "C" void kernel_launch(void* const* d_in, const int* in_sizes, int n_in,
                              void* d_out, int out_size, void* d_ws, size_t ws_size,
                              hipStream_t stream) {
  const float* color  = (const float*)d_in[0];
  const float* gray   = (const float*)d_in[1];
  const float* Wq     = (const float*)d_in[2];
  const float* Wk     = (const float*)d_in[3];
  const float* Wv     = (const float*)d_in[4];
  const float* Wproj  = (const float*)d_in[5];
  const float* ca_w1  = (const float*)d_in[6];
  const float* ca_w2  = (const float*)d_in[7];
  const float* sa_w   = (const float*)d_in[8];
  const float* fuse_w = (const float*)d_in[9];
  const float* bn_g   = (const float*)d_in[10];
  const float* bn_b   = (const float*)d_in[11];
  const float* bn_m   = (const float*)d_in[12];
  const float* bn_v   = (const float*)d_in[13];
  float* out = (float*)d_out;

  char* ws = (char*)d_ws;
  // [0,16MB): Qbf+Kbf bf16; proj fp32 overlays after attention.
  unsigned short* Qbf = (unsigned short*)(ws);
  unsigned short* Kbf = (unsigned short*)(ws + (8u << 20));
  float* proj         = (float*)(ws);
  float* ao           = (float*)(ws + (16u << 20));          // 16MB fp32 (dead after proj)
  unsigned short* Vbf = (unsigned short*)(ws + (32u << 20)); // 8MB (dead after attn)
  unsigned short* catg = (unsigned short*)(ws + (16u << 20)); // 21.6MB, overlays ao+Vbf
  unsigned short* Wt  = (unsigned short*)(ws + (40u << 20));  // 2.36MB
  float* pavg  = (float*)(ws + (43u << 20));
  float* pmax  = pavg + 2048;
  float* wch   = pmax + 2048;
  float* sa_in = wch + 2048;     // 32768
  float* wsp   = sa_in + 32768;  // 16384
  (void)in_sizes; (void)n_in; (void)out_size; (void)ws_size;

  const float qscale = 0.125f * 1.44269504f;

  wtrans_kernel<<<dim3(512), 256, 0, stream>>>(fuse_w, Wt);
  dim3 g_gemm(64, 4, 4);
  gemm256_kernel<<<g_gemm, 256, 0, stream>>>(color, Wq, Qbf, 1, qscale);
  gemm256_kernel<<<g_gemm, 256, 0, stream>>>(gray, Wk, Kbf, 1, 1.0f);
  gemm256_kernel<<<g_gemm, 256, 0, stream>>>(gray, Wv, Vbf, 2, 1.0f);
  attn_mfma_kernel<<<dim3(32, 16), 256, 0, stream>>>(Qbf, Kbf, Vbf, ao);
  gemm256_kernel<<<g_gemm, 256, 0, stream>>>(ao, Wproj, proj, 0, 1.0f);
  pool_kernel<<<dim3(512, 4), 256, 0, stream>>>(proj, gray, pavg, pmax);
  se_kernel<<<dim3(4), 256, 0, stream>>>(pavg, pmax, ca_w1, ca_w2, wch);
  sa_reduce_kernel<<<dim3(16, 4), 256, 0, stream>>>(proj, gray, wch, sa_in);
  sa_conv_kernel<<<dim3(16, 4), 256, 0, stream>>>(sa_in, sa_w, wsp);
  gate_kernel<<<dim3(66, 4), 256, 0, stream>>>(proj, gray, wch, wsp, catg);
  fuse_mfma_kernel<<<dim3(16, 4, 4), 256, 0, stream>>>(catg, Wt, bn_g, bn_b, bn_m, bn_v, out);
}

// Round 4
// 350.767 us; speedup vs baseline: 6.1140x; 1.2660x over previous
//
#include <hip/hip_runtime.h>
#include <hip/hip_bf16.h>
#include <stdint.h>

#define HW_ 4096

typedef short bf16x8 __attribute__((ext_vector_type(8)));
typedef short short4v __attribute__((ext_vector_type(4)));
typedef short short8v __attribute__((ext_vector_type(8)));
typedef float f32x4 __attribute__((ext_vector_type(4)));
typedef float f32x16 __attribute__((ext_vector_type(16)));

__device__ inline unsigned short f2bf(float x) {
  uint32_t u = __builtin_bit_cast(uint32_t, x);
  uint32_t r = ((u >> 16) & 1u) + 0x7fffu;
  return (unsigned short)((u + r) >> 16);
}
__device__ inline uint32_t cvt_pk_bf16(float lo, float hi) {
  uint32_t r;
  asm("v_cvt_pk_bf16_f32 %0, %1, %2" : "=v"(r) : "v"(lo), "v"(hi));
  return r;
}
__device__ inline void gld_lds16(const unsigned short* g, unsigned short* l) {
  __builtin_amdgcn_global_load_lds((const __attribute__((address_space(1))) void*)g,
                                   (__attribute__((address_space(3))) void*)l, 16, 0, 0);
}

// ---------------- xconv: fp32 [b][c][p] -> bf16 cgroup layout [(b*32+cg)][p][e] ----------------
__global__ __launch_bounds__(256) void xconv_kernel(
    const float* __restrict__ X, unsigned short* __restrict__ Y) {
  const int i = blockIdx.x * 256 + threadIdx.x;  // 4*32*4096 threads
  const int p = i & 4095;
  const int cg = (i >> 12) & 31;
  const int b = i >> 17;
  const float* src = X + ((size_t)b * 256 + cg * 8) * HW_ + p;
  float v[8];
#pragma unroll
  for (int e = 0; e < 8; ++e) v[e] = src[(size_t)e * HW_];
  uint4 o;
  o.x = cvt_pk_bf16(v[0], v[1]);
  o.y = cvt_pk_bf16(v[2], v[3]);
  o.z = cvt_pk_bf16(v[4], v[5]);
  o.w = cvt_pk_bf16(v[6], v[7]);
  *(uint4*)&Y[((size_t)(b * 32 + cg) * HW_ + p) * 8] = o;
}

// ---------------- wconv: fp32 W[o][c] -> bf16 [cg][o][e] ----------------
__global__ __launch_bounds__(256) void wconv_kernel(
    const float* __restrict__ W, unsigned short* __restrict__ Y) {
  const int i = blockIdx.x * 256 + threadIdx.x;  // 8192
  const int o = i & 255;
  const int cg = i >> 8;
  float4 a = *(const float4*)&W[(size_t)o * 256 + cg * 8];
  float4 bq = *(const float4*)&W[(size_t)o * 256 + cg * 8 + 4];
  uint4 ov;
  ov.x = cvt_pk_bf16(a.x, a.y);
  ov.y = cvt_pk_bf16(a.z, a.w);
  ov.z = cvt_pk_bf16(bq.x, bq.y);
  ov.w = cvt_pk_bf16(bq.z, bq.w);
  *(uint4*)&Y[((size_t)cg * 256 + o) * 8] = ov;
}

// ---------------- MFMA GEMM: Y[o][p] = sum_c W[o][c] X[c][p] ----------------
// Xbf: [(b*32+cg)][p][e], Wbf: [cg][o][e]. Block: 64o x 128p, 4 waves (32o x 64p),
// wave frags 2x of 32x32x16. mode 0: fp32 [b][o][p]; 1: bf16 [b*4+oy][p][dd]*oscale;
// 2: bf16 [b][o][p].
__global__ __launch_bounds__(256) void gemm_mfma_kernel(
    const unsigned short* __restrict__ Xbf, const unsigned short* __restrict__ Wbf,
    void* __restrict__ Yv, int mode, float oscale) {
  __shared__ unsigned short W_l[32][64][8];     // [ks*2+g][oc][e] 32KB, staged once
  __shared__ unsigned short X_l[2][2][128][8];  // [buf][g][p][e] 8KB
  const int t = threadIdx.x;
  const int w = t >> 6;
  const int l = t & 63;
  const int n = l & 31;
  const int g32 = l >> 5;
  const int p0 = blockIdx.x * 128;
  const int o0 = blockIdx.y * 64;
  const int b = blockIdx.z;
  const int wo = w >> 1, wp = w & 1;
  const unsigned short* Xb = Xbf + (size_t)b * 32 * HW_ * 8;

  for (int i = t; i < 2048; i += 256) {
    const int ksg = i >> 6, oc = i & 63;
    gld_lds16(Wbf + ((size_t)ksg * 256 + o0 + oc) * 8, &W_l[0][0][0] + (size_t)i * 8);
  }
  {
    const int gg = t >> 7, pp = t & 127;
    gld_lds16(Xb + ((size_t)gg * HW_ + p0 + pp) * 8, &X_l[0][0][0][0] + (size_t)t * 8);
  }
  f32x16 acc[2] = {};
  int buf = 0;
  for (int ks = 0; ks < 16; ++ks) {
    asm volatile("s_waitcnt vmcnt(0)" ::: "memory");
    __syncthreads();
    if (ks < 15) {
      const int gg = t >> 7, pp = t & 127;
      gld_lds16(Xb + ((size_t)((ks + 1) * 2 + gg) * HW_ + p0 + pp) * 8,
                &X_l[buf ^ 1][0][0][0] + (size_t)t * 8);
    }
    bf16x8 af = *(const bf16x8*)&W_l[ks * 2 + g32][wo * 32 + n][0];
    bf16x8 b0 = *(const bf16x8*)&X_l[buf][g32][wp * 64 + n][0];
    bf16x8 b1 = *(const bf16x8*)&X_l[buf][g32][wp * 64 + 32 + n][0];
    acc[0] = __builtin_amdgcn_mfma_f32_32x32x16_bf16(af, b0, acc[0], 0, 0, 0);
    acc[1] = __builtin_amdgcn_mfma_f32_32x32x16_bf16(af, b1, acc[1], 0, 0, 0);
    buf ^= 1;
  }

  if (mode == 0) {
    float* Y = (float*)Yv;
#pragma unroll
    for (int pf = 0; pf < 2; ++pf) {
      const int p = p0 + wp * 64 + pf * 32 + n;
#pragma unroll
      for (int r = 0; r < 16; ++r) {
        const int m = (r & 3) + 8 * (r >> 2) + 4 * g32;
        Y[((size_t)b * 256 + o0 + wo * 32 + m) * HW_ + p] = acc[pf][r];
      }
    }
  } else if (mode == 1) {
    unsigned short* Y = (unsigned short*)Yv;
    const size_t bh = (size_t)b * 4 + blockIdx.y;
#pragma unroll
    for (int pf = 0; pf < 2; ++pf) {
      const int p = p0 + wp * 64 + pf * 32 + n;
      unsigned short* dst = Y + (bh * HW_ + p) * 64 + wo * 32 + 4 * g32;
#pragma unroll
      for (int q = 0; q < 4; ++q) {
        uint2 uu;
        uu.x = cvt_pk_bf16(acc[pf][q * 4 + 0] * oscale, acc[pf][q * 4 + 1] * oscale);
        uu.y = cvt_pk_bf16(acc[pf][q * 4 + 2] * oscale, acc[pf][q * 4 + 3] * oscale);
        *(uint2*)&dst[8 * q] = uu;
      }
    }
  } else {
    unsigned short* Y = (unsigned short*)Yv;
#pragma unroll
    for (int pf = 0; pf < 2; ++pf) {
      const int p = p0 + wp * 64 + pf * 32 + n;
#pragma unroll
      for (int r = 0; r < 16; ++r) {
        const int m = (r & 3) + 8 * (r >> 2) + 4 * g32;
        Y[((size_t)b * 256 + o0 + wo * 32 + m) * HW_ + p] = f2bf(acc[pf][r]);
      }
    }
  }
}

// ---------------- MFMA flash attention, no-max softmax (|S|<1 by construction) ----------------
// Qb,Kb: bf16 [bn][p][d] (Q pre-scaled by 0.125*log2e). Vb: bf16 [b][c][p].
// Output: bf16 cgroup layout [(b*32+cg)][p][e] for the proj GEMM.
__global__ __launch_bounds__(256) void attn_mfma_kernel(
    const unsigned short* __restrict__ Qb, const unsigned short* __restrict__ Kb,
    const unsigned short* __restrict__ Vb, unsigned short* __restrict__ Abf) {
  __shared__ unsigned short k_l[2][64][64];
  __shared__ unsigned short v_l[2][64][64];
  const int t = threadIdx.x;
  const int w = t >> 6;
  const int l = t & 63;
  const int g = l >> 4;
  const int c = l & 15;
  const int bid = blockIdx.x;
  const int gidx = (bid & 7) * 64 + (bid >> 3);  // XCD-contiguous bn
  const int bn = gidx >> 5;
  const int q0 = (gidx & 31) * 128 + w * 32;

  bf16x8 qf[2][2];
#pragma unroll
  for (int qt = 0; qt < 2; ++qt)
#pragma unroll
    for (int dh = 0; dh < 2; ++dh)
      qf[qt][dh] = *(const bf16x8*)&Qb[((size_t)bn * HW_ + q0 + qt * 16 + c) * 64 + dh * 32 + g * 8];

  const int srow = 16 * w + (l >> 3);
  const int schunk = (l & 7) ^ ((l >> 3) & 7);
  const unsigned short* gK = Kb + ((size_t)bn * HW_ + srow) * 64 + schunk * 8;
  const unsigned short* gV = Vb + ((size_t)bn * 64 + srow) * HW_ + schunk * 8;

  f32x4 accO[2][4] = {};
  float l_r[2] = {0.f, 0.f};

#pragma unroll
  for (int h = 0; h < 2; ++h) {
    gld_lds16(gK + (size_t)(8 * h) * 64, &k_l[0][16 * w + 8 * h][0]);
    gld_lds16(gV + (size_t)(8 * h) * HW_, &v_l[0][16 * w + 8 * h][0]);
  }

  int buf = 0;
  for (int kt = 0; kt < 64; ++kt) {
    asm volatile("s_waitcnt vmcnt(0)" ::: "memory");
    __syncthreads();
    if (kt < 63) {
      const int j0 = (kt + 1) * 64;
#pragma unroll
      for (int h = 0; h < 2; ++h) {
        gld_lds16(gK + ((size_t)j0 + 8 * h) * 64, &k_l[buf ^ 1][16 * w + 8 * h][0]);
        gld_lds16(gV + (size_t)(8 * h) * HW_ + j0, &v_l[buf ^ 1][16 * w + 8 * h][0]);
      }
    }

    // ---- QK^T (swapped: lane owns q-row q0+qt*16+c) ----
    f32x4 accS[2][4] = {};
#pragma unroll
    for (int jt = 0; jt < 4; ++jt) {
      const int jrow = jt * 16 + c;
      bf16x8 kf0 = *(const bf16x8*)&k_l[buf][jrow][((0 * 4 + g) ^ (c & 7)) * 8];
      bf16x8 kf1 = *(const bf16x8*)&k_l[buf][jrow][((1 * 4 + g) ^ (c & 7)) * 8];
#pragma unroll
      for (int qt = 0; qt < 2; ++qt) {
        accS[qt][jt] = __builtin_amdgcn_mfma_f32_16x16x32_bf16(kf0, qf[qt][0], accS[qt][jt], 0, 0, 0);
        accS[qt][jt] = __builtin_amdgcn_mfma_f32_16x16x32_bf16(kf1, qf[qt][1], accS[qt][jt], 0, 0, 0);
      }
    }

    // ---- softmax numerator: exp2 direct (no max), per-lane partial sums ----
    uint32_t pw[2][4][2];
#pragma unroll
    for (int qt = 0; qt < 2; ++qt) {
      float rs = 0.f;
#pragma unroll
      for (int jt = 0; jt < 4; ++jt) {
        const float e0 = __builtin_amdgcn_exp2f(accS[qt][jt][0]);
        const float e1 = __builtin_amdgcn_exp2f(accS[qt][jt][1]);
        const float e2 = __builtin_amdgcn_exp2f(accS[qt][jt][2]);
        const float e3 = __builtin_amdgcn_exp2f(accS[qt][jt][3]);
        rs += (e0 + e1) + (e2 + e3);
        pw[qt][jt][0] = cvt_pk_bf16(e0, e1);
        pw[qt][jt][1] = cvt_pk_bf16(e2, e3);
      }
      l_r[qt] += rs;
    }

    // ---- PV (A = V^T from LDS with permuted-k; B = P packed words in-reg) ----
#pragma unroll
    for (int dt = 0; dt < 4; ++dt) {
      const int row = dt * 16 + c;
      const int sw = c & 7;
#pragma unroll
      for (int kb = 0; kb < 2; ++kb) {
        short4v va = *(const short4v*)&v_l[buf][row][(((kb * 4 + 0) + (g >> 1)) ^ sw) * 8 + (g & 1) * 4];
        short4v vb = *(const short4v*)&v_l[buf][row][(((kb * 4 + 2) + (g >> 1)) ^ sw) * 8 + (g & 1) * 4];
        bf16x8 vf;
        vf[0] = va[0]; vf[1] = va[1]; vf[2] = va[2]; vf[3] = va[3];
        vf[4] = vb[0]; vf[5] = vb[1]; vf[6] = vb[2]; vf[7] = vb[3];
#pragma unroll
        for (int qt = 0; qt < 2; ++qt) {
          union { uint32_t u[4]; bf16x8 v; } pu;
          pu.u[0] = pw[qt][2 * kb][0];
          pu.u[1] = pw[qt][2 * kb][1];
          pu.u[2] = pw[qt][2 * kb + 1][0];
          pu.u[3] = pw[qt][2 * kb + 1][1];
          accO[qt][dt] = __builtin_amdgcn_mfma_f32_16x16x32_bf16(vf, pu.v, accO[qt][dt], 0, 0, 0);
        }
      }
    }
    buf ^= 1;
  }

  // ---- epilogue: normalize, emit bf16 cgroup layout for proj GEMM ----
  const int head = bn & 3;
  const int bb = bn >> 2;
#pragma unroll
  for (int qt = 0; qt < 2; ++qt) {
    float s = l_r[qt];
    s += __shfl_xor(s, 16);
    s += __shfl_xor(s, 32);
    const float inv = 1.0f / s;
    const int p = q0 + qt * 16 + c;
#pragma unroll
    for (int dt = 0; dt < 4; ++dt) {
      uint2 uu;
      uu.x = cvt_pk_bf16(accO[qt][dt][0] * inv, accO[qt][dt][1] * inv);
      uu.y = cvt_pk_bf16(accO[qt][dt][2] * inv, accO[qt][dt][3] * inv);
      const int cg = head * 8 + dt * 2 + (g >> 1);
      *(uint2*)&Abf[((size_t)(bb * 32 + cg) * HW_ + p) * 8 + (g & 1) * 4] = uu;
    }
  }
}

// ---------------- SE pooling ----------------
__global__ __launch_bounds__(256) void pool_kernel(
    const float* __restrict__ proj, const float* __restrict__ gray,
    float* __restrict__ pavg, float* __restrict__ pmax) {
  const int ch = blockIdx.x;
  const int b = blockIdx.y;
  const int t = threadIdx.x;
  const float* src = (ch < 256) ? (proj + ((size_t)b * 256 + ch) * HW_)
                                : (gray + ((size_t)b * 256 + (ch - 256)) * HW_);
  float s = 0.f, mx = -1e30f;
  for (int p = t; p < HW_; p += 256) {
    const float v_ = src[p];
    s += v_;
    mx = fmaxf(mx, v_);
  }
#pragma unroll
  for (int o = 1; o < 64; o <<= 1) {
    s += __shfl_xor(s, o);
    mx = fmaxf(mx, __shfl_xor(mx, o));
  }
  __shared__ float ss[4], sm[4];
  if ((t & 63) == 0) { ss[t >> 6] = s; sm[t >> 6] = mx; }
  __syncthreads();
  if (t == 0) {
    const float S = ss[0] + ss[1] + ss[2] + ss[3];
    const float M = fmaxf(fmaxf(sm[0], sm[1]), fmaxf(sm[2], sm[3]));
    pavg[b * 512 + ch] = S * (1.f / 4096.f);
    pmax[b * 512 + ch] = M;
  }
}

// ---------------- SE MLP ----------------
__global__ __launch_bounds__(256) void se_kernel(
    const float* __restrict__ pavg, const float* __restrict__ pmax,
    const float* __restrict__ w1, const float* __restrict__ w2,
    float* __restrict__ wch) {
  const int b = blockIdx.x;
  const int t = threadIdx.x;
  __shared__ float za[512], zm[512], hs[64];
  za[t] = pavg[b * 512 + t];
  za[256 + t] = pavg[b * 512 + 256 + t];
  zm[t] = pmax[b * 512 + t];
  zm[256 + t] = pmax[b * 512 + 256 + t];
  __syncthreads();
  if (t < 64) {
    float ha = 0.f, hm = 0.f;
    for (int c = 0; c < 512; ++c) {
      const float w = w1[t * 512 + c];
      ha += w * za[c];
      hm += w * zm[c];
    }
    hs[t] = fmaxf(ha, 0.f) + fmaxf(hm, 0.f);
  }
  __syncthreads();
  for (int o = t; o < 512; o += 256) {
    float acc = 0.f;
#pragma unroll
    for (int hh = 0; hh < 64; ++hh) acc += hs[hh] * w2[o * 64 + hh];
    wch[b * 512 + o] = 1.f / (1.f + __expf(-acc));
  }
}

// ---------------- spatial-attention input ----------------
__global__ __launch_bounds__(256) void sa_reduce_kernel(
    const float* __restrict__ proj, const float* __restrict__ gray,
    const float* __restrict__ wch, float* __restrict__ sa_in) {
  const int b = blockIdx.y;
  const int p = blockIdx.x * 256 + threadIdx.x;
  __shared__ float wl[512];
  wl[threadIdx.x] = wch[b * 512 + threadIdx.x];
  wl[256 + threadIdx.x] = wch[b * 512 + 256 + threadIdx.x];
  __syncthreads();
  const float* pb = proj + (size_t)b * 256 * HW_;
  const float* gb = gray + (size_t)b * 256 * HW_;
  float s = 0.f, mx = -1e30f;
  for (int ch = 0; ch < 256; ++ch) {
    const float v_ = pb[(size_t)ch * HW_ + p] * wl[ch];
    s += v_;
    mx = fmaxf(mx, v_);
  }
  for (int ch = 0; ch < 256; ++ch) {
    const float v_ = gb[(size_t)ch * HW_ + p] * wl[256 + ch];
    s += v_;
    mx = fmaxf(mx, v_);
  }
  sa_in[((size_t)b * 2 + 0) * HW_ + p] = s * (1.f / 512.f);
  sa_in[((size_t)b * 2 + 1) * HW_ + p] = mx;
}

// ---------------- 7x7 spatial conv + sigmoid -> wsp ----------------
__global__ __launch_bounds__(256) void sa_conv_kernel(
    const float* __restrict__ sa_in, const float* __restrict__ sa_w,
    float* __restrict__ wsp) {
  const int b = blockIdx.y;
  const int t = threadIdx.x;
  __shared__ float pl[2][64][64];
  __shared__ float wl[98];
  for (int e = t; e < 8192; e += 256) ((float*)pl)[e] = sa_in[(size_t)b * 8192 + e];
  if (t < 98) wl[t] = sa_w[t];
  __syncthreads();
  const int pix = blockIdx.x * 256 + t;
  const int y = pix >> 6, x = pix & 63;
  float acc = 0.f;
#pragma unroll
  for (int ic = 0; ic < 2; ++ic)
#pragma unroll
    for (int ky = 0; ky < 7; ++ky) {
      const int yy = y + ky - 3;
      if (yy < 0 || yy > 63) continue;
#pragma unroll
      for (int kx = 0; kx < 7; ++kx) {
        const int xx = x + kx - 3;
        if (xx < 0 || xx > 63) continue;
        acc += pl[ic][yy][xx] * wl[ic * 49 + ky * 7 + kx];
      }
    }
  wsp[(size_t)b * HW_ + pix] = 1.f / (1.f + __expf(-acc));
}

// ---------------- gate: catg[b][yp:66][xi:80][ic:512] bf16 = cat*wch*wsp, halo=0 ----------------
__global__ __launch_bounds__(256) void gate_kernel(
    const float* __restrict__ proj, const float* __restrict__ gray,
    const float* __restrict__ wch, const float* __restrict__ wsp,
    unsigned short* __restrict__ catg) {
  const int yp = blockIdx.x;  // 0..65
  const int b = blockIdx.y;
  const int t = threadIdx.x;
  unsigned short* rowp = catg + ((size_t)b * 66 + yp) * 80 * 512;
  if (yp == 0 || yp == 65) {
    short8v z = {};
    for (int m = t; m < 5120; m += 256) *(short8v*)&rowp[m * 8] = z;
    return;
  }
  const int y = yp - 1;
  __shared__ unsigned short tile[64][136];
  __shared__ float wchl[512];
  __shared__ float wspl[64];
  for (int e = t; e < 512; e += 256) wchl[e] = wch[b * 512 + e];
  if (t < 64) wspl[t] = wsp[(size_t)b * HW_ + y * 64 + t];
  {
    short8v z = {};
    for (int m = t; m < 1024; m += 256) {
      const int col = m >> 6;
      const int xi = (col < 8) ? col : (col + 64);
      const int c8 = m & 63;
      *(short8v*)&rowp[xi * 512 + c8 * 8] = z;
    }
  }
  const float* pb = proj + (size_t)b * 256 * HW_;
  const float* gb = gray + (size_t)b * 256 * HW_;
  const int x = t & 63;
  const int cg = t >> 6;
  for (int ct = 0; ct < 4; ++ct) {
    __syncthreads();
    for (int r = 0; r < 32; ++r) {
      const int ch = ct * 128 + cg * 32 + r;
      const float sv = (ch < 256) ? pb[(size_t)ch * HW_ + y * 64 + x]
                                  : gb[(size_t)(ch - 256) * HW_ + y * 64 + x];
      tile[x][cg * 32 + r] = f2bf(sv * wchl[ch] * wspl[x]);
    }
    __syncthreads();
    const int c8t = t & 15;
    const int xg = t >> 4;
#pragma unroll
    for (int p = 0; p < 4; ++p) {
      const int xx = xg * 4 + p;
      short8v v8 = *(const short8v*)&tile[xx][c8t * 8];
      *(short8v*)&rowp[(size_t)(xx + 8) * 512 + ct * 128 + c8t * 8] = v8;
    }
  }
}

// ---------------- weight transform: fuse_w fp32 [oc][ic][3][3] -> bf16 [tap][oc][ic] ----------------
__global__ __launch_bounds__(256) void wtrans_kernel(
    const float* __restrict__ fw, unsigned short* __restrict__ wt) {
  const size_t i = (size_t)blockIdx.x * 256 + threadIdx.x;  // over 256*512
  const int oc = (int)(i >> 9);
  const int ic = (int)(i & 511);
  const float* src = fw + i * 9;
#pragma unroll
  for (int tap = 0; tap < 9; ++tap)
    wt[((size_t)tap * 256 + oc) * 512 + ic] = f2bf(src[tap]);
}

// ---------------- fuse conv via MFMA ----------------
__global__ __launch_bounds__(256) void fuse_mfma_kernel(
    const unsigned short* __restrict__ catg, const unsigned short* __restrict__ wt,
    const float* __restrict__ bn_g, const float* __restrict__ bn_b,
    const float* __restrict__ bn_m, const float* __restrict__ bn_v,
    float* __restrict__ out) {
  __shared__ unsigned short X_l[2][6][2][80][8];
  __shared__ unsigned short W_l[2][9][2][64][8];
  __shared__ float invl[64], shl[64];
  const int t = threadIdx.x;
  const int w = t >> 6;
  const int l = t & 63;
  const int n = l & 31;
  const int g = l >> 5;
  const int y0 = blockIdx.x * 4;
  const int o0 = blockIdx.y * 64;
  const int b = blockIdx.z;

  if (t < 64) {
    const float iv = bn_g[o0 + t] * rsqrtf(bn_v[o0 + t] + 1e-5f);
    invl[t] = iv;
    shl[t] = bn_b[o0 + t] - bn_m[o0 + t] * iv;
  }

  const unsigned short* catb = catg + ((size_t)b * 66 + y0) * 80 * 512;

  auto stageX = [&](int bi, int ic0) {
    for (int wc = w; wc < 15; wc += 4) {
      const int m = wc * 64 + l;
      const int lr = m / 160;
      const int rem = m - lr * 160;
      const int half = rem / 80;
      const int xi = rem - half * 80;
      gld_lds16(catb + ((size_t)lr * 80 + xi) * 512 + ic0 + half * 8,
                &X_l[bi][0][0][0][0] + (size_t)wc * 512);
    }
  };
  auto stageW = [&](int bi, int ic0) {
    for (int wc = w; wc < 18; wc += 4) {
      const int m = wc * 64 + l;
      const int tap = m >> 7;
      const int rem = m & 127;
      const int half = rem >> 6;
      const int oc = rem & 63;
      gld_lds16(wt + ((size_t)tap * 256 + o0 + oc) * 512 + ic0 + half * 8,
                &W_l[bi][0][0][0][0] + (size_t)wc * 512);
    }
  };

  f32x16 acc[2][2] = {};

  stageX(0, 0);
  stageW(0, 0);
  int buf = 0;
  for (int ks = 0; ks < 32; ++ks) {
    asm volatile("s_waitcnt vmcnt(0)" ::: "memory");
    __syncthreads();
    if (ks < 31) {
      stageX(buf ^ 1, (ks + 1) * 16);
      stageW(buf ^ 1, (ks + 1) * 16);
    }
#pragma unroll
    for (int ky = 0; ky < 3; ++ky) {
      const int lr = w + ky;
#pragma unroll
      for (int kx = 0; kx < 3; ++kx) {
        const int tap = ky * 3 + kx;
        bf16x8 a0 = *(const bf16x8*)&W_l[buf][tap][g][n][0];
        bf16x8 a1 = *(const bf16x8*)&W_l[buf][tap][g][32 + n][0];
        bf16x8 b0 = *(const bf16x8*)&X_l[buf][lr][g][n + kx + 7][0];
        bf16x8 b1 = *(const bf16x8*)&X_l[buf][lr][g][32 + n + kx + 7][0];
        acc[0][0] = __builtin_amdgcn_mfma_f32_32x32x16_bf16(a0, b0, acc[0][0], 0, 0, 0);
        acc[0][1] = __builtin_amdgcn_mfma_f32_32x32x16_bf16(a0, b1, acc[0][1], 0, 0, 0);
        acc[1][0] = __builtin_amdgcn_mfma_f32_32x32x16_bf16(a1, b0, acc[1][0], 0, 0, 0);
        acc[1][1] = __builtin_amdgcn_mfma_f32_32x32x16_bf16(a1, b1, acc[1][1], 0, 0, 0);
      }
    }
    buf ^= 1;
  }

#pragma unroll
  for (int of = 0; of < 2; ++of)
#pragma unroll
    for (int pf = 0; pf < 2; ++pf)
#pragma unroll
      for (int r = 0; r < 16; ++r) {
        const int row = (r & 3) + 8 * (r >> 2) + 4 * g;
        const int oc = of * 32 + row;
        const float yv = acc[of][pf][r] * invl[oc] + shl[oc];
        const float ov = yv > 0.f ? yv : 0.2f * yv;
        out[((size_t)b * 256 + o0 + oc) * HW_ + (size_t)(y0 + w) * 64 + pf * 32 + n] = ov;
      }
}

extern "C" void kernel_launch(void* const* d_in, const int* in_sizes, int n_in,
                              void* d_out, int out_size, void* d_ws, size_t ws_size,
                              hipStream_t stream) {
  const float* color  = (const float*)d_in[0];
  const float* gray   = (const float*)d_in[1];
  const float* Wq     = (const float*)d_in[2];
  const float* Wk     = (const float*)d_in[3];
  const float* Wv     = (const float*)d_in[4];
  const float* Wproj  = (const float*)d_in[5];
  const float* ca_w1  = (const float*)d_in[6];
  const float* ca_w2  = (const float*)d_in[7];
  const float* sa_w   = (const float*)d_in[8];
  const float* fuse_w = (const float*)d_in[9];
  const float* bn_g   = (const float*)d_in[10];
  const float* bn_b   = (const float*)d_in[11];
  const float* bn_m   = (const float*)d_in[12];
  const float* bn_v   = (const float*)d_in[13];
  float* out = (float*)d_out;

  char* ws = (char*)d_ws;
  // Overlay plan (MB offsets):
  // [0,8)  Cbf -> (after Q gemm) Abf -> (after proj gemm) catg[0,21.6)
  // [8,16) Gbf                         (catg continues to 21.6)
  // [16,24) Qbf
  // [24,32) Kbf -> proj fp32 [24,40)
  // [32,40) Vbf
  // [40,40.5) W bf16 x4; [40.5,42.75) Wt; [42.75,~43) smalls
  unsigned short* Cbf = (unsigned short*)(ws);
  unsigned short* Gbf = (unsigned short*)(ws + (8u << 20));
  unsigned short* Qbf = (unsigned short*)(ws + (16u << 20));
  unsigned short* Kbf = (unsigned short*)(ws + (24u << 20));
  unsigned short* Vbf = (unsigned short*)(ws + (32u << 20));
  unsigned short* Abf = (unsigned short*)(ws);
  float* proj         = (float*)(ws + (24u << 20));
  unsigned short* catg = (unsigned short*)(ws);
  unsigned short* WqB = (unsigned short*)(ws + (40u << 20));
  unsigned short* WkB = WqB + 65536;
  unsigned short* WvB = WkB + 65536;
  unsigned short* WpB = WvB + 65536;
  unsigned short* Wt  = WpB + 65536;           // 9*256*512 bf16 = 2.25MB
  float* pavg  = (float*)((char*)Wt + 9 * 256 * 512 * 2);
  float* pmax  = pavg + 2048;
  float* wch   = pmax + 2048;
  float* sa_in = wch + 2048;     // 32768
  float* wsp   = sa_in + 32768;  // 16384
  (void)in_sizes; (void)n_in; (void)out_size; (void)ws_size;

  const float qscale = 0.125f * 1.44269504f;

  wconv_kernel<<<dim3(32), 256, 0, stream>>>(Wq, WqB);
  wconv_kernel<<<dim3(32), 256, 0, stream>>>(Wk, WkB);
  wconv_kernel<<<dim3(32), 256, 0, stream>>>(Wv, WvB);
  wconv_kernel<<<dim3(32), 256, 0, stream>>>(Wproj, WpB);
  wtrans_kernel<<<dim3(512), 256, 0, stream>>>(fuse_w, Wt);
  xconv_kernel<<<dim3(2048), 256, 0, stream>>>(color, Cbf);
  xconv_kernel<<<dim3(2048), 256, 0, stream>>>(gray, Gbf);

  dim3 g_gemm(32, 4, 4);
  gemm_mfma_kernel<<<g_gemm, 256, 0, stream>>>(Cbf, WqB, Qbf, 1, qscale);
  gemm_mfma_kernel<<<g_gemm, 256, 0, stream>>>(Gbf, WkB, Kbf, 1, 1.0f);
  gemm_mfma_kernel<<<g_gemm, 256, 0, stream>>>(Gbf, WvB, Vbf, 2, 1.0f);
  attn_mfma_kernel<<<dim3(512), 256, 0, stream>>>(Qbf, Kbf, Vbf, Abf);
  gemm_mfma_kernel<<<g_gemm, 256, 0, stream>>>(Abf, WpB, proj, 0, 1.0f);

  pool_kernel<<<dim3(512, 4), 256, 0, stream>>>(proj, gray, pavg, pmax);
  se_kernel<<<dim3(4), 256, 0, stream>>>(pavg, pmax, ca_w1, ca_w2, wch);
  sa_reduce_kernel<<<dim3(16, 4), 256, 0, stream>>>(proj, gray, wch, sa_in);
  sa_conv_kernel<<<dim3(16, 4), 256, 0, stream>>>(sa_in, sa_w, wsp);
  gate_kernel<<<dim3(66, 4), 256, 0, stream>>>(proj, gray, wch, wsp, catg);
  fuse_mfma_kernel<<<dim3(16, 4, 4), 256, 0, stream>>>(catg, Wt, bn_g, bn_b, bn_m, bn_v, out);
}

// Round 5
// 278.838 us; speedup vs baseline: 7.6912x; 1.2580x over previous
//
#include <hip/hip_runtime.h>
#include <hip/hip_bf16.h>
#include <stdint.h>

#define HW_ 4096

typedef short bf16x8 __attribute__((ext_vector_type(8)));
typedef short short4v __attribute__((ext_vector_type(4)));
typedef short short8v __attribute__((ext_vector_type(8)));
typedef float f32x4 __attribute__((ext_vector_type(4)));
typedef float f32x16 __attribute__((ext_vector_type(16)));
typedef uint32_t u32x4 __attribute__((ext_vector_type(4)));

__device__ inline unsigned short f2bf(float x) {
  uint32_t u = __builtin_bit_cast(uint32_t, x);
  uint32_t r = ((u >> 16) & 1u) + 0x7fffu;
  return (unsigned short)((u + r) >> 16);
}
__device__ inline uint32_t cvt_pk_bf16(float lo, float hi) {
  uint32_t r;
  asm("v_cvt_pk_bf16_f32 %0, %1, %2" : "=v"(r) : "v"(lo), "v"(hi));
  return r;
}
__device__ inline float bf_lo(uint32_t u) { return __builtin_bit_cast(float, u << 16); }
__device__ inline float bf_hi(uint32_t u) { return __builtin_bit_cast(float, u & 0xffff0000u); }
__device__ inline void gld_lds16(const unsigned short* g, unsigned short* l) {
  __builtin_amdgcn_global_load_lds((const __attribute__((address_space(1))) void*)g,
                                   (__attribute__((address_space(3))) void*)l, 16, 0, 0);
}

// ---------------- xconv: fp32 [b][c][p] -> bf16 cgroup layout [(b*32+cg)][p][e] ----------------
__global__ __launch_bounds__(256) void xconv_kernel(
    const float* __restrict__ X, unsigned short* __restrict__ Y) {
  const int i = blockIdx.x * 256 + threadIdx.x;
  const int p = i & 4095;
  const int cg = (i >> 12) & 31;
  const int b = i >> 17;
  const float* src = X + ((size_t)b * 256 + cg * 8) * HW_ + p;
  float v[8];
#pragma unroll
  for (int e = 0; e < 8; ++e) v[e] = src[(size_t)e * HW_];
  uint4 o;
  o.x = cvt_pk_bf16(v[0], v[1]);
  o.y = cvt_pk_bf16(v[2], v[3]);
  o.z = cvt_pk_bf16(v[4], v[5]);
  o.w = cvt_pk_bf16(v[6], v[7]);
  *(uint4*)&Y[((size_t)(b * 32 + cg) * HW_ + p) * 8] = o;
}

// ---------------- prep: 4x wconv (fp32 W[o][c] -> bf16 [cg][o][e]) + wtrans ----------------
__global__ __launch_bounds__(256) void prep_kernel(
    const float* __restrict__ Wq, const float* __restrict__ Wk,
    const float* __restrict__ Wv, const float* __restrict__ Wp,
    const float* __restrict__ fw,
    unsigned short* __restrict__ WqB, unsigned short* __restrict__ WkB,
    unsigned short* __restrict__ WvB, unsigned short* __restrict__ WpB,
    unsigned short* __restrict__ wt) {
  const int blk = blockIdx.x;
  if (blk < 128) {
    const int which = blk >> 5;
    const float* W = which == 0 ? Wq : which == 1 ? Wk : which == 2 ? Wv : Wp;
    unsigned short* Y = which == 0 ? WqB : which == 1 ? WkB : which == 2 ? WvB : WpB;
    const int i = (blk & 31) * 256 + threadIdx.x;  // 8192
    const int o = i & 255;
    const int cg = i >> 8;
    float4 a = *(const float4*)&W[(size_t)o * 256 + cg * 8];
    float4 bq = *(const float4*)&W[(size_t)o * 256 + cg * 8 + 4];
    uint4 ov;
    ov.x = cvt_pk_bf16(a.x, a.y);
    ov.y = cvt_pk_bf16(a.z, a.w);
    ov.z = cvt_pk_bf16(bq.x, bq.y);
    ov.w = cvt_pk_bf16(bq.z, bq.w);
    *(uint4*)&Y[((size_t)cg * 256 + o) * 8] = ov;
  } else {
    const size_t i = (size_t)(blk - 128) * 256 + threadIdx.x;  // 256*512
    const int oc = (int)(i >> 9);
    const int ic = (int)(i & 511);
    const float* src = fw + i * 9;
#pragma unroll
    for (int tap = 0; tap < 9; ++tap)
      wt[((size_t)tap * 256 + oc) * 512 + ic] = f2bf(src[tap]);
  }
}

// ---------------- MFMA GEMM ----------------
// Xbf: [(b*32+cg)][p][e], Wbf: [cg][o][e]. Block 64o x 128p, 4 waves.
// mode 1: bf16 [b*4+oy][p][dd]*oscale; 2: bf16 [b][o][p]; 3: bf16 cgroup.
__global__ __launch_bounds__(256) void gemm_mfma_kernel(
    const unsigned short* __restrict__ Xbf, const unsigned short* __restrict__ Wbf,
    void* __restrict__ Yv, int mode, float oscale) {
  __shared__ unsigned short W_l[32][64][8];
  __shared__ unsigned short X_l[2][2][128][8];
  const int t = threadIdx.x;
  const int w = t >> 6;
  const int l = t & 63;
  const int n = l & 31;
  const int g32 = l >> 5;
  const int p0 = blockIdx.x * 128;
  const int o0 = blockIdx.y * 64;
  const int b = blockIdx.z;
  const int wo = w >> 1, wp = w & 1;
  const unsigned short* Xb = Xbf + (size_t)b * 32 * HW_ * 8;

  for (int i = t; i < 2048; i += 256) {
    const int ksg = i >> 6, oc = i & 63;
    gld_lds16(Wbf + ((size_t)ksg * 256 + o0 + oc) * 8, &W_l[0][0][0] + (size_t)i * 8);
  }
  {
    const int gg = t >> 7, pp = t & 127;
    gld_lds16(Xb + ((size_t)gg * HW_ + p0 + pp) * 8, &X_l[0][0][0][0] + (size_t)t * 8);
  }
  f32x16 acc[2] = {};
  int buf = 0;
  for (int ks = 0; ks < 16; ++ks) {
    asm volatile("s_waitcnt vmcnt(0)" ::: "memory");
    __syncthreads();
    if (ks < 15) {
      const int gg = t >> 7, pp = t & 127;
      gld_lds16(Xb + ((size_t)((ks + 1) * 2 + gg) * HW_ + p0 + pp) * 8,
                &X_l[buf ^ 1][0][0][0] + (size_t)t * 8);
    }
    bf16x8 af = *(const bf16x8*)&W_l[ks * 2 + g32][wo * 32 + n][0];
    bf16x8 b0 = *(const bf16x8*)&X_l[buf][g32][wp * 64 + n][0];
    bf16x8 b1 = *(const bf16x8*)&X_l[buf][g32][wp * 64 + 32 + n][0];
    acc[0] = __builtin_amdgcn_mfma_f32_32x32x16_bf16(af, b0, acc[0], 0, 0, 0);
    acc[1] = __builtin_amdgcn_mfma_f32_32x32x16_bf16(af, b1, acc[1], 0, 0, 0);
    buf ^= 1;
  }

  if (mode == 1) {
    unsigned short* Y = (unsigned short*)Yv;
    const size_t bh = (size_t)b * 4 + blockIdx.y;
#pragma unroll
    for (int pf = 0; pf < 2; ++pf) {
      const int p = p0 + wp * 64 + pf * 32 + n;
      unsigned short* dst = Y + (bh * HW_ + p) * 64 + wo * 32 + 4 * g32;
#pragma unroll
      for (int q = 0; q < 4; ++q) {
        uint2 uu;
        uu.x = cvt_pk_bf16(acc[pf][q * 4 + 0] * oscale, acc[pf][q * 4 + 1] * oscale);
        uu.y = cvt_pk_bf16(acc[pf][q * 4 + 2] * oscale, acc[pf][q * 4 + 3] * oscale);
        *(uint2*)&dst[8 * q] = uu;
      }
    }
  } else if (mode == 2) {
    unsigned short* Y = (unsigned short*)Yv;
#pragma unroll
    for (int pf = 0; pf < 2; ++pf) {
      const int p = p0 + wp * 64 + pf * 32 + n;
#pragma unroll
      for (int r = 0; r < 16; ++r) {
        const int m = (r & 3) + 8 * (r >> 2) + 4 * g32;
        Y[((size_t)b * 256 + o0 + wo * 32 + m) * HW_ + p] = f2bf(acc[pf][r]);
      }
    }
  } else {  // mode 3: bf16 cgroup [(b*32+cg)][p][e]
    unsigned short* Y = (unsigned short*)Yv;
    const int cgb = (o0 + wo * 32) >> 3;
#pragma unroll
    for (int pf = 0; pf < 2; ++pf) {
      const int p = p0 + wp * 64 + pf * 32 + n;
#pragma unroll
      for (int q = 0; q < 4; ++q) {
        uint2 uu;
        uu.x = cvt_pk_bf16(acc[pf][q * 4 + 0], acc[pf][q * 4 + 1]);
        uu.y = cvt_pk_bf16(acc[pf][q * 4 + 2], acc[pf][q * 4 + 3]);
        *(uint2*)&Y[((size_t)(b * 32 + cgb + q) * HW_ + p) * 8 + 4 * g32] = uu;
      }
    }
  }
}

// ---------------- MFMA flash attention (no-max softmax; static-buf unrolled phases) ----------------
#define ATTN_STAGE(BUF, KP, VP)                                              \
  {                                                                          \
    gld_lds16((KP), &k_l[BUF][16 * w][0]);                                   \
    gld_lds16((KP) + (size_t)8 * 64, &k_l[BUF][16 * w + 8][0]);              \
    gld_lds16((VP), &v_l[BUF][16 * w][0]);                                   \
    gld_lds16((VP) + (size_t)8 * HW_, &v_l[BUF][16 * w + 8][0]);             \
  }

#define ATTN_COMPUTE(BUF)                                                    \
  {                                                                          \
    f32x4 accS[2][4];                                                        \
    _Pragma("unroll") for (int jt = 0; jt < 4; ++jt) {                       \
      const int jrow = jt * 16 + c;                                          \
      bf16x8 kf0 = *(const bf16x8*)&k_l[BUF][jrow][((0 + g) ^ (c & 7)) * 8]; \
      bf16x8 kf1 = *(const bf16x8*)&k_l[BUF][jrow][((4 + g) ^ (c & 7)) * 8]; \
      _Pragma("unroll") for (int qt = 0; qt < 2; ++qt) {                     \
        f32x4 s0 = __builtin_amdgcn_mfma_f32_16x16x32_bf16(kf0, qf[qt][0], zero4, 0, 0, 0); \
        accS[qt][jt] = __builtin_amdgcn_mfma_f32_16x16x32_bf16(kf1, qf[qt][1], s0, 0, 0, 0); \
      }                                                                      \
    }                                                                        \
    uint32_t pwu[2][2][4];                                                   \
    _Pragma("unroll") for (int qt = 0; qt < 2; ++qt) {                       \
      float rs = 0.f;                                                        \
      _Pragma("unroll") for (int jt = 0; jt < 4; ++jt) {                     \
        const float e0 = __builtin_amdgcn_exp2f(accS[qt][jt][0]);            \
        const float e1 = __builtin_amdgcn_exp2f(accS[qt][jt][1]);            \
        const float e2 = __builtin_amdgcn_exp2f(accS[qt][jt][2]);            \
        const float e3 = __builtin_amdgcn_exp2f(accS[qt][jt][3]);            \
        rs += (e0 + e1) + (e2 + e3);                                         \
        pwu[qt][jt >> 1][(jt & 1) * 2 + 0] = cvt_pk_bf16(e0, e1);            \
        pwu[qt][jt >> 1][(jt & 1) * 2 + 1] = cvt_pk_bf16(e2, e3);            \
      }                                                                      \
      l_r[qt] += rs;                                                         \
    }                                                                        \
    bf16x8 pf[2][2];                                                         \
    _Pragma("unroll") for (int qt = 0; qt < 2; ++qt)                         \
    _Pragma("unroll") for (int kb = 0; kb < 2; ++kb) {                       \
      u32x4 tmp = {pwu[qt][kb][0], pwu[qt][kb][1], pwu[qt][kb][2], pwu[qt][kb][3]}; \
      pf[qt][kb] = __builtin_bit_cast(bf16x8, tmp);                          \
    }                                                                        \
    _Pragma("unroll") for (int dt = 0; dt < 4; ++dt) {                       \
      const int row = dt * 16 + c;                                           \
      const int sw = c & 7;                                                  \
      _Pragma("unroll") for (int kb = 0; kb < 2; ++kb) {                     \
        union { short4v h[2]; bf16x8 v8; } vv;                               \
        vv.h[0] = *(const short4v*)&v_l[BUF][row][(((kb * 4 + 0) + (g >> 1)) ^ sw) * 8 + (g & 1) * 4]; \
        vv.h[1] = *(const short4v*)&v_l[BUF][row][(((kb * 4 + 2) + (g >> 1)) ^ sw) * 8 + (g & 1) * 4]; \
        accO[0][dt] = __builtin_amdgcn_mfma_f32_16x16x32_bf16(vv.v8, pf[0][kb], accO[0][dt], 0, 0, 0); \
        accO[1][dt] = __builtin_amdgcn_mfma_f32_16x16x32_bf16(vv.v8, pf[1][kb], accO[1][dt], 0, 0, 0); \
      }                                                                      \
    }                                                                        \
  }

__global__ __launch_bounds__(256) void attn_mfma_kernel(
    const unsigned short* __restrict__ Qb, const unsigned short* __restrict__ Kb,
    const unsigned short* __restrict__ Vb, unsigned short* __restrict__ Abf) {
  __shared__ unsigned short k_l[2][64][64];
  __shared__ unsigned short v_l[2][64][64];
  const int t = threadIdx.x;
  const int w = t >> 6;
  const int l = t & 63;
  const int g = l >> 4;
  const int c = l & 15;
  const int bid = blockIdx.x;
  const int gidx = (bid & 7) * 64 + (bid >> 3);  // XCD-contiguous bn
  const int bn = gidx >> 5;
  const int q0 = (gidx & 31) * 128 + w * 32;

  bf16x8 qf[2][2];
#pragma unroll
  for (int qt = 0; qt < 2; ++qt)
#pragma unroll
    for (int dh = 0; dh < 2; ++dh)
      qf[qt][dh] = *(const bf16x8*)&Qb[((size_t)bn * HW_ + q0 + qt * 16 + c) * 64 + dh * 32 + g * 8];

  const int srow = 16 * w + (l >> 3);
  const int schunk = (l & 7) ^ ((l >> 3) & 7);
  const unsigned short* gKp = Kb + ((size_t)bn * HW_ + srow) * 64 + schunk * 8;
  const unsigned short* gVp = Vb + ((size_t)bn * 64 + srow) * HW_ + schunk * 8;

  f32x4 accO[2][4] = {};
  float l_r[2] = {0.f, 0.f};
  const f32x4 zero4 = {0.f, 0.f, 0.f, 0.f};

  ATTN_STAGE(0, gKp, gVp);
  gKp += 4096; gVp += 64;

  for (int kt2 = 0; kt2 < 32; ++kt2) {
    asm volatile("s_waitcnt vmcnt(0)" ::: "memory");
    __syncthreads();
    ATTN_STAGE(1, gKp, gVp);
    gKp += 4096; gVp += 64;
    ATTN_COMPUTE(0)
    asm volatile("s_waitcnt vmcnt(0)" ::: "memory");
    __syncthreads();
    if (kt2 < 31) {
      ATTN_STAGE(0, gKp, gVp);
      gKp += 4096; gVp += 64;
    }
    ATTN_COMPUTE(1)
  }

  // epilogue: normalize, emit bf16 cgroup layout for proj GEMM
  const int head = bn & 3;
  const int bb = bn >> 2;
#pragma unroll
  for (int qt = 0; qt < 2; ++qt) {
    float s = l_r[qt];
    s += __shfl_xor(s, 16);
    s += __shfl_xor(s, 32);
    const float inv = 1.0f / s;
    const int p = q0 + qt * 16 + c;
#pragma unroll
    for (int dt = 0; dt < 4; ++dt) {
      uint2 uu;
      uu.x = cvt_pk_bf16(accO[qt][dt][0] * inv, accO[qt][dt][1] * inv);
      uu.y = cvt_pk_bf16(accO[qt][dt][2] * inv, accO[qt][dt][3] * inv);
      const int cg = head * 8 + dt * 2 + (g >> 1);
      *(uint2*)&Abf[((size_t)(bb * 32 + cg) * HW_ + p) * 8 + (g & 1) * 4] = uu;
    }
  }
}

// ---------------- SE pooling from bf16 cgroup (proj + gray) ----------------
__global__ __launch_bounds__(256) void pool_kernel(
    const unsigned short* __restrict__ Pbf, const unsigned short* __restrict__ Gbf,
    float* __restrict__ pavg, float* __restrict__ pmax) {
  const int cg = blockIdx.x;  // 0..31
  const int b = blockIdx.y;
  const int t = threadIdx.x;
  const unsigned short* P = Pbf + (size_t)(b * 32 + cg) * HW_ * 8;
  const unsigned short* G = Gbf + (size_t)(b * 32 + cg) * HW_ * 8;
  float s[16], m[16];
#pragma unroll
  for (int i = 0; i < 16; ++i) { s[i] = 0.f; m[i] = -1e30f; }
  for (int p = t; p < HW_; p += 256) {
    uint4 a = *(const uint4*)&P[(size_t)p * 8];
    uint4 gg = *(const uint4*)&G[(size_t)p * 8];
    const uint32_t ua[4] = {a.x, a.y, a.z, a.w};
    const uint32_t ug[4] = {gg.x, gg.y, gg.z, gg.w};
#pragma unroll
    for (int q = 0; q < 4; ++q) {
      const float a0 = bf_lo(ua[q]), a1 = bf_hi(ua[q]);
      const float g0 = bf_lo(ug[q]), g1 = bf_hi(ug[q]);
      s[q * 2] += a0; s[q * 2 + 1] += a1;
      m[q * 2] = fmaxf(m[q * 2], a0); m[q * 2 + 1] = fmaxf(m[q * 2 + 1], a1);
      s[8 + q * 2] += g0; s[8 + q * 2 + 1] += g1;
      m[8 + q * 2] = fmaxf(m[8 + q * 2], g0); m[8 + q * 2 + 1] = fmaxf(m[8 + q * 2 + 1], g1);
    }
  }
#pragma unroll
  for (int i = 0; i < 16; ++i)
#pragma unroll
    for (int off = 1; off < 64; off <<= 1) {
      s[i] += __shfl_xor(s[i], off);
      m[i] = fmaxf(m[i], __shfl_xor(m[i], off));
    }
  __shared__ float red[4][32];
  const int wv = t >> 6;
  if ((t & 63) == 0) {
#pragma unroll
    for (int i = 0; i < 16; ++i) { red[wv][i] = s[i]; red[wv][16 + i] = m[i]; }
  }
  __syncthreads();
  if (t < 32) {
    const float v0 = red[0][t], v1 = red[1][t], v2 = red[2][t], v3 = red[3][t];
    if (t < 16) {
      const int ch = (t < 8) ? cg * 8 + t : 256 + cg * 8 + (t - 8);
      pavg[b * 512 + ch] = (v0 + v1 + v2 + v3) * (1.f / 4096.f);
    } else {
      const int i = t - 16;
      const int ch = (i < 8) ? cg * 8 + i : 256 + cg * 8 + (i - 8);
      pmax[b * 512 + ch] = fmaxf(fmaxf(v0, v1), fmaxf(v2, v3));
    }
  }
}

// ---------------- SE MLP ----------------
__global__ __launch_bounds__(256) void se_kernel(
    const float* __restrict__ pavg, const float* __restrict__ pmax,
    const float* __restrict__ w1, const float* __restrict__ w2,
    float* __restrict__ wch) {
  const int b = blockIdx.x;
  const int t = threadIdx.x;
  __shared__ float za[512], zm[512], hs[64];
  za[t] = pavg[b * 512 + t];
  za[256 + t] = pavg[b * 512 + 256 + t];
  zm[t] = pmax[b * 512 + t];
  zm[256 + t] = pmax[b * 512 + 256 + t];
  __syncthreads();
  if (t < 64) {
    float ha = 0.f, hm = 0.f;
    for (int c = 0; c < 512; ++c) {
      const float w = w1[t * 512 + c];
      ha += w * za[c];
      hm += w * zm[c];
    }
    hs[t] = fmaxf(ha, 0.f) + fmaxf(hm, 0.f);
  }
  __syncthreads();
  for (int o = t; o < 512; o += 256) {
    float acc = 0.f;
#pragma unroll
    for (int hh = 0; hh < 64; ++hh) acc += hs[hh] * w2[o * 64 + hh];
    wch[b * 512 + o] = 1.f / (1.f + __expf(-acc));
  }
}

// ---------------- spatial-attention input (bf16 cgroup sources) ----------------
__global__ __launch_bounds__(256) void sa_reduce_kernel(
    const unsigned short* __restrict__ Pbf, const unsigned short* __restrict__ Gbf,
    const float* __restrict__ wch, float* __restrict__ sa_in) {
  const int b = blockIdx.y;
  const int p = blockIdx.x * 256 + threadIdx.x;
  __shared__ float wl[512];
  wl[threadIdx.x] = wch[b * 512 + threadIdx.x];
  wl[256 + threadIdx.x] = wch[b * 512 + 256 + threadIdx.x];
  __syncthreads();
  float s = 0.f, mx = -1e30f;
#pragma unroll 4
  for (int cg = 0; cg < 32; ++cg) {
    uint4 a = *(const uint4*)&Pbf[((size_t)(b * 32 + cg) * HW_ + p) * 8];
    const uint32_t u[4] = {a.x, a.y, a.z, a.w};
#pragma unroll
    for (int q = 0; q < 4; ++q) {
      const float v0 = bf_lo(u[q]) * wl[cg * 8 + q * 2];
      const float v1 = bf_hi(u[q]) * wl[cg * 8 + q * 2 + 1];
      s += v0 + v1;
      mx = fmaxf(mx, fmaxf(v0, v1));
    }
  }
#pragma unroll 4
  for (int cg = 0; cg < 32; ++cg) {
    uint4 a = *(const uint4*)&Gbf[((size_t)(b * 32 + cg) * HW_ + p) * 8];
    const uint32_t u[4] = {a.x, a.y, a.z, a.w};
#pragma unroll
    for (int q = 0; q < 4; ++q) {
      const float v0 = bf_lo(u[q]) * wl[256 + cg * 8 + q * 2];
      const float v1 = bf_hi(u[q]) * wl[256 + cg * 8 + q * 2 + 1];
      s += v0 + v1;
      mx = fmaxf(mx, fmaxf(v0, v1));
    }
  }
  sa_in[((size_t)b * 2 + 0) * HW_ + p] = s * (1.f / 512.f);
  sa_in[((size_t)b * 2 + 1) * HW_ + p] = mx;
}

// ---------------- 7x7 spatial conv + sigmoid -> wsp ----------------
__global__ __launch_bounds__(256) void sa_conv_kernel(
    const float* __restrict__ sa_in, const float* __restrict__ sa_w,
    float* __restrict__ wsp) {
  const int b = blockIdx.y;
  const int t = threadIdx.x;
  __shared__ float pl[2][64][64];
  __shared__ float wl[98];
  for (int e = t; e < 8192; e += 256) ((float*)pl)[e] = sa_in[(size_t)b * 8192 + e];
  if (t < 98) wl[t] = sa_w[t];
  __syncthreads();
  const int pix = blockIdx.x * 256 + t;
  const int y = pix >> 6, x = pix & 63;
  float acc = 0.f;
#pragma unroll
  for (int ic = 0; ic < 2; ++ic)
#pragma unroll
    for (int ky = 0; ky < 7; ++ky) {
      const int yy = y + ky - 3;
      if (yy < 0 || yy > 63) continue;
#pragma unroll
      for (int kx = 0; kx < 7; ++kx) {
        const int xx = x + kx - 3;
        if (xx < 0 || xx > 63) continue;
        acc += pl[ic][yy][xx] * wl[ic * 49 + ky * 7 + kx];
      }
    }
  wsp[(size_t)b * HW_ + pix] = 1.f / (1.f + __expf(-acc));
}

// ---------------- gate: catg[b][yp:66][xi:80][ic:512] bf16 (NHWC, halo=0) ----------------
__global__ __launch_bounds__(256) void gate_kernel(
    const unsigned short* __restrict__ Pbf, const unsigned short* __restrict__ Gbf,
    const float* __restrict__ wch, const float* __restrict__ wsp,
    unsigned short* __restrict__ catg) {
  const int yp = blockIdx.x;  // 0..65
  const int b = blockIdx.y;
  const int t = threadIdx.x;
  unsigned short* rowp = catg + ((size_t)b * 66 + yp) * 80 * 512;
  if (yp == 0 || yp == 65) {
    short8v z = {};
    for (int m = t; m < 5120; m += 256) *(short8v*)&rowp[m * 8] = z;
    return;
  }
  const int y = yp - 1;
  __shared__ unsigned short tile[64][512];  // [x][ch], chunk XOR-swizzled by (x&7)
  __shared__ float wchl[512];
  __shared__ float wspl[64];
  for (int e = t; e < 512; e += 256) wchl[e] = wch[b * 512 + e];
  if (t < 64) wspl[t] = wsp[(size_t)b * HW_ + y * 64 + t];
  {
    short8v z = {};
    for (int m = t; m < 1024; m += 256) {
      const int col = m >> 6;
      const int xi = (col < 8) ? col : (col + 64);
      *(short8v*)&rowp[(size_t)xi * 512 + (m & 63) * 8] = z;
    }
  }
  __syncthreads();
  const int x = t & 63;
  const int cs = t >> 6;
  const float wx = wspl[x];
#pragma unroll
  for (int k = 0; k < 16; ++k) {
    const int chunk = cs * 16 + k;  // 0..63 (proj: 0..31, gray: 32..63)
    const unsigned short* src = (chunk < 32)
        ? &Pbf[((size_t)(b * 32 + chunk) * HW_ + y * 64 + x) * 8]
        : &Gbf[((size_t)(b * 32 + (chunk - 32)) * HW_ + y * 64 + x) * 8];
    uint4 a = *(const uint4*)src;
    const uint32_t u[4] = {a.x, a.y, a.z, a.w};
    uint32_t o[4];
#pragma unroll
    for (int q = 0; q < 4; ++q) {
      const float lo = bf_lo(u[q]) * wchl[chunk * 8 + q * 2] * wx;
      const float hi = bf_hi(u[q]) * wchl[chunk * 8 + q * 2 + 1] * wx;
      o[q] = cvt_pk_bf16(lo, hi);
    }
    uint4 ov = {o[0], o[1], o[2], o[3]};
    *(uint4*)&tile[x][(chunk ^ (x & 7)) * 8] = ov;
  }
  __syncthreads();
#pragma unroll
  for (int j = 0; j < 16; ++j) {
    const int xi = (t >> 6) + 4 * j;
    const int c8 = t & 63;
    uint4 v = *(const uint4*)&tile[xi][(c8 ^ (xi & 7)) * 8];
    *(uint4*)&rowp[(size_t)(xi + 8) * 512 + c8 * 8] = v;
  }
}

// ---------------- fuse conv via MFMA (XCD-grouped oc-tiles for catg L2 reuse) ----------------
__global__ __launch_bounds__(256) void fuse_mfma_kernel(
    const unsigned short* __restrict__ catg, const unsigned short* __restrict__ wt,
    const float* __restrict__ bn_g, const float* __restrict__ bn_b,
    const float* __restrict__ bn_m, const float* __restrict__ bn_v,
    float* __restrict__ out) {
  __shared__ unsigned short X_l[2][6][2][80][8];
  __shared__ unsigned short W_l[2][9][2][64][8];
  __shared__ float invl[64], shl[64];
  const int t = threadIdx.x;
  const int w = t >> 6;
  const int l = t & 63;
  const int n = l & 31;
  const int g = l >> 5;
  // decode: 4 oc-tiles of the same (y,b) land on the same XCD (i%8 fixed)
  const int i = blockIdx.x;
  const int xcd = i & 7, slot = i >> 3;
  const int ocB = slot & 3;
  const int yb = xcd + 8 * (slot >> 2);
  const int y0 = (yb & 15) * 4;
  const int o0 = ocB * 64;
  const int b = yb >> 4;

  if (t < 64) {
    const float iv = bn_g[o0 + t] * rsqrtf(bn_v[o0 + t] + 1e-5f);
    invl[t] = iv;
    shl[t] = bn_b[o0 + t] - bn_m[o0 + t] * iv;
  }

  const unsigned short* catb = catg + ((size_t)b * 66 + y0) * 80 * 512;

  auto stageX = [&](int bi, int ic0) {
    for (int wc = w; wc < 15; wc += 4) {
      const int m = wc * 64 + l;
      const int lr = m / 160;
      const int rem = m - lr * 160;
      const int half = rem / 80;
      const int xi = rem - half * 80;
      gld_lds16(catb + ((size_t)lr * 80 + xi) * 512 + ic0 + half * 8,
                &X_l[bi][0][0][0][0] + (size_t)wc * 512);
    }
  };
  auto stageW = [&](int bi, int ic0) {
    for (int wc = w; wc < 18; wc += 4) {
      const int m = wc * 64 + l;
      const int tap = m >> 7;
      const int rem = m & 127;
      const int half = rem >> 6;
      const int oc = rem & 63;
      gld_lds16(wt + ((size_t)tap * 256 + o0 + oc) * 512 + ic0 + half * 8,
                &W_l[bi][0][0][0][0] + (size_t)wc * 512);
    }
  };

  f32x16 acc[2][2] = {};

  stageX(0, 0);
  stageW(0, 0);
  int buf = 0;
  for (int ks = 0; ks < 32; ++ks) {
    asm volatile("s_waitcnt vmcnt(0)" ::: "memory");
    __syncthreads();
    if (ks < 31) {
      stageX(buf ^ 1, (ks + 1) * 16);
      stageW(buf ^ 1, (ks + 1) * 16);
    }
#pragma unroll
    for (int ky = 0; ky < 3; ++ky) {
      const int lr = w + ky;
#pragma unroll
      for (int kx = 0; kx < 3; ++kx) {
        const int tap = ky * 3 + kx;
        bf16x8 a0 = *(const bf16x8*)&W_l[buf][tap][g][n][0];
        bf16x8 a1 = *(const bf16x8*)&W_l[buf][tap][g][32 + n][0];
        bf16x8 b0 = *(const bf16x8*)&X_l[buf][lr][g][n + kx + 7][0];
        bf16x8 b1 = *(const bf16x8*)&X_l[buf][lr][g][32 + n + kx + 7][0];
        acc[0][0] = __builtin_amdgcn_mfma_f32_32x32x16_bf16(a0, b0, acc[0][0], 0, 0, 0);
        acc[0][1] = __builtin_amdgcn_mfma_f32_32x32x16_bf16(a0, b1, acc[0][1], 0, 0, 0);
        acc[1][0] = __builtin_amdgcn_mfma_f32_32x32x16_bf16(a1, b0, acc[1][0], 0, 0, 0);
        acc[1][1] = __builtin_amdgcn_mfma_f32_32x32x16_bf16(a1, b1, acc[1][1], 0, 0, 0);
      }
    }
    buf ^= 1;
  }

#pragma unroll
  for (int of = 0; of < 2; ++of)
#pragma unroll
    for (int pf = 0; pf < 2; ++pf)
#pragma unroll
      for (int r = 0; r < 16; ++r) {
        const int row = (r & 3) + 8 * (r >> 2) + 4 * g;
        const int oc = of * 32 + row;
        const float yv = acc[of][pf][r] * invl[oc] + shl[oc];
        const float ov = yv > 0.f ? yv : 0.2f * yv;
        out[((size_t)b * 256 + o0 + oc) * HW_ + (size_t)(y0 + w) * 64 + pf * 32 + n] = ov;
      }
}

extern "C" void kernel_launch(void* const* d_in, const int* in_sizes, int n_in,
                              void* d_out, int out_size, void* d_ws, size_t ws_size,
                              hipStream_t stream) {
  const float* color  = (const float*)d_in[0];
  const float* gray   = (const float*)d_in[1];
  const float* Wq     = (const float*)d_in[2];
  const float* Wk     = (const float*)d_in[3];
  const float* Wv     = (const float*)d_in[4];
  const float* Wproj  = (const float*)d_in[5];
  const float* ca_w1  = (const float*)d_in[6];
  const float* ca_w2  = (const float*)d_in[7];
  const float* sa_w   = (const float*)d_in[8];
  const float* fuse_w = (const float*)d_in[9];
  const float* bn_g   = (const float*)d_in[10];
  const float* bn_b   = (const float*)d_in[11];
  const float* bn_m   = (const float*)d_in[12];
  const float* bn_v   = (const float*)d_in[13];
  float* out = (float*)d_out;

  char* ws = (char*)d_ws;
  // Overlay (MiB):
  // [0,8)   Cbf -> Abf (Cbf dead after Q gemm; attn writes Abf)
  // [8,16)  Gbf (live through gate)
  // [16,24) Qbf -> Pbf (Qbf dead after attn; proj gemm writes Pbf)
  // [24,32) Kbf \ dead after attn -> catg [24, 44.63)
  // [32,40) Vbf /
  // [45,45.5) WqB..WpB; [45.5,47.75) Wt; [48,48.25) smalls
  unsigned short* Cbf = (unsigned short*)(ws);
  unsigned short* Gbf = (unsigned short*)(ws + (8u << 20));
  unsigned short* Qbf = (unsigned short*)(ws + (16u << 20));
  unsigned short* Kbf = (unsigned short*)(ws + (24u << 20));
  unsigned short* Vbf = (unsigned short*)(ws + (32u << 20));
  unsigned short* Abf = (unsigned short*)(ws);
  unsigned short* Pbf = (unsigned short*)(ws + (16u << 20));
  unsigned short* catg = (unsigned short*)(ws + (24u << 20));
  unsigned short* WqB = (unsigned short*)(ws + (45u << 20));
  unsigned short* WkB = WqB + 65536;
  unsigned short* WvB = WkB + 65536;
  unsigned short* WpB = WvB + 65536;
  unsigned short* Wt  = (unsigned short*)(ws + (45u << 20) + (1u << 19));
  float* pavg  = (float*)(ws + (48u << 20));
  float* pmax  = pavg + 2048;
  float* wch   = pmax + 2048;
  float* sa_in = wch + 2048;     // 32768
  float* wsp   = sa_in + 32768;  // 16384
  (void)in_sizes; (void)n_in; (void)out_size; (void)ws_size;

  const float qscale = 0.125f * 1.44269504f;

  prep_kernel<<<dim3(640), 256, 0, stream>>>(Wq, Wk, Wv, Wproj, fuse_w,
                                             WqB, WkB, WvB, WpB, Wt);
  xconv_kernel<<<dim3(2048), 256, 0, stream>>>(color, Cbf);
  xconv_kernel<<<dim3(2048), 256, 0, stream>>>(gray, Gbf);

  dim3 g_gemm(32, 4, 4);
  gemm_mfma_kernel<<<g_gemm, 256, 0, stream>>>(Cbf, WqB, Qbf, 1, qscale);
  gemm_mfma_kernel<<<g_gemm, 256, 0, stream>>>(Gbf, WkB, Kbf, 1, 1.0f);
  gemm_mfma_kernel<<<g_gemm, 256, 0, stream>>>(Gbf, WvB, Vbf, 2, 1.0f);
  attn_mfma_kernel<<<dim3(512), 256, 0, stream>>>(Qbf, Kbf, Vbf, Abf);
  gemm_mfma_kernel<<<g_gemm, 256, 0, stream>>>(Abf, WpB, Pbf, 3, 1.0f);

  pool_kernel<<<dim3(32, 4), 256, 0, stream>>>(Pbf, Gbf, pavg, pmax);
  se_kernel<<<dim3(4), 256, 0, stream>>>(pavg, pmax, ca_w1, ca_w2, wch);
  sa_reduce_kernel<<<dim3(16, 4), 256, 0, stream>>>(Pbf, Gbf, wch, sa_in);
  sa_conv_kernel<<<dim3(16, 4), 256, 0, stream>>>(sa_in, sa_w, wsp);
  gate_kernel<<<dim3(66, 4), 256, 0, stream>>>(Pbf, Gbf, wch, wsp, catg);
  fuse_mfma_kernel<<<dim3(256), 256, 0, stream>>>(catg, Wt, bn_g, bn_b, bn_m, bn_v, out);
}

// Round 6
// 267.500 us; speedup vs baseline: 8.0172x; 1.0424x over previous
//
#include <hip/hip_runtime.h>
#include <hip/hip_bf16.h>
#include <stdint.h>

#define HW_ 4096

typedef short bf16x8 __attribute__((ext_vector_type(8)));
typedef short short4v __attribute__((ext_vector_type(4)));
typedef short short8v __attribute__((ext_vector_type(8)));
typedef float f32x4 __attribute__((ext_vector_type(4)));
typedef float f32x16 __attribute__((ext_vector_type(16)));
typedef uint32_t u32x4 __attribute__((ext_vector_type(4)));

__device__ inline unsigned short f2bf(float x) {
  uint32_t u = __builtin_bit_cast(uint32_t, x);
  uint32_t r = ((u >> 16) & 1u) + 0x7fffu;
  return (unsigned short)((u + r) >> 16);
}
__device__ inline uint32_t cvt_pk_bf16(float lo, float hi) {
  uint32_t r;
  asm("v_cvt_pk_bf16_f32 %0, %1, %2" : "=v"(r) : "v"(lo), "v"(hi));
  return r;
}
__device__ inline float bf_lo(uint32_t u) { return __builtin_bit_cast(float, u << 16); }
__device__ inline float bf_hi(uint32_t u) { return __builtin_bit_cast(float, u & 0xffff0000u); }
__device__ inline void gld_lds16(const unsigned short* g, unsigned short* l) {
  __builtin_amdgcn_global_load_lds((const __attribute__((address_space(1))) void*)g,
                                   (__attribute__((address_space(3))) void*)l, 16, 0, 0);
}

// ---------------- xconv: fp32 [b][c][p] -> bf16 cgroup layout [(b*32+cg)][p][e] ----------------
__global__ __launch_bounds__(256) void xconv_kernel(
    const float* __restrict__ X, unsigned short* __restrict__ Y) {
  const int i = blockIdx.x * 256 + threadIdx.x;
  const int p = i & 4095;
  const int cg = (i >> 12) & 31;
  const int b = i >> 17;
  const float* src = X + ((size_t)b * 256 + cg * 8) * HW_ + p;
  float v[8];
#pragma unroll
  for (int e = 0; e < 8; ++e) v[e] = src[(size_t)e * HW_];
  uint4 o;
  o.x = cvt_pk_bf16(v[0], v[1]);
  o.y = cvt_pk_bf16(v[2], v[3]);
  o.z = cvt_pk_bf16(v[4], v[5]);
  o.w = cvt_pk_bf16(v[6], v[7]);
  *(uint4*)&Y[((size_t)(b * 32 + cg) * HW_ + p) * 8] = o;
}

// ---------------- prep: 4x wconv (fp32 W[o][c] -> bf16 [cg][o][e]) + wtrans ----------------
__global__ __launch_bounds__(256) void prep_kernel(
    const float* __restrict__ Wq, const float* __restrict__ Wk,
    const float* __restrict__ Wv, const float* __restrict__ Wp,
    const float* __restrict__ fw,
    unsigned short* __restrict__ WqB, unsigned short* __restrict__ WkB,
    unsigned short* __restrict__ WvB, unsigned short* __restrict__ WpB,
    unsigned short* __restrict__ wt) {
  const int blk = blockIdx.x;
  if (blk < 128) {
    const int which = blk >> 5;
    const float* W = which == 0 ? Wq : which == 1 ? Wk : which == 2 ? Wv : Wp;
    unsigned short* Y = which == 0 ? WqB : which == 1 ? WkB : which == 2 ? WvB : WpB;
    const int i = (blk & 31) * 256 + threadIdx.x;  // 8192
    const int o = i & 255;
    const int cg = i >> 8;
    float4 a = *(const float4*)&W[(size_t)o * 256 + cg * 8];
    float4 bq = *(const float4*)&W[(size_t)o * 256 + cg * 8 + 4];
    uint4 ov;
    ov.x = cvt_pk_bf16(a.x, a.y);
    ov.y = cvt_pk_bf16(a.z, a.w);
    ov.z = cvt_pk_bf16(bq.x, bq.y);
    ov.w = cvt_pk_bf16(bq.z, bq.w);
    *(uint4*)&Y[((size_t)cg * 256 + o) * 8] = ov;
  } else {
    const size_t i = (size_t)(blk - 128) * 256 + threadIdx.x;  // 256*512
    const int oc = (int)(i >> 9);
    const int ic = (int)(i & 511);
    const float* src = fw + i * 9;
#pragma unroll
    for (int tap = 0; tap < 9; ++tap)
      wt[((size_t)tap * 256 + oc) * 512 + ic] = f2bf(src[tap]);
  }
}

// ---------------- MFMA GEMM ----------------
// Xbf: [(b*32+cg)][p][e], Wbf: [cg][o][e]. Block 64o x 128p, 4 waves.
// mode 1: bf16 [b*4+oy][p][dd]*oscale; 2: bf16 [b][o][p]; 3: bf16 cgroup.
__global__ __launch_bounds__(256) void gemm_mfma_kernel(
    const unsigned short* __restrict__ Xbf, const unsigned short* __restrict__ Wbf,
    void* __restrict__ Yv, int mode, float oscale) {
  __shared__ unsigned short W_l[32][64][8];
  __shared__ unsigned short X_l[2][2][128][8];
  const int t = threadIdx.x;
  const int w = t >> 6;
  const int l = t & 63;
  const int n = l & 31;
  const int g32 = l >> 5;
  const int p0 = blockIdx.x * 128;
  const int o0 = blockIdx.y * 64;
  const int b = blockIdx.z;
  const int wo = w >> 1, wp = w & 1;
  const unsigned short* Xb = Xbf + (size_t)b * 32 * HW_ * 8;

  for (int i = t; i < 2048; i += 256) {
    const int ksg = i >> 6, oc = i & 63;
    gld_lds16(Wbf + ((size_t)ksg * 256 + o0 + oc) * 8, &W_l[0][0][0] + (size_t)i * 8);
  }
  {
    const int gg = t >> 7, pp = t & 127;
    gld_lds16(Xb + ((size_t)gg * HW_ + p0 + pp) * 8, &X_l[0][0][0][0] + (size_t)t * 8);
  }
  f32x16 acc[2] = {};
  int buf = 0;
  for (int ks = 0; ks < 16; ++ks) {
    asm volatile("s_waitcnt vmcnt(0)" ::: "memory");
    __syncthreads();
    if (ks < 15) {
      const int gg = t >> 7, pp = t & 127;
      gld_lds16(Xb + ((size_t)((ks + 1) * 2 + gg) * HW_ + p0 + pp) * 8,
                &X_l[buf ^ 1][0][0][0] + (size_t)t * 8);
    }
    bf16x8 af = *(const bf16x8*)&W_l[ks * 2 + g32][wo * 32 + n][0];
    bf16x8 b0 = *(const bf16x8*)&X_l[buf][g32][wp * 64 + n][0];
    bf16x8 b1 = *(const bf16x8*)&X_l[buf][g32][wp * 64 + 32 + n][0];
    acc[0] = __builtin_amdgcn_mfma_f32_32x32x16_bf16(af, b0, acc[0], 0, 0, 0);
    acc[1] = __builtin_amdgcn_mfma_f32_32x32x16_bf16(af, b1, acc[1], 0, 0, 0);
    buf ^= 1;
  }

  if (mode == 1) {
    unsigned short* Y = (unsigned short*)Yv;
    const size_t bh = (size_t)b * 4 + blockIdx.y;
#pragma unroll
    for (int pf = 0; pf < 2; ++pf) {
      const int p = p0 + wp * 64 + pf * 32 + n;
      unsigned short* dst = Y + (bh * HW_ + p) * 64 + wo * 32 + 4 * g32;
#pragma unroll
      for (int q = 0; q < 4; ++q) {
        uint2 uu;
        uu.x = cvt_pk_bf16(acc[pf][q * 4 + 0] * oscale, acc[pf][q * 4 + 1] * oscale);
        uu.y = cvt_pk_bf16(acc[pf][q * 4 + 2] * oscale, acc[pf][q * 4 + 3] * oscale);
        *(uint2*)&dst[8 * q] = uu;
      }
    }
  } else if (mode == 2) {
    unsigned short* Y = (unsigned short*)Yv;
#pragma unroll
    for (int pf = 0; pf < 2; ++pf) {
      const int p = p0 + wp * 64 + pf * 32 + n;
#pragma unroll
      for (int r = 0; r < 16; ++r) {
        const int m = (r & 3) + 8 * (r >> 2) + 4 * g32;
        Y[((size_t)b * 256 + o0 + wo * 32 + m) * HW_ + p] = f2bf(acc[pf][r]);
      }
    }
  } else {  // mode 3: bf16 cgroup [(b*32+cg)][p][e]
    unsigned short* Y = (unsigned short*)Yv;
    const int cgb = (o0 + wo * 32) >> 3;
#pragma unroll
    for (int pf = 0; pf < 2; ++pf) {
      const int p = p0 + wp * 64 + pf * 32 + n;
#pragma unroll
      for (int q = 0; q < 4; ++q) {
        uint2 uu;
        uu.x = cvt_pk_bf16(acc[pf][q * 4 + 0], acc[pf][q * 4 + 1]);
        uu.y = cvt_pk_bf16(acc[pf][q * 4 + 2], acc[pf][q * 4 + 3]);
        *(uint2*)&Y[((size_t)(b * 32 + cgb + q) * HW_ + p) * 8 + 4 * g32] = uu;
      }
    }
  }
}

// ---------------- MFMA flash attention, K-split=2 (no-max softmax) ----------------
#define ATTN_STAGE(BUF, KP, VP)                                              \
  {                                                                          \
    gld_lds16((KP), &k_l[BUF][16 * w][0]);                                   \
    gld_lds16((KP) + (size_t)8 * 64, &k_l[BUF][16 * w + 8][0]);              \
    gld_lds16((VP), &v_l[BUF][16 * w][0]);                                   \
    gld_lds16((VP) + (size_t)8 * HW_, &v_l[BUF][16 * w + 8][0]);             \
  }

#define ATTN_COMPUTE(BUF)                                                    \
  {                                                                          \
    f32x4 accS[2][4];                                                        \
    _Pragma("unroll") for (int jt = 0; jt < 4; ++jt) {                       \
      const int jrow = jt * 16 + c;                                          \
      bf16x8 kf0 = *(const bf16x8*)&k_l[BUF][jrow][((0 + g) ^ (c & 7)) * 8]; \
      bf16x8 kf1 = *(const bf16x8*)&k_l[BUF][jrow][((4 + g) ^ (c & 7)) * 8]; \
      _Pragma("unroll") for (int qt = 0; qt < 2; ++qt) {                     \
        f32x4 s0 = __builtin_amdgcn_mfma_f32_16x16x32_bf16(kf0, qf[qt][0], zero4, 0, 0, 0); \
        accS[qt][jt] = __builtin_amdgcn_mfma_f32_16x16x32_bf16(kf1, qf[qt][1], s0, 0, 0, 0); \
      }                                                                      \
    }                                                                        \
    uint32_t pwu[2][2][4];                                                   \
    _Pragma("unroll") for (int qt = 0; qt < 2; ++qt) {                       \
      float rs = 0.f;                                                        \
      _Pragma("unroll") for (int jt = 0; jt < 4; ++jt) {                     \
        const float e0 = __builtin_amdgcn_exp2f(accS[qt][jt][0]);            \
        const float e1 = __builtin_amdgcn_exp2f(accS[qt][jt][1]);            \
        const float e2 = __builtin_amdgcn_exp2f(accS[qt][jt][2]);            \
        const float e3 = __builtin_amdgcn_exp2f(accS[qt][jt][3]);            \
        rs += (e0 + e1) + (e2 + e3);                                         \
        pwu[qt][jt >> 1][(jt & 1) * 2 + 0] = cvt_pk_bf16(e0, e1);            \
        pwu[qt][jt >> 1][(jt & 1) * 2 + 1] = cvt_pk_bf16(e2, e3);            \
      }                                                                      \
      l_r[qt] += rs;                                                         \
    }                                                                        \
    bf16x8 pf[2][2];                                                         \
    _Pragma("unroll") for (int qt = 0; qt < 2; ++qt)                         \
    _Pragma("unroll") for (int kb = 0; kb < 2; ++kb) {                       \
      u32x4 tmp = {pwu[qt][kb][0], pwu[qt][kb][1], pwu[qt][kb][2], pwu[qt][kb][3]}; \
      pf[qt][kb] = __builtin_bit_cast(bf16x8, tmp);                          \
    }                                                                        \
    _Pragma("unroll") for (int dt = 0; dt < 4; ++dt) {                       \
      const int row = dt * 16 + c;                                           \
      const int sw = c & 7;                                                  \
      _Pragma("unroll") for (int kb = 0; kb < 2; ++kb) {                     \
        union { short4v h[2]; bf16x8 v8; } vv;                               \
        vv.h[0] = *(const short4v*)&v_l[BUF][row][(((kb * 4 + 0) + (g >> 1)) ^ sw) * 8 + (g & 1) * 4]; \
        vv.h[1] = *(const short4v*)&v_l[BUF][row][(((kb * 4 + 2) + (g >> 1)) ^ sw) * 8 + (g & 1) * 4]; \
        accO[0][dt] = __builtin_amdgcn_mfma_f32_16x16x32_bf16(vv.v8, pf[0][kb], accO[0][dt], 0, 0, 0); \
        accO[1][dt] = __builtin_amdgcn_mfma_f32_16x16x32_bf16(vv.v8, pf[1][kb], accO[1][dt], 0, 0, 0); \
      }                                                                      \
    }                                                                        \
  }

__global__ __launch_bounds__(256) void attn_mfma_kernel(
    const unsigned short* __restrict__ Qb, const unsigned short* __restrict__ Kb,
    const unsigned short* __restrict__ Vb, unsigned short* __restrict__ Op0,
    unsigned short* __restrict__ Op1, float* __restrict__ lpart) {
  __shared__ unsigned short k_l[2][64][64];
  __shared__ unsigned short v_l[2][64][64];
  const int t = threadIdx.x;
  const int w = t >> 6;
  const int l = t & 63;
  const int g = l >> 4;
  const int c = l & 15;
  const int bid = blockIdx.x;
  // 1024 blocks; 128 per XCD => 2 bn per XCD (K/V stay L2-resident)
  const int gidx = (bid & 7) * 128 + (bid >> 3);
  const int bn = gidx >> 6;
  const int sq = gidx & 63;
  const int split = sq >> 5;
  const int q0 = (sq & 31) * 128 + w * 32;

  bf16x8 qf[2][2];
#pragma unroll
  for (int qt = 0; qt < 2; ++qt)
#pragma unroll
    for (int dh = 0; dh < 2; ++dh)
      qf[qt][dh] = *(const bf16x8*)&Qb[((size_t)bn * HW_ + q0 + qt * 16 + c) * 64 + dh * 32 + g * 8];

  const int srow = 16 * w + (l >> 3);
  const int schunk = (l & 7) ^ ((l >> 3) & 7);
  const unsigned short* gKp = Kb + ((size_t)bn * HW_ + split * 2048 + srow) * 64 + schunk * 8;
  const unsigned short* gVp = Vb + ((size_t)bn * 64 + srow) * HW_ + split * 2048 + schunk * 8;

  f32x4 accO[2][4] = {};
  float l_r[2] = {0.f, 0.f};
  const f32x4 zero4 = {0.f, 0.f, 0.f, 0.f};

  ATTN_STAGE(0, gKp, gVp);
  gKp += 4096; gVp += 64;

  for (int kt2 = 0; kt2 < 16; ++kt2) {
    asm volatile("s_waitcnt vmcnt(0)" ::: "memory");
    __syncthreads();
    ATTN_STAGE(1, gKp, gVp);
    gKp += 4096; gVp += 64;
    ATTN_COMPUTE(0)
    asm volatile("s_waitcnt vmcnt(0)" ::: "memory");
    __syncthreads();
    if (kt2 < 15) {
      ATTN_STAGE(0, gKp, gVp);
      gKp += 4096; gVp += 64;
    }
    ATTN_COMPUTE(1)
  }

  // epilogue: store UNNORMALIZED O (bf16) + partial l (fp32)
  unsigned short* Op = split ? Op1 : Op0;
#pragma unroll
  for (int qt = 0; qt < 2; ++qt) {
    float s = l_r[qt];
    s += __shfl_xor(s, 16);
    s += __shfl_xor(s, 32);
    const int p = q0 + qt * 16 + c;
    if (l < 16) lpart[((size_t)split * 16 + bn) * HW_ + p] = s;
#pragma unroll
    for (int dt = 0; dt < 4; ++dt) {
      uint2 uu;
      uu.x = cvt_pk_bf16(accO[qt][dt][0], accO[qt][dt][1]);
      uu.y = cvt_pk_bf16(accO[qt][dt][2], accO[qt][dt][3]);
      *(uint2*)&Op[((size_t)bn * HW_ + p) * 64 + dt * 16 + g * 4] = uu;
    }
  }
}

// ---------------- combine: O = (O1+O2)/(l1+l2) -> bf16 cgroup for proj ----------------
__global__ __launch_bounds__(256) void attn_combine_kernel(
    const unsigned short* __restrict__ Op0, const unsigned short* __restrict__ Op1,
    const float* __restrict__ lpart, unsigned short* __restrict__ Abf) {
  const int tg = blockIdx.x * 256 + threadIdx.x;  // 524288
  const int dg = tg & 7;
  const int q = (tg >> 3) & 4095;
  const int bn = tg >> 15;
  const size_t oidx = ((size_t)bn * HW_ + q) * 64 + dg * 8;
  uint4 a = *(const uint4*)&Op0[oidx];
  uint4 b2 = *(const uint4*)&Op1[oidx];
  const float lsum = lpart[(size_t)bn * HW_ + q] + lpart[(size_t)(16 + bn) * HW_ + q];
  const float inv = 1.0f / lsum;
  const uint32_t ua[4] = {a.x, a.y, a.z, a.w};
  const uint32_t ub[4] = {b2.x, b2.y, b2.z, b2.w};
  uint32_t o[4];
#pragma unroll
  for (int k = 0; k < 4; ++k) {
    const float lo = (bf_lo(ua[k]) + bf_lo(ub[k])) * inv;
    const float hi = (bf_hi(ua[k]) + bf_hi(ub[k])) * inv;
    o[k] = cvt_pk_bf16(lo, hi);
  }
  const int head = bn & 3, bb = bn >> 2;
  const int cg = head * 8 + dg;
  uint4 ov = {o[0], o[1], o[2], o[3]};
  *(uint4*)&Abf[((size_t)(bb * 32 + cg) * HW_ + q) * 8] = ov;
}

// ---------------- SE pooling from bf16 cgroup, p-split x2 (raw sums; merged in se) ----------------
__global__ __launch_bounds__(256) void pool_kernel(
    const unsigned short* __restrict__ Pbf, const unsigned short* __restrict__ Gbf,
    float* __restrict__ psum, float* __restrict__ pmaxH) {
  const int cg = blockIdx.x;  // 0..31
  const int b = blockIdx.y;
  const int half = blockIdx.z;
  const int t = threadIdx.x;
  const unsigned short* P = Pbf + ((size_t)(b * 32 + cg) * HW_ + half * 2048) * 8;
  const unsigned short* G = Gbf + ((size_t)(b * 32 + cg) * HW_ + half * 2048) * 8;
  float s[16], m[16];
#pragma unroll
  for (int i = 0; i < 16; ++i) { s[i] = 0.f; m[i] = -1e30f; }
  for (int p = t; p < 2048; p += 256) {
    uint4 a = *(const uint4*)&P[(size_t)p * 8];
    uint4 gg = *(const uint4*)&G[(size_t)p * 8];
    const uint32_t ua[4] = {a.x, a.y, a.z, a.w};
    const uint32_t ug[4] = {gg.x, gg.y, gg.z, gg.w};
#pragma unroll
    for (int q = 0; q < 4; ++q) {
      const float a0 = bf_lo(ua[q]), a1 = bf_hi(ua[q]);
      const float g0 = bf_lo(ug[q]), g1 = bf_hi(ug[q]);
      s[q * 2] += a0; s[q * 2 + 1] += a1;
      m[q * 2] = fmaxf(m[q * 2], a0); m[q * 2 + 1] = fmaxf(m[q * 2 + 1], a1);
      s[8 + q * 2] += g0; s[8 + q * 2 + 1] += g1;
      m[8 + q * 2] = fmaxf(m[8 + q * 2], g0); m[8 + q * 2 + 1] = fmaxf(m[8 + q * 2 + 1], g1);
    }
  }
#pragma unroll
  for (int i = 0; i < 16; ++i)
#pragma unroll
    for (int off = 1; off < 64; off <<= 1) {
      s[i] += __shfl_xor(s[i], off);
      m[i] = fmaxf(m[i], __shfl_xor(m[i], off));
    }
  __shared__ float red[4][32];
  const int wv = t >> 6;
  if ((t & 63) == 0) {
#pragma unroll
    for (int i = 0; i < 16; ++i) { red[wv][i] = s[i]; red[wv][16 + i] = m[i]; }
  }
  __syncthreads();
  if (t < 32) {
    const float v0 = red[0][t], v1 = red[1][t], v2 = red[2][t], v3 = red[3][t];
    if (t < 16) {
      const int ch = (t < 8) ? cg * 8 + t : 256 + cg * 8 + (t - 8);
      psum[half * 2048 + b * 512 + ch] = v0 + v1 + v2 + v3;
    } else {
      const int i = t - 16;
      const int ch = (i < 8) ? cg * 8 + i : 256 + cg * 8 + (i - 8);
      pmaxH[half * 2048 + b * 512 + ch] = fmaxf(fmaxf(v0, v1), fmaxf(v2, v3));
    }
  }
}

// ---------------- SE MLP (merges pool halves) ----------------
__global__ __launch_bounds__(256) void se_kernel(
    const float* __restrict__ psum, const float* __restrict__ pmaxH,
    const float* __restrict__ w1, const float* __restrict__ w2,
    float* __restrict__ wch) {
  const int b = blockIdx.x;
  const int t = threadIdx.x;
  __shared__ float za[512], zm[512], hs[64];
  za[t] = (psum[b * 512 + t] + psum[2048 + b * 512 + t]) * (1.f / 4096.f);
  za[256 + t] = (psum[b * 512 + 256 + t] + psum[2048 + b * 512 + 256 + t]) * (1.f / 4096.f);
  zm[t] = fmaxf(pmaxH[b * 512 + t], pmaxH[2048 + b * 512 + t]);
  zm[256 + t] = fmaxf(pmaxH[b * 512 + 256 + t], pmaxH[2048 + b * 512 + 256 + t]);
  __syncthreads();
  if (t < 64) {
    float ha = 0.f, hm = 0.f;
    for (int c = 0; c < 512; ++c) {
      const float w = w1[t * 512 + c];
      ha += w * za[c];
      hm += w * zm[c];
    }
    hs[t] = fmaxf(ha, 0.f) + fmaxf(hm, 0.f);
  }
  __syncthreads();
  for (int o = t; o < 512; o += 256) {
    float acc = 0.f;
#pragma unroll
    for (int hh = 0; hh < 64; ++hh) acc += hs[hh] * w2[o * 64 + hh];
    wch[b * 512 + o] = 1.f / (1.f + __expf(-acc));
  }
}

// ---------------- spatial-attention input: 4 ch-slices per block, LDS combine ----------------
__global__ __launch_bounds__(256) void sa_reduce_kernel(
    const unsigned short* __restrict__ Pbf, const unsigned short* __restrict__ Gbf,
    const float* __restrict__ wch, float* __restrict__ sa_in) {
  const int b = blockIdx.y;
  const int t = threadIdx.x;
  const int px = t & 63;
  const int sl = t >> 6;
  const int p = blockIdx.x * 64 + px;
  __shared__ float wl[512];
  __shared__ float sred[4][64], mred[4][64];
  wl[t] = wch[b * 512 + t];
  wl[256 + t] = wch[b * 512 + 256 + t];
  __syncthreads();
  float s = 0.f, mx = -1e30f;
#pragma unroll 4
  for (int k = 0; k < 16; ++k) {
    const int chunk = sl * 16 + k;  // 0..63: proj 0..31, gray 32..63
    const unsigned short* src = (chunk < 32)
        ? &Pbf[((size_t)(b * 32 + chunk) * HW_ + p) * 8]
        : &Gbf[((size_t)(b * 32 + (chunk - 32)) * HW_ + p) * 8];
    uint4 a = *(const uint4*)src;
    const uint32_t u[4] = {a.x, a.y, a.z, a.w};
#pragma unroll
    for (int q = 0; q < 4; ++q) {
      const float v0 = bf_lo(u[q]) * wl[chunk * 8 + q * 2];
      const float v1 = bf_hi(u[q]) * wl[chunk * 8 + q * 2 + 1];
      s += v0 + v1;
      mx = fmaxf(mx, fmaxf(v0, v1));
    }
  }
  sred[sl][px] = s;
  mred[sl][px] = mx;
  __syncthreads();
  if (sl == 0) {
    const float S = sred[0][px] + sred[1][px] + sred[2][px] + sred[3][px];
    const float M = fmaxf(fmaxf(mred[0][px], mred[1][px]), fmaxf(mred[2][px], mred[3][px]));
    sa_in[((size_t)b * 2 + 0) * HW_ + p] = S * (1.f / 512.f);
    sa_in[((size_t)b * 2 + 1) * HW_ + p] = M;
  }
}

// ---------------- 7x7 spatial conv + sigmoid -> wsp ----------------
__global__ __launch_bounds__(256) void sa_conv_kernel(
    const float* __restrict__ sa_in, const float* __restrict__ sa_w,
    float* __restrict__ wsp) {
  const int b = blockIdx.y;
  const int t = threadIdx.x;
  __shared__ float pl[2][64][64];
  __shared__ float wl[98];
  for (int e = t; e < 8192; e += 256) ((float*)pl)[e] = sa_in[(size_t)b * 8192 + e];
  if (t < 98) wl[t] = sa_w[t];
  __syncthreads();
  const int pix = blockIdx.x * 256 + t;
  const int y = pix >> 6, x = pix & 63;
  float acc = 0.f;
#pragma unroll
  for (int ic = 0; ic < 2; ++ic)
#pragma unroll
    for (int ky = 0; ky < 7; ++ky) {
      const int yy = y + ky - 3;
      if (yy < 0 || yy > 63) continue;
#pragma unroll
      for (int kx = 0; kx < 7; ++kx) {
        const int xx = x + kx - 3;
        if (xx < 0 || xx > 63) continue;
        acc += pl[ic][yy][xx] * wl[ic * 49 + ky * 7 + kx];
      }
    }
  wsp[(size_t)b * HW_ + pix] = 1.f / (1.f + __expf(-acc));
}

// ---------------- gate: catg[b][yp:66][xi:80][ic:512] bf16 (NHWC, halo=0) ----------------
__global__ __launch_bounds__(256) void gate_kernel(
    const unsigned short* __restrict__ Pbf, const unsigned short* __restrict__ Gbf,
    const float* __restrict__ wch, const float* __restrict__ wsp,
    unsigned short* __restrict__ catg) {
  const int yp = blockIdx.x;  // 0..65
  const int b = blockIdx.y;
  const int t = threadIdx.x;
  unsigned short* rowp = catg + ((size_t)b * 66 + yp) * 80 * 512;
  if (yp == 0 || yp == 65) {
    short8v z = {};
    for (int m = t; m < 5120; m += 256) *(short8v*)&rowp[m * 8] = z;
    return;
  }
  const int y = yp - 1;
  __shared__ unsigned short tile[64][512];  // [x][ch], chunk XOR-swizzled by (x&7)
  __shared__ float wchl[512];
  __shared__ float wspl[64];
  for (int e = t; e < 512; e += 256) wchl[e] = wch[b * 512 + e];
  if (t < 64) wspl[t] = wsp[(size_t)b * HW_ + y * 64 + t];
  {
    short8v z = {};
    for (int m = t; m < 1024; m += 256) {
      const int col = m >> 6;
      const int xi = (col < 8) ? col : (col + 64);
      *(short8v*)&rowp[(size_t)xi * 512 + (m & 63) * 8] = z;
    }
  }
  __syncthreads();
  const int x = t & 63;
  const int cs = t >> 6;
  const float wx = wspl[x];
#pragma unroll
  for (int k = 0; k < 16; ++k) {
    const int chunk = cs * 16 + k;  // 0..63 (proj: 0..31, gray: 32..63)
    const unsigned short* src = (chunk < 32)
        ? &Pbf[((size_t)(b * 32 + chunk) * HW_ + y * 64 + x) * 8]
        : &Gbf[((size_t)(b * 32 + (chunk - 32)) * HW_ + y * 64 + x) * 8];
    uint4 a = *(const uint4*)src;
    const uint32_t u[4] = {a.x, a.y, a.z, a.w};
    uint32_t o[4];
#pragma unroll
    for (int q = 0; q < 4; ++q) {
      const float lo = bf_lo(u[q]) * wchl[chunk * 8 + q * 2] * wx;
      const float hi = bf_hi(u[q]) * wchl[chunk * 8 + q * 2 + 1] * wx;
      o[q] = cvt_pk_bf16(lo, hi);
    }
    uint4 ov = {o[0], o[1], o[2], o[3]};
    *(uint4*)&tile[x][(chunk ^ (x & 7)) * 8] = ov;
  }
  __syncthreads();
#pragma unroll
  for (int j = 0; j < 16; ++j) {
    const int xi = (t >> 6) + 4 * j;
    const int c8 = t & 63;
    uint4 v = *(const uint4*)&tile[xi][(c8 ^ (xi & 7)) * 8];
    *(uint4*)&rowp[(size_t)(xi + 8) * 512 + c8 * 8] = v;
  }
}

// ---------------- fuse conv via MFMA: 32-oc tiles, 512 blocks, XCD-grouped ----------------
__global__ __launch_bounds__(256) void fuse_mfma_kernel(
    const unsigned short* __restrict__ catg, const unsigned short* __restrict__ wt,
    const float* __restrict__ bn_g, const float* __restrict__ bn_b,
    const float* __restrict__ bn_m, const float* __restrict__ bn_v,
    float* __restrict__ out) {
  __shared__ unsigned short X_l[2][6][2][80][8];  // 30 KiB
  __shared__ unsigned short W_l[2][9][2][32][8];  // 18 KiB
  __shared__ float invl[32], shl[32];
  const int t = threadIdx.x;
  const int w = t >> 6;
  const int l = t & 63;
  const int n = l & 31;
  const int g = l >> 5;
  // 8 oc-tiles of the same (y,b) share an XCD -> catg L2 reuse
  const int i = blockIdx.x;
  const int xcd = i & 7, slot = i >> 3;  // slot 0..63
  const int ocB = slot & 7;
  const int yb = xcd + 8 * (slot >> 3);  // 0..63
  const int y0 = (yb & 15) * 4;
  const int o0 = ocB * 32;
  const int b = yb >> 4;

  if (t < 32) {
    const float iv = bn_g[o0 + t] * rsqrtf(bn_v[o0 + t] + 1e-5f);
    invl[t] = iv;
    shl[t] = bn_b[o0 + t] - bn_m[o0 + t] * iv;
  }

  const unsigned short* catb = catg + ((size_t)b * 66 + y0) * 80 * 512;

  auto stageX = [&](int bi, int ic0) {
    for (int wc = w; wc < 15; wc += 4) {
      const int m = wc * 64 + l;
      const int lr = m / 160;
      const int rem = m - lr * 160;
      const int half = rem / 80;
      const int xi = rem - half * 80;
      gld_lds16(catb + ((size_t)lr * 80 + xi) * 512 + ic0 + half * 8,
                &X_l[bi][0][0][0][0] + (size_t)wc * 512);
    }
  };
  auto stageW = [&](int bi, int ic0) {
    for (int wc = w; wc < 9; wc += 4) {
      const int m = wc * 64 + l;
      const int tap = m >> 6;
      const int rem = m & 63;
      const int half = rem >> 5;
      const int oc = rem & 31;
      gld_lds16(wt + ((size_t)tap * 256 + o0 + oc) * 512 + ic0 + half * 8,
                &W_l[bi][0][0][0][0] + (size_t)wc * 512);
    }
  };

  f32x16 acc[2] = {};

  stageX(0, 0);
  stageW(0, 0);
  int buf = 0;
  for (int ks = 0; ks < 32; ++ks) {
    asm volatile("s_waitcnt vmcnt(0)" ::: "memory");
    __syncthreads();
    if (ks < 31) {
      stageX(buf ^ 1, (ks + 1) * 16);
      stageW(buf ^ 1, (ks + 1) * 16);
    }
#pragma unroll
    for (int ky = 0; ky < 3; ++ky) {
      const int lr = w + ky;
#pragma unroll
      for (int kx = 0; kx < 3; ++kx) {
        const int tap = ky * 3 + kx;
        bf16x8 a0 = *(const bf16x8*)&W_l[buf][tap][g][n][0];
        bf16x8 b0 = *(const bf16x8*)&X_l[buf][lr][g][n + kx + 7][0];
        bf16x8 b1 = *(const bf16x8*)&X_l[buf][lr][g][32 + n + kx + 7][0];
        acc[0] = __builtin_amdgcn_mfma_f32_32x32x16_bf16(a0, b0, acc[0], 0, 0, 0);
        acc[1] = __builtin_amdgcn_mfma_f32_32x32x16_bf16(a0, b1, acc[1], 0, 0, 0);
      }
    }
    buf ^= 1;
  }

#pragma unroll
  for (int pf = 0; pf < 2; ++pf)
#pragma unroll
    for (int r = 0; r < 16; ++r) {
      const int row = (r & 3) + 8 * (r >> 2) + 4 * g;
      const float yv = acc[pf][r] * invl[row] + shl[row];
      const float ov = yv > 0.f ? yv : 0.2f * yv;
      out[((size_t)b * 256 + o0 + row) * HW_ + (size_t)(y0 + w) * 64 + pf * 32 + n] = ov;
    }
}

extern "C" void kernel_launch(void* const* d_in, const int* in_sizes, int n_in,
                              void* d_out, int out_size, void* d_ws, size_t ws_size,
                              hipStream_t stream) {
  const float* color  = (const float*)d_in[0];
  const float* gray   = (const float*)d_in[1];
  const float* Wq     = (const float*)d_in[2];
  const float* Wk     = (const float*)d_in[3];
  const float* Wv     = (const float*)d_in[4];
  const float* Wproj  = (const float*)d_in[5];
  const float* ca_w1  = (const float*)d_in[6];
  const float* ca_w2  = (const float*)d_in[7];
  const float* sa_w   = (const float*)d_in[8];
  const float* fuse_w = (const float*)d_in[9];
  const float* bn_g   = (const float*)d_in[10];
  const float* bn_b   = (const float*)d_in[11];
  const float* bn_m   = (const float*)d_in[12];
  const float* bn_v   = (const float*)d_in[13];
  float* out = (float*)d_out;

  char* ws = (char*)d_ws;
  // Overlay (MiB):
  // [0,8)   Cbf -> Opart0 (attn epi) -> Pbf (proj out)
  // [8,16)  Gbf (live through gate)
  // [16,24) Qbf -> Abf (combine out)
  // [24,32) Kbf \ dead after attn -> catg [24,44.63)
  // [32,40) Vbf /
  // [45,45.5) WqB..WpB; [45.5,47.75) Wt
  // [48,56) Opart1; [56,56.5) lpart; [57,...) smalls
  unsigned short* Cbf = (unsigned short*)(ws);
  unsigned short* Gbf = (unsigned short*)(ws + (8u << 20));
  unsigned short* Qbf = (unsigned short*)(ws + (16u << 20));
  unsigned short* Kbf = (unsigned short*)(ws + (24u << 20));
  unsigned short* Vbf = (unsigned short*)(ws + (32u << 20));
  unsigned short* Abf = (unsigned short*)(ws + (16u << 20));
  unsigned short* Pbf = (unsigned short*)(ws);
  unsigned short* Op0 = (unsigned short*)(ws);
  unsigned short* Op1 = (unsigned short*)(ws + (48u << 20));
  float* lpart        = (float*)(ws + (56u << 20));
  unsigned short* catg = (unsigned short*)(ws + (24u << 20));
  unsigned short* WqB = (unsigned short*)(ws + (45u << 20));
  unsigned short* WkB = WqB + 65536;
  unsigned short* WvB = WkB + 65536;
  unsigned short* WpB = WvB + 65536;
  unsigned short* Wt  = (unsigned short*)(ws + (45u << 20) + (1u << 19));
  float* psum  = (float*)(ws + (57u << 20));  // [2][2048]
  float* pmaxH = psum + 4096;                 // [2][2048]
  float* wch   = pmaxH + 4096;
  float* sa_in = wch + 2048;     // 32768
  float* wsp   = sa_in + 32768;  // 16384
  (void)in_sizes; (void)n_in; (void)out_size; (void)ws_size;

  const float qscale = 0.125f * 1.44269504f;

  prep_kernel<<<dim3(640), 256, 0, stream>>>(Wq, Wk, Wv, Wproj, fuse_w,
                                             WqB, WkB, WvB, WpB, Wt);
  xconv_kernel<<<dim3(2048), 256, 0, stream>>>(color, Cbf);
  xconv_kernel<<<dim3(2048), 256, 0, stream>>>(gray, Gbf);

  dim3 g_gemm(32, 4, 4);
  gemm_mfma_kernel<<<g_gemm, 256, 0, stream>>>(Cbf, WqB, Qbf, 1, qscale);
  gemm_mfma_kernel<<<g_gemm, 256, 0, stream>>>(Gbf, WkB, Kbf, 1, 1.0f);
  gemm_mfma_kernel<<<g_gemm, 256, 0, stream>>>(Gbf, WvB, Vbf, 2, 1.0f);
  attn_mfma_kernel<<<dim3(1024), 256, 0, stream>>>(Qbf, Kbf, Vbf, Op0, Op1, lpart);
  attn_combine_kernel<<<dim3(2048), 256, 0, stream>>>(Op0, Op1, lpart, Abf);
  gemm_mfma_kernel<<<g_gemm, 256, 0, stream>>>(Abf, WpB, Pbf, 3, 1.0f);

  pool_kernel<<<dim3(32, 4, 2), 256, 0, stream>>>(Pbf, Gbf, psum, pmaxH);
  se_kernel<<<dim3(4), 256, 0, stream>>>(psum, pmaxH, ca_w1, ca_w2, wch);
  sa_reduce_kernel<<<dim3(64, 4), 256, 0, stream>>>(Pbf, Gbf, wch, sa_in);
  sa_conv_kernel<<<dim3(16, 4), 256, 0, stream>>>(sa_in, sa_w, wsp);
  gate_kernel<<<dim3(66, 4), 256, 0, stream>>>(Pbf, Gbf, wch, wsp, catg);
  fuse_mfma_kernel<<<dim3(512), 256, 0, stream>>>(catg, Wt, bn_g, bn_b, bn_m, bn_v, out);
}

// Round 7
// 253.412 us; speedup vs baseline: 8.4629x; 1.0556x over previous
//
#include <hip/hip_runtime.h>
#include <hip/hip_bf16.h>
#include <stdint.h>

#define HW_ 4096

typedef short bf16x8 __attribute__((ext_vector_type(8)));
typedef short short4v __attribute__((ext_vector_type(4)));
typedef short short8v __attribute__((ext_vector_type(8)));
typedef float f32x4 __attribute__((ext_vector_type(4)));
typedef float f32x16 __attribute__((ext_vector_type(16)));
typedef uint32_t u32x4 __attribute__((ext_vector_type(4)));

__device__ inline unsigned short f2bf(float x) {
  uint32_t u = __builtin_bit_cast(uint32_t, x);
  uint32_t r = ((u >> 16) & 1u) + 0x7fffu;
  return (unsigned short)((u + r) >> 16);
}
__device__ inline uint32_t cvt_pk_bf16(float lo, float hi) {
  uint32_t r;
  asm("v_cvt_pk_bf16_f32 %0, %1, %2" : "=v"(r) : "v"(lo), "v"(hi));
  return r;
}
__device__ inline float bf_lo(uint32_t u) { return __builtin_bit_cast(float, u << 16); }
__device__ inline float bf_hi(uint32_t u) { return __builtin_bit_cast(float, u & 0xffff0000u); }
__device__ inline void gld_lds16(const unsigned short* g, unsigned short* l) {
  __builtin_amdgcn_global_load_lds((const __attribute__((address_space(1))) void*)g,
                                   (__attribute__((address_space(3))) void*)l, 16, 0, 0);
}

// ---------------- xconv: fp32 [b][c][p] -> bf16 cgroup layout [(b*32+cg)][p][e] ----------------
__global__ __launch_bounds__(256) void xconv_kernel(
    const float* __restrict__ X, unsigned short* __restrict__ Y) {
  const int i = blockIdx.x * 256 + threadIdx.x;
  const int p = i & 4095;
  const int cg = (i >> 12) & 31;
  const int b = i >> 17;
  const float* src = X + ((size_t)b * 256 + cg * 8) * HW_ + p;
  float v[8];
#pragma unroll
  for (int e = 0; e < 8; ++e) v[e] = src[(size_t)e * HW_];
  uint4 o;
  o.x = cvt_pk_bf16(v[0], v[1]);
  o.y = cvt_pk_bf16(v[2], v[3]);
  o.z = cvt_pk_bf16(v[4], v[5]);
  o.w = cvt_pk_bf16(v[6], v[7]);
  *(uint4*)&Y[((size_t)(b * 32 + cg) * HW_ + p) * 8] = o;
}

// ---------------- prep: 4x wconv (fp32 W[o][c] -> bf16 [cg][o][e]) + wtrans ----------------
__global__ __launch_bounds__(256) void prep_kernel(
    const float* __restrict__ Wq, const float* __restrict__ Wk,
    const float* __restrict__ Wv, const float* __restrict__ Wp,
    const float* __restrict__ fw,
    unsigned short* __restrict__ WqB, unsigned short* __restrict__ WkB,
    unsigned short* __restrict__ WvB, unsigned short* __restrict__ WpB,
    unsigned short* __restrict__ wt) {
  const int blk = blockIdx.x;
  if (blk < 128) {
    const int which = blk >> 5;
    const float* W = which == 0 ? Wq : which == 1 ? Wk : which == 2 ? Wv : Wp;
    unsigned short* Y = which == 0 ? WqB : which == 1 ? WkB : which == 2 ? WvB : WpB;
    const int i = (blk & 31) * 256 + threadIdx.x;  // 8192
    const int o = i & 255;
    const int cg = i >> 8;
    float4 a = *(const float4*)&W[(size_t)o * 256 + cg * 8];
    float4 bq = *(const float4*)&W[(size_t)o * 256 + cg * 8 + 4];
    uint4 ov;
    ov.x = cvt_pk_bf16(a.x, a.y);
    ov.y = cvt_pk_bf16(a.z, a.w);
    ov.z = cvt_pk_bf16(bq.x, bq.y);
    ov.w = cvt_pk_bf16(bq.z, bq.w);
    *(uint4*)&Y[((size_t)cg * 256 + o) * 8] = ov;
  } else {
    const size_t i = (size_t)(blk - 128) * 256 + threadIdx.x;  // 256*512
    const int oc = (int)(i >> 9);
    const int ic = (int)(i & 511);
    const float* src = fw + i * 9;
#pragma unroll
    for (int tap = 0; tap < 9; ++tap)
      wt[((size_t)tap * 256 + oc) * 512 + ic] = f2bf(src[tap]);
  }
}

// ---------------- MFMA GEMM ----------------
// Xbf: [(b*32+cg)][p][e], Wbf: [cg][o][e]. Block 64o x 128p, 4 waves.
// mode 1: bf16 [b*4+oy][p][dd]*oscale; 2: bf16 [b][o][p]; 3: bf16 cgroup.
__global__ __launch_bounds__(256) void gemm_mfma_kernel(
    const unsigned short* __restrict__ Xbf, const unsigned short* __restrict__ Wbf,
    void* __restrict__ Yv, int mode, float oscale) {
  __shared__ unsigned short W_l[32][64][8];
  __shared__ unsigned short X_l[2][2][128][8];
  const int t = threadIdx.x;
  const int w = t >> 6;
  const int l = t & 63;
  const int n = l & 31;
  const int g32 = l >> 5;
  const int p0 = blockIdx.x * 128;
  const int o0 = blockIdx.y * 64;
  const int b = blockIdx.z;
  const int wo = w >> 1, wp = w & 1;
  const unsigned short* Xb = Xbf + (size_t)b * 32 * HW_ * 8;

  for (int i = t; i < 2048; i += 256) {
    const int ksg = i >> 6, oc = i & 63;
    gld_lds16(Wbf + ((size_t)ksg * 256 + o0 + oc) * 8, &W_l[0][0][0] + (size_t)i * 8);
  }
  {
    const int gg = t >> 7, pp = t & 127;
    gld_lds16(Xb + ((size_t)gg * HW_ + p0 + pp) * 8, &X_l[0][0][0][0] + (size_t)t * 8);
  }
  f32x16 acc[2] = {};
  int buf = 0;
  for (int ks = 0; ks < 16; ++ks) {
    asm volatile("s_waitcnt vmcnt(0)" ::: "memory");
    __syncthreads();
    if (ks < 15) {
      const int gg = t >> 7, pp = t & 127;
      gld_lds16(Xb + ((size_t)((ks + 1) * 2 + gg) * HW_ + p0 + pp) * 8,
                &X_l[buf ^ 1][0][0][0] + (size_t)t * 8);
    }
    bf16x8 af = *(const bf16x8*)&W_l[ks * 2 + g32][wo * 32 + n][0];
    bf16x8 b0 = *(const bf16x8*)&X_l[buf][g32][wp * 64 + n][0];
    bf16x8 b1 = *(const bf16x8*)&X_l[buf][g32][wp * 64 + 32 + n][0];
    acc[0] = __builtin_amdgcn_mfma_f32_32x32x16_bf16(af, b0, acc[0], 0, 0, 0);
    acc[1] = __builtin_amdgcn_mfma_f32_32x32x16_bf16(af, b1, acc[1], 0, 0, 0);
    buf ^= 1;
  }

  if (mode == 1) {
    unsigned short* Y = (unsigned short*)Yv;
    const size_t bh = (size_t)b * 4 + blockIdx.y;
#pragma unroll
    for (int pf = 0; pf < 2; ++pf) {
      const int p = p0 + wp * 64 + pf * 32 + n;
      unsigned short* dst = Y + (bh * HW_ + p) * 64 + wo * 32 + 4 * g32;
#pragma unroll
      for (int q = 0; q < 4; ++q) {
        uint2 uu;
        uu.x = cvt_pk_bf16(acc[pf][q * 4 + 0] * oscale, acc[pf][q * 4 + 1] * oscale);
        uu.y = cvt_pk_bf16(acc[pf][q * 4 + 2] * oscale, acc[pf][q * 4 + 3] * oscale);
        *(uint2*)&dst[8 * q] = uu;
      }
    }
  } else if (mode == 2) {
    unsigned short* Y = (unsigned short*)Yv;
#pragma unroll
    for (int pf = 0; pf < 2; ++pf) {
      const int p = p0 + wp * 64 + pf * 32 + n;
#pragma unroll
      for (int r = 0; r < 16; ++r) {
        const int m = (r & 3) + 8 * (r >> 2) + 4 * g32;
        Y[((size_t)b * 256 + o0 + wo * 32 + m) * HW_ + p] = f2bf(acc[pf][r]);
      }
    }
  } else {  // mode 3: bf16 cgroup [(b*32+cg)][p][e]
    unsigned short* Y = (unsigned short*)Yv;
    const int cgb = (o0 + wo * 32) >> 3;
#pragma unroll
    for (int pf = 0; pf < 2; ++pf) {
      const int p = p0 + wp * 64 + pf * 32 + n;
#pragma unroll
      for (int q = 0; q < 4; ++q) {
        uint2 uu;
        uu.x = cvt_pk_bf16(acc[pf][q * 4 + 0], acc[pf][q * 4 + 1]);
        uu.y = cvt_pk_bf16(acc[pf][q * 4 + 2], acc[pf][q * 4 + 3]);
        *(uint2*)&Y[((size_t)(b * 32 + cgb + q) * HW_ + p) * 8 + 4 * g32] = uu;
      }
    }
  }
}

// ---------------- MFMA flash attention: 4-buf counted-vmcnt pipeline (T3/T4) ----------------
// k_l/v_l: 4 buffers x (64 rows x 64 ushort) each; per wave 4 gld_lds16 per stage.
#define ATTN_STAGE(SB)                                                       \
  {                                                                          \
    gld_lds16(gKp, kst + (SB) * 4096);                                       \
    gld_lds16(gKp + 8 * 64, kst + (SB) * 4096 + 512);                        \
    gld_lds16(gVp, vst + (SB) * 4096);                                       \
    gld_lds16(gVp + (size_t)8 * HW_, vst + (SB) * 4096 + 512);               \
    gKp += 4096;                                                             \
    gVp += 64;                                                               \
  }

#define ATTN_COMPUTE(BUF)                                                    \
  {                                                                          \
    f32x4 accS[2][4];                                                        \
    _Pragma("unroll") for (int jt = 0; jt < 4; ++jt) {                       \
      bf16x8 kf0 = *(const bf16x8*)&k_l[(BUF) * 4096 + jt * 1024 + ko0];     \
      bf16x8 kf1 = *(const bf16x8*)&k_l[(BUF) * 4096 + jt * 1024 + ko1];     \
      _Pragma("unroll") for (int qt = 0; qt < 2; ++qt) {                     \
        f32x4 s0 = __builtin_amdgcn_mfma_f32_16x16x32_bf16(kf0, qf[qt][0], zero4, 0, 0, 0); \
        accS[qt][jt] = __builtin_amdgcn_mfma_f32_16x16x32_bf16(kf1, qf[qt][1], s0, 0, 0, 0); \
      }                                                                      \
    }                                                                        \
    uint32_t pwu[2][2][4];                                                   \
    _Pragma("unroll") for (int qt = 0; qt < 2; ++qt) {                       \
      float rs = 0.f;                                                        \
      _Pragma("unroll") for (int jt = 0; jt < 4; ++jt) {                     \
        const float e0 = __builtin_amdgcn_exp2f(accS[qt][jt][0]);            \
        const float e1 = __builtin_amdgcn_exp2f(accS[qt][jt][1]);            \
        const float e2 = __builtin_amdgcn_exp2f(accS[qt][jt][2]);            \
        const float e3 = __builtin_amdgcn_exp2f(accS[qt][jt][3]);            \
        rs += (e0 + e1) + (e2 + e3);                                         \
        pwu[qt][jt >> 1][(jt & 1) * 2 + 0] = cvt_pk_bf16(e0, e1);            \
        pwu[qt][jt >> 1][(jt & 1) * 2 + 1] = cvt_pk_bf16(e2, e3);            \
      }                                                                      \
      l_r[qt] += rs;                                                         \
    }                                                                        \
    bf16x8 pf[2][2];                                                         \
    _Pragma("unroll") for (int qt = 0; qt < 2; ++qt)                         \
    _Pragma("unroll") for (int kb = 0; kb < 2; ++kb) {                       \
      u32x4 tmp = {pwu[qt][kb][0], pwu[qt][kb][1], pwu[qt][kb][2], pwu[qt][kb][3]}; \
      pf[qt][kb] = __builtin_bit_cast(bf16x8, tmp);                          \
    }                                                                        \
    _Pragma("unroll") for (int dt = 0; dt < 4; ++dt) {                       \
      union { short4v h[2]; bf16x8 v8; } vv0, vv1;                           \
      vv0.h[0] = *(const short4v*)&v_l[(BUF) * 4096 + dt * 1024 + vo00];     \
      vv0.h[1] = *(const short4v*)&v_l[(BUF) * 4096 + dt * 1024 + vo01];     \
      vv1.h[0] = *(const short4v*)&v_l[(BUF) * 4096 + dt * 1024 + vo10];     \
      vv1.h[1] = *(const short4v*)&v_l[(BUF) * 4096 + dt * 1024 + vo11];     \
      accO[0][dt] = __builtin_amdgcn_mfma_f32_16x16x32_bf16(vv0.v8, pf[0][0], accO[0][dt], 0, 0, 0); \
      accO[1][dt] = __builtin_amdgcn_mfma_f32_16x16x32_bf16(vv0.v8, pf[1][0], accO[1][dt], 0, 0, 0); \
      accO[0][dt] = __builtin_amdgcn_mfma_f32_16x16x32_bf16(vv1.v8, pf[0][1], accO[0][dt], 0, 0, 0); \
      accO[1][dt] = __builtin_amdgcn_mfma_f32_16x16x32_bf16(vv1.v8, pf[1][1], accO[1][dt], 0, 0, 0); \
    }                                                                        \
  }

// counted vmcnt: 4 own loads (next tile) stay in flight across the raw barrier
#define ATTN_PHASE(B, SB, VMSTR, DOST)                                       \
  asm volatile("s_waitcnt " VMSTR ::: "memory");                             \
  __builtin_amdgcn_s_barrier();                                              \
  if (DOST) { ATTN_STAGE(SB) }                                               \
  ATTN_COMPUTE(B)

__global__ __launch_bounds__(256) void attn_mfma_kernel(
    const unsigned short* __restrict__ Qb, const unsigned short* __restrict__ Kb,
    const unsigned short* __restrict__ Vb, unsigned short* __restrict__ Abf) {
  __shared__ unsigned short k_l[4 * 4096];  // 32 KiB
  __shared__ unsigned short v_l[4 * 4096];  // 32 KiB
  const int t = threadIdx.x;
  const int w = t >> 6;
  const int l = t & 63;
  const int g = l >> 4;
  const int c = l & 15;
  const int bid = blockIdx.x;
  const int gidx = (bid & 7) * 64 + (bid >> 3);  // XCD-contiguous bn
  const int bn = gidx >> 5;
  const int q0 = (gidx & 31) * 128 + w * 32;

  bf16x8 qf[2][2];
#pragma unroll
  for (int qt = 0; qt < 2; ++qt)
#pragma unroll
    for (int dh = 0; dh < 2; ++dh)
      qf[qt][dh] = *(const bf16x8*)&Qb[((size_t)bn * HW_ + q0 + qt * 16 + c) * 64 + dh * 32 + g * 8];

  // hoisted LDS fragment offsets (ushort units); buf/jt/dt fold into imm offsets
  const int sw = c & 7;
  const int ko0 = c * 64 + ((g ^ sw) * 8);
  const int ko1 = c * 64 + (((4 + g) ^ sw) * 8);
  const int vb_ = c * 64 + (g & 1) * 4;
  const int gh = g >> 1;
  const int vo00 = vb_ + (((0 + gh) ^ sw) * 8);
  const int vo01 = vb_ + (((2 + gh) ^ sw) * 8);
  const int vo10 = vb_ + (((4 + gh) ^ sw) * 8);
  const int vo11 = vb_ + (((6 + gh) ^ sw) * 8);

  const int srow = 16 * w + (l >> 3);
  const int schunk = (l & 7) ^ ((l >> 3) & 7);
  const unsigned short* gKp = Kb + ((size_t)bn * HW_ + srow) * 64 + schunk * 8;
  const unsigned short* gVp = Vb + ((size_t)bn * 64 + srow) * HW_ + schunk * 8;
  unsigned short* kst = k_l + w * 1024;  // wave-uniform stage bases
  unsigned short* vst = v_l + w * 1024;

  f32x4 accO[2][4] = {};
  float l_r[2] = {0.f, 0.f};
  const f32x4 zero4 = {0.f, 0.f, 0.f, 0.f};

  // prologue: tiles 0,1 -> bufs 0,1 (8 loads in flight per wave)
  ATTN_STAGE(0)
  ATTN_STAGE(1)

  for (int t4 = 0; t4 < 15; ++t4) {
    ATTN_PHASE(0, 2, "vmcnt(4)", 1)
    ATTN_PHASE(1, 3, "vmcnt(4)", 1)
    ATTN_PHASE(2, 0, "vmcnt(4)", 1)
    ATTN_PHASE(3, 1, "vmcnt(4)", 1)
  }
  ATTN_PHASE(0, 2, "vmcnt(4)", 1)  // t=60, stage 62
  ATTN_PHASE(1, 3, "vmcnt(4)", 1)  // t=61, stage 63
  ATTN_PHASE(2, 0, "vmcnt(4)", 0)  // t=62
  ATTN_PHASE(3, 0, "vmcnt(0)", 0)  // t=63

  // epilogue: normalize, emit bf16 cgroup layout for proj GEMM
  const int head = bn & 3;
  const int bb = bn >> 2;
#pragma unroll
  for (int qt = 0; qt < 2; ++qt) {
    float s = l_r[qt];
    s += __shfl_xor(s, 16);
    s += __shfl_xor(s, 32);
    const float inv = 1.0f / s;
    const int p = q0 + qt * 16 + c;
#pragma unroll
    for (int dt = 0; dt < 4; ++dt) {
      uint2 uu;
      uu.x = cvt_pk_bf16(accO[qt][dt][0] * inv, accO[qt][dt][1] * inv);
      uu.y = cvt_pk_bf16(accO[qt][dt][2] * inv, accO[qt][dt][3] * inv);
      const int cg = head * 8 + dt * 2 + (g >> 1);
      *(uint2*)&Abf[((size_t)(bb * 32 + cg) * HW_ + p) * 8 + (g & 1) * 4] = uu;
    }
  }
}

// ---------------- SE pooling from bf16 cgroup, p-split x2 (raw sums; merged in se) ----------------
__global__ __launch_bounds__(256) void pool_kernel(
    const unsigned short* __restrict__ Pbf, const unsigned short* __restrict__ Gbf,
    float* __restrict__ psum, float* __restrict__ pmaxH) {
  const int cg = blockIdx.x;  // 0..31
  const int b = blockIdx.y;
  const int half = blockIdx.z;
  const int t = threadIdx.x;
  const unsigned short* P = Pbf + ((size_t)(b * 32 + cg) * HW_ + half * 2048) * 8;
  const unsigned short* G = Gbf + ((size_t)(b * 32 + cg) * HW_ + half * 2048) * 8;
  float s[16], m[16];
#pragma unroll
  for (int i = 0; i < 16; ++i) { s[i] = 0.f; m[i] = -1e30f; }
  for (int p = t; p < 2048; p += 256) {
    uint4 a = *(const uint4*)&P[(size_t)p * 8];
    uint4 gg = *(const uint4*)&G[(size_t)p * 8];
    const uint32_t ua[4] = {a.x, a.y, a.z, a.w};
    const uint32_t ug[4] = {gg.x, gg.y, gg.z, gg.w};
#pragma unroll
    for (int q = 0; q < 4; ++q) {
      const float a0 = bf_lo(ua[q]), a1 = bf_hi(ua[q]);
      const float g0 = bf_lo(ug[q]), g1 = bf_hi(ug[q]);
      s[q * 2] += a0; s[q * 2 + 1] += a1;
      m[q * 2] = fmaxf(m[q * 2], a0); m[q * 2 + 1] = fmaxf(m[q * 2 + 1], a1);
      s[8 + q * 2] += g0; s[8 + q * 2 + 1] += g1;
      m[8 + q * 2] = fmaxf(m[8 + q * 2], g0); m[8 + q * 2 + 1] = fmaxf(m[8 + q * 2 + 1], g1);
    }
  }
#pragma unroll
  for (int i = 0; i < 16; ++i)
#pragma unroll
    for (int off = 1; off < 64; off <<= 1) {
      s[i] += __shfl_xor(s[i], off);
      m[i] = fmaxf(m[i], __shfl_xor(m[i], off));
    }
  __shared__ float red[4][32];
  const int wv = t >> 6;
  if ((t & 63) == 0) {
#pragma unroll
    for (int i = 0; i < 16; ++i) { red[wv][i] = s[i]; red[wv][16 + i] = m[i]; }
  }
  __syncthreads();
  if (t < 32) {
    const float v0 = red[0][t], v1 = red[1][t], v2 = red[2][t], v3 = red[3][t];
    if (t < 16) {
      const int ch = (t < 8) ? cg * 8 + t : 256 + cg * 8 + (t - 8);
      psum[half * 2048 + b * 512 + ch] = v0 + v1 + v2 + v3;
    } else {
      const int i = t - 16;
      const int ch = (i < 8) ? cg * 8 + i : 256 + cg * 8 + (i - 8);
      pmaxH[half * 2048 + b * 512 + ch] = fmaxf(fmaxf(v0, v1), fmaxf(v2, v3));
    }
  }
}

// ---------------- SE MLP (merges pool halves) ----------------
__global__ __launch_bounds__(256) void se_kernel(
    const float* __restrict__ psum, const float* __restrict__ pmaxH,
    const float* __restrict__ w1, const float* __restrict__ w2,
    float* __restrict__ wch) {
  const int b = blockIdx.x;
  const int t = threadIdx.x;
  __shared__ float za[512], zm[512], hs[64];
  za[t] = (psum[b * 512 + t] + psum[2048 + b * 512 + t]) * (1.f / 4096.f);
  za[256 + t] = (psum[b * 512 + 256 + t] + psum[2048 + b * 512 + 256 + t]) * (1.f / 4096.f);
  zm[t] = fmaxf(pmaxH[b * 512 + t], pmaxH[2048 + b * 512 + t]);
  zm[256 + t] = fmaxf(pmaxH[b * 512 + 256 + t], pmaxH[2048 + b * 512 + 256 + t]);
  __syncthreads();
  if (t < 64) {
    float ha = 0.f, hm = 0.f;
    for (int c = 0; c < 512; ++c) {
      const float w = w1[t * 512 + c];
      ha += w * za[c];
      hm += w * zm[c];
    }
    hs[t] = fmaxf(ha, 0.f) + fmaxf(hm, 0.f);
  }
  __syncthreads();
  for (int o = t; o < 512; o += 256) {
    float acc = 0.f;
#pragma unroll
    for (int hh = 0; hh < 64; ++hh) acc += hs[hh] * w2[o * 64 + hh];
    wch[b * 512 + o] = 1.f / (1.f + __expf(-acc));
  }
}

// ---------------- spatial-attention input: 4 ch-slices per block, LDS combine ----------------
__global__ __launch_bounds__(256) void sa_reduce_kernel(
    const unsigned short* __restrict__ Pbf, const unsigned short* __restrict__ Gbf,
    const float* __restrict__ wch, float* __restrict__ sa_in) {
  const int b = blockIdx.y;
  const int t = threadIdx.x;
  const int px = t & 63;
  const int sl = t >> 6;
  const int p = blockIdx.x * 64 + px;
  __shared__ float wl[512];
  __shared__ float sred[4][64], mred[4][64];
  wl[t] = wch[b * 512 + t];
  wl[256 + t] = wch[b * 512 + 256 + t];
  __syncthreads();
  float s = 0.f, mx = -1e30f;
#pragma unroll 4
  for (int k = 0; k < 16; ++k) {
    const int chunk = sl * 16 + k;  // 0..63: proj 0..31, gray 32..63
    const unsigned short* src = (chunk < 32)
        ? &Pbf[((size_t)(b * 32 + chunk) * HW_ + p) * 8]
        : &Gbf[((size_t)(b * 32 + (chunk - 32)) * HW_ + p) * 8];
    uint4 a = *(const uint4*)src;
    const uint32_t u[4] = {a.x, a.y, a.z, a.w};
#pragma unroll
    for (int q = 0; q < 4; ++q) {
      const float v0 = bf_lo(u[q]) * wl[chunk * 8 + q * 2];
      const float v1 = bf_hi(u[q]) * wl[chunk * 8 + q * 2 + 1];
      s += v0 + v1;
      mx = fmaxf(mx, fmaxf(v0, v1));
    }
  }
  sred[sl][px] = s;
  mred[sl][px] = mx;
  __syncthreads();
  if (sl == 0) {
    const float S = sred[0][px] + sred[1][px] + sred[2][px] + sred[3][px];
    const float M = fmaxf(fmaxf(mred[0][px], mred[1][px]), fmaxf(mred[2][px], mred[3][px]));
    sa_in[((size_t)b * 2 + 0) * HW_ + p] = S * (1.f / 512.f);
    sa_in[((size_t)b * 2 + 1) * HW_ + p] = M;
  }
}

// ---------------- 7x7 spatial conv + sigmoid -> wsp ----------------
__global__ __launch_bounds__(256) void sa_conv_kernel(
    const float* __restrict__ sa_in, const float* __restrict__ sa_w,
    float* __restrict__ wsp) {
  const int b = blockIdx.y;
  const int t = threadIdx.x;
  __shared__ float pl[2][64][64];
  __shared__ float wl[98];
  for (int e = t; e < 8192; e += 256) ((float*)pl)[e] = sa_in[(size_t)b * 8192 + e];
  if (t < 98) wl[t] = sa_w[t];
  __syncthreads();
  const int pix = blockIdx.x * 256 + t;
  const int y = pix >> 6, x = pix & 63;
  float acc = 0.f;
#pragma unroll
  for (int ic = 0; ic < 2; ++ic)
#pragma unroll
    for (int ky = 0; ky < 7; ++ky) {
      const int yy = y + ky - 3;
      if (yy < 0 || yy > 63) continue;
#pragma unroll
      for (int kx = 0; kx < 7; ++kx) {
        const int xx = x + kx - 3;
        if (xx < 0 || xx > 63) continue;
        acc += pl[ic][yy][xx] * wl[ic * 49 + ky * 7 + kx];
      }
    }
  wsp[(size_t)b * HW_ + pix] = 1.f / (1.f + __expf(-acc));
}

// ---------------- gate: catg[b][yp:66][xi:80][ic:512] bf16 (NHWC, halo=0) ----------------
__global__ __launch_bounds__(256) void gate_kernel(
    const unsigned short* __restrict__ Pbf, const unsigned short* __restrict__ Gbf,
    const float* __restrict__ wch, const float* __restrict__ wsp,
    unsigned short* __restrict__ catg) {
  const int yp = blockIdx.x;  // 0..65
  const int b = blockIdx.y;
  const int t = threadIdx.x;
  unsigned short* rowp = catg + ((size_t)b * 66 + yp) * 80 * 512;
  if (yp == 0 || yp == 65) {
    short8v z = {};
    for (int m = t; m < 5120; m += 256) *(short8v*)&rowp[m * 8] = z;
    return;
  }
  const int y = yp - 1;
  __shared__ unsigned short tile[64][512];  // [x][ch], chunk XOR-swizzled by (x&7)
  __shared__ float wchl[512];
  __shared__ float wspl[64];
  for (int e = t; e < 512; e += 256) wchl[e] = wch[b * 512 + e];
  if (t < 64) wspl[t] = wsp[(size_t)b * HW_ + y * 64 + t];
  {
    short8v z = {};
    for (int m = t; m < 1024; m += 256) {
      const int col = m >> 6;
      const int xi = (col < 8) ? col : (col + 64);
      *(short8v*)&rowp[(size_t)xi * 512 + (m & 63) * 8] = z;
    }
  }
  __syncthreads();
  const int x = t & 63;
  const int cs = t >> 6;
  const float wx = wspl[x];
#pragma unroll
  for (int k = 0; k < 16; ++k) {
    const int chunk = cs * 16 + k;  // 0..63 (proj: 0..31, gray: 32..63)
    const unsigned short* src = (chunk < 32)
        ? &Pbf[((size_t)(b * 32 + chunk) * HW_ + y * 64 + x) * 8]
        : &Gbf[((size_t)(b * 32 + (chunk - 32)) * HW_ + y * 64 + x) * 8];
    uint4 a = *(const uint4*)src;
    const uint32_t u[4] = {a.x, a.y, a.z, a.w};
    uint32_t o[4];
#pragma unroll
    for (int q = 0; q < 4; ++q) {
      const float lo = bf_lo(u[q]) * wchl[chunk * 8 + q * 2] * wx;
      const float hi = bf_hi(u[q]) * wchl[chunk * 8 + q * 2 + 1] * wx;
      o[q] = cvt_pk_bf16(lo, hi);
    }
    uint4 ov = {o[0], o[1], o[2], o[3]};
    *(uint4*)&tile[x][(chunk ^ (x & 7)) * 8] = ov;
  }
  __syncthreads();
#pragma unroll
  for (int j = 0; j < 16; ++j) {
    const int xi = (t >> 6) + 4 * j;
    const int c8 = t & 63;
    uint4 v = *(const uint4*)&tile[xi][(c8 ^ (xi & 7)) * 8];
    *(uint4*)&rowp[(size_t)(xi + 8) * 512 + c8 * 8] = v;
  }
}

// ---------------- fuse conv via MFMA: 32-oc tiles, 512 blocks, XCD-grouped ----------------
__global__ __launch_bounds__(256) void fuse_mfma_kernel(
    const unsigned short* __restrict__ catg, const unsigned short* __restrict__ wt,
    const float* __restrict__ bn_g, const float* __restrict__ bn_b,
    const float* __restrict__ bn_m, const float* __restrict__ bn_v,
    float* __restrict__ out) {
  __shared__ unsigned short X_l[2][6][2][80][8];  // 30 KiB
  __shared__ unsigned short W_l[2][9][2][32][8];  // 18 KiB
  __shared__ float invl[32], shl[32];
  const int t = threadIdx.x;
  const int w = t >> 6;
  const int l = t & 63;
  const int n = l & 31;
  const int g = l >> 5;
  const int i = blockIdx.x;
  const int xcd = i & 7, slot = i >> 3;  // slot 0..63
  const int ocB = slot & 7;
  const int yb = xcd + 8 * (slot >> 3);  // 0..63
  const int y0 = (yb & 15) * 4;
  const int o0 = ocB * 32;
  const int b = yb >> 4;

  if (t < 32) {
    const float iv = bn_g[o0 + t] * rsqrtf(bn_v[o0 + t] + 1e-5f);
    invl[t] = iv;
    shl[t] = bn_b[o0 + t] - bn_m[o0 + t] * iv;
  }

  const unsigned short* catb = catg + ((size_t)b * 66 + y0) * 80 * 512;

  auto stageX = [&](int bi, int ic0) {
    for (int wc = w; wc < 15; wc += 4) {
      const int m = wc * 64 + l;
      const int lr = m / 160;
      const int rem = m - lr * 160;
      const int half = rem / 80;
      const int xi = rem - half * 80;
      gld_lds16(catb + ((size_t)lr * 80 + xi) * 512 + ic0 + half * 8,
                &X_l[bi][0][0][0][0] + (size_t)wc * 512);
    }
  };
  auto stageW = [&](int bi, int ic0) {
    for (int wc = w; wc < 9; wc += 4) {
      const int m = wc * 64 + l;
      const int tap = m >> 6;
      const int rem = m & 63;
      const int half = rem >> 5;
      const int oc = rem & 31;
      gld_lds16(wt + ((size_t)tap * 256 + o0 + oc) * 512 + ic0 + half * 8,
                &W_l[bi][0][0][0][0] + (size_t)wc * 512);
    }
  };

  f32x16 acc[2] = {};

  stageX(0, 0);
  stageW(0, 0);
  int buf = 0;
  for (int ks = 0; ks < 32; ++ks) {
    asm volatile("s_waitcnt vmcnt(0)" ::: "memory");
    __syncthreads();
    if (ks < 31) {
      stageX(buf ^ 1, (ks + 1) * 16);
      stageW(buf ^ 1, (ks + 1) * 16);
    }
#pragma unroll
    for (int ky = 0; ky < 3; ++ky) {
      const int lr = w + ky;
#pragma unroll
      for (int kx = 0; kx < 3; ++kx) {
        const int tap = ky * 3 + kx;
        bf16x8 a0 = *(const bf16x8*)&W_l[buf][tap][g][n][0];
        bf16x8 b0 = *(const bf16x8*)&X_l[buf][lr][g][n + kx + 7][0];
        bf16x8 b1 = *(const bf16x8*)&X_l[buf][lr][g][32 + n + kx + 7][0];
        acc[0] = __builtin_amdgcn_mfma_f32_32x32x16_bf16(a0, b0, acc[0], 0, 0, 0);
        acc[1] = __builtin_amdgcn_mfma_f32_32x32x16_bf16(a0, b1, acc[1], 0, 0, 0);
      }
    }
    buf ^= 1;
  }

#pragma unroll
  for (int pf = 0; pf < 2; ++pf)
#pragma unroll
    for (int r = 0; r < 16; ++r) {
      const int row = (r & 3) + 8 * (r >> 2) + 4 * g;
      const float yv = acc[pf][r] * invl[row] + shl[row];
      const float ov = yv > 0.f ? yv : 0.2f * yv;
      out[((size_t)b * 256 + o0 + row) * HW_ + (size_t)(y0 + w) * 64 + pf * 32 + n] = ov;
    }
}

extern "C" void kernel_launch(void* const* d_in, const int* in_sizes, int n_in,
                              void* d_out, int out_size, void* d_ws, size_t ws_size,
                              hipStream_t stream) {
  const float* color  = (const float*)d_in[0];
  const float* gray   = (const float*)d_in[1];
  const float* Wq     = (const float*)d_in[2];
  const float* Wk     = (const float*)d_in[3];
  const float* Wv     = (const float*)d_in[4];
  const float* Wproj  = (const float*)d_in[5];
  const float* ca_w1  = (const float*)d_in[6];
  const float* ca_w2  = (const float*)d_in[7];
  const float* sa_w   = (const float*)d_in[8];
  const float* fuse_w = (const float*)d_in[9];
  const float* bn_g   = (const float*)d_in[10];
  const float* bn_b   = (const float*)d_in[11];
  const float* bn_m   = (const float*)d_in[12];
  const float* bn_v   = (const float*)d_in[13];
  float* out = (float*)d_out;

  char* ws = (char*)d_ws;
  // Overlay (MiB):
  // [0,8)   Cbf -> Abf (attn out; Cbf dead after Q gemm)
  // [8,16)  Gbf (live through gate)
  // [16,24) Qbf -> Pbf (proj out; Qbf dead after attn)
  // [24,32) Kbf \ dead after attn -> catg [24,44.63)
  // [32,40) Vbf /
  // [45,45.5) WqB..WpB; [45.5,47.75) Wt; [48,...) smalls
  unsigned short* Cbf = (unsigned short*)(ws);
  unsigned short* Gbf = (unsigned short*)(ws + (8u << 20));
  unsigned short* Qbf = (unsigned short*)(ws + (16u << 20));
  unsigned short* Kbf = (unsigned short*)(ws + (24u << 20));
  unsigned short* Vbf = (unsigned short*)(ws + (32u << 20));
  unsigned short* Abf = (unsigned short*)(ws);
  unsigned short* Pbf = (unsigned short*)(ws + (16u << 20));
  unsigned short* catg = (unsigned short*)(ws + (24u << 20));
  unsigned short* WqB = (unsigned short*)(ws + (45u << 20));
  unsigned short* WkB = WqB + 65536;
  unsigned short* WvB = WkB + 65536;
  unsigned short* WpB = WvB + 65536;
  unsigned short* Wt  = (unsigned short*)(ws + (45u << 20) + (1u << 19));
  float* psum  = (float*)(ws + (48u << 20));  // [2][2048]
  float* pmaxH = psum + 4096;                 // [2][2048]
  float* wch   = pmaxH + 4096;
  float* sa_in = wch + 2048;     // 32768
  float* wsp   = sa_in + 32768;  // 16384
  (void)in_sizes; (void)n_in; (void)out_size; (void)ws_size;

  const float qscale = 0.125f * 1.44269504f;

  prep_kernel<<<dim3(640), 256, 0, stream>>>(Wq, Wk, Wv, Wproj, fuse_w,
                                             WqB, WkB, WvB, WpB, Wt);
  xconv_kernel<<<dim3(2048), 256, 0, stream>>>(color, Cbf);
  xconv_kernel<<<dim3(2048), 256, 0, stream>>>(gray, Gbf);

  dim3 g_gemm(32, 4, 4);
  gemm_mfma_kernel<<<g_gemm, 256, 0, stream>>>(Cbf, WqB, Qbf, 1, qscale);
  gemm_mfma_kernel<<<g_gemm, 256, 0, stream>>>(Gbf, WkB, Kbf, 1, 1.0f);
  gemm_mfma_kernel<<<g_gemm, 256, 0, stream>>>(Gbf, WvB, Vbf, 2, 1.0f);
  attn_mfma_kernel<<<dim3(512), 256, 0, stream>>>(Qbf, Kbf, Vbf, Abf);
  gemm_mfma_kernel<<<g_gemm, 256, 0, stream>>>(Abf, WpB, Pbf, 3, 1.0f);

  pool_kernel<<<dim3(32, 4, 2), 256, 0, stream>>>(Pbf, Gbf, psum, pmaxH);
  se_kernel<<<dim3(4), 256, 0, stream>>>(psum, pmaxH, ca_w1, ca_w2, wch);
  sa_reduce_kernel<<<dim3(64, 4), 256, 0, stream>>>(Pbf, Gbf, wch, sa_in);
  sa_conv_kernel<<<dim3(16, 4), 256, 0, stream>>>(sa_in, sa_w, wsp);
  gate_kernel<<<dim3(66, 4), 256, 0, stream>>>(Pbf, Gbf, wch, wsp, catg);
  fuse_mfma_kernel<<<dim3(512), 256, 0, stream>>>(catg, Wt, bn_g, bn_b, bn_m, bn_v, out);
}